// Round 1
// baseline (1003.650 us; speedup 1.0000x reference)
//
#include <hip/hip_runtime.h>
#include <hip/hip_bf16.h>
#include <math.h>

#define NN 50000
#define NE 800000
#define FDIM 128
#define NBITS 64
#define NCLS 100
#define HD 300

typedef unsigned short u16;
typedef __attribute__((ext_vector_type(8))) short bf16x8;
typedef __attribute__((ext_vector_type(4))) float f32x4;

__device__ __forceinline__ float us2f(unsigned short u) {
    union { unsigned int i; float f; } x; x.i = ((unsigned int)u) << 16; return x.f;
}
__device__ __forceinline__ unsigned short f2bf(float f) {
    union { float f; unsigned int i; } x; x.f = f;
    unsigned int i = x.i;
    i += 0x7fffu + ((i >> 16) & 1u);   // round-to-nearest-even
    return (unsigned short)(i >> 16);
}

template <bool BF>
__device__ __forceinline__ float ldv(const void* p, size_t i) {
    return BF ? us2f(((const unsigned short*)p)[i]) : ((const float*)p)[i];
}
template <bool BF>
__device__ __forceinline__ void stv(void* p, size_t i, float v) {
    if (BF) ((unsigned short*)p)[i] = f2bf(v);
    else    ((float*)p)[i] = v;
}

// ---------------- dtype detection (flag=1 => bf16 buffers) ----------------
__global__ void __launch_bounds__(256) detect_kernel(const unsigned short* __restrict__ f,
                                                     int* __restrict__ flag) {
    __shared__ int bad;
    if (threadIdx.x == 0) bad = 0;
    __syncthreads();
    int b = 0;
    for (int i = threadIdx.x; i < 4096; i += 256) {
        float v = us2f(f[i]);
        if (!(fabsf(v) < 1e4f)) b = 1;   // catches NaN too
    }
    if (b) atomicOr(&bad, 1);
    __syncthreads();
    if (threadIdx.x == 0) flag[0] = bad ? 0 : 1;
}

// ---------------- CSR build ----------------
__global__ void __launch_bounds__(256) deg_kernel(const int* __restrict__ dst,
                                                  int* __restrict__ deg) {
    int e = blockIdx.x * 256 + threadIdx.x;
    if (e < NE) atomicAdd(&deg[dst[e]], 1);
}

// single-block hierarchical exclusive scan of deg[NN] -> rowptr[NN+1]
__global__ void __launch_bounds__(1024) scan_kernel(const int* __restrict__ deg,
                                                    int* __restrict__ rowptr) {
    __shared__ int wsum[16];
    __shared__ int carry_sh;
    int t = threadIdx.x;
    int lane = t & 63;
    int w = t >> 6;
    if (t == 0) carry_sh = 0;
    __syncthreads();
    for (int base = 0; base < NN; base += 1024) {
        int i = base + t;
        int v = (i < NN) ? deg[i] : 0;
        int x = v;
#pragma unroll
        for (int off = 1; off < 64; off <<= 1) {
            int u = __shfl_up(x, off);
            if (lane >= off) x += u;
        }
        if (lane == 63) wsum[w] = x;
        __syncthreads();
        if (w == 0) {
            int y = (lane < 16) ? wsum[lane] : 0;
#pragma unroll
            for (int off = 1; off < 16; off <<= 1) {
                int u = __shfl_up(y, off);
                if (lane >= off) y += u;
            }
            if (lane < 16) wsum[lane] = y;
        }
        __syncthreads();
        int woff = (w > 0) ? wsum[w - 1] : 0;
        int incl = x + woff;
        int carry = carry_sh;
        if (i < NN) rowptr[i] = carry + incl - v;   // exclusive
        __syncthreads();
        if (t == 1023) carry_sh = carry + incl;
        __syncthreads();
    }
    if (t == 0) rowptr[NN] = carry_sh;
}

__global__ void __launch_bounds__(256) fill_kernel(const int* __restrict__ src,
                                                   const int* __restrict__ dst,
                                                   const int* __restrict__ rowptr,
                                                   int* __restrict__ cursor,
                                                   int* __restrict__ col) {
    int e = blockIdx.x * 256 + threadIdx.x;
    if (e >= NE) return;
    int d = dst[e];
    int p = atomicAdd(&cursor[d], 1);
    col[rowptr[d] + p] = src[e];
}

// ---------------- weight transpose/pack (bf16 mode only) ----------------
// WT layout (elems): wt1l 0 | wt1r 16384 | wt2l 32768 | wt2r 49152 |
//                    wthd 65536 (304x128) | wtclas 104448 (112x128) |
//                    wtconv 118784 (64x128) | wtcv 126976 (112x64) | end 134144
#define WT_1L   0
#define WT_1R   16384
#define WT_2L   32768
#define WT_2R   49152
#define WT_HD   65536
#define WT_CLS  104448
#define WT_CONV 118784
#define WT_CV   126976
#define WT_TOTAL 134144

__global__ void __launch_bounds__(256) tr_all_kernel(
        const void* w1l, const void* w1r, const void* w2l, const void* w2r,
        const void* whd, const void* wclas, const void* wconv, const void* wcv,
        u16* __restrict__ wt, const int* __restrict__ flag) {
    if (!flag[0]) return;
    int idx = blockIdx.x * 256 + threadIdx.x;
    if (idx >= WT_TOTAL) return;
    const u16* src; int K, F, d;
    if      (idx < WT_1R)  { src = (const u16*)w1l;   K = 128; F = 128; d = idx - WT_1L; }
    else if (idx < WT_2L)  { src = (const u16*)w1r;   K = 128; F = 128; d = idx - WT_1R; }
    else if (idx < WT_2R)  { src = (const u16*)w2l;   K = 128; F = 128; d = idx - WT_2L; }
    else if (idx < WT_HD)  { src = (const u16*)w2r;   K = 128; F = 128; d = idx - WT_2R; }
    else if (idx < WT_CLS) { src = (const u16*)whd;   K = 128; F = 300; d = idx - WT_HD; }
    else if (idx < WT_CONV){ src = (const u16*)wclas; K = 128; F = 100; d = idx - WT_CLS; }
    else if (idx < WT_CV)  { src = (const u16*)wconv; K = 128; F = 64;  d = idx - WT_CONV; }
    else                   { src = (const u16*)wcv;   K = 64;  F = 100; d = idx - WT_CV; }
    int lgK = (K == 64) ? 6 : 7;
    int f = d >> lgK;          // padded output column (WT row)
    int k = d & (K - 1);
    wt[idx] = (f < F) ? src[k * F + f] : (u16)0;
}

// ---------------- gather aggregation ----------------
// one wave per node, 2 channels per lane
template <bool BF>
__device__ __forceinline__ void agg_body(const void* xv, const int* rowptr,
                                         const int* col, float* aggm) {
    int node = blockIdx.x * 4 + (threadIdx.x >> 6);
    int lane = threadIdx.x & 63;
    int beg = rowptr[node], end = rowptr[node + 1];
    float a0 = 0.f, a1 = 0.f;
    for (int j = beg; j < end; ++j) {
        int nbr = col[j];
        if (BF) {
            ushort2 u = *(const ushort2*)((const unsigned short*)xv + (size_t)nbr * FDIM + lane * 2);
            a0 += us2f(u.x); a1 += us2f(u.y);
        } else {
            float2 u = *(const float2*)((const float*)xv + (size_t)nbr * FDIM + lane * 2);
            a0 += u.x; a1 += u.y;
        }
    }
    float inv = 1.f / fmaxf((float)(end - beg), 1.f);
    float2 o; o.x = a0 * inv; o.y = a1 * inv;
    *(float2*)(aggm + (size_t)node * FDIM + lane * 2) = o;
}

// f32 mode gather (gated)
__global__ void __launch_bounds__(256) agg_f32_kernel(const float* __restrict__ x,
                                                      const int* __restrict__ rowptr,
                                                      const int* __restrict__ col,
                                                      float* __restrict__ aggm,
                                                      const int* __restrict__ flag) {
    if (flag[0]) return;
    agg_body<false>(x, rowptr, col, aggm);
}

// bf16 mode gather: bf16 in -> mean (f32 accum) -> bf16 out
__global__ void __launch_bounds__(256) aggb_kernel(const u16* __restrict__ xv,
                                                   const int* __restrict__ rowptr,
                                                   const int* __restrict__ col,
                                                   u16* __restrict__ aggm,
                                                   const int* __restrict__ flag) {
    if (!flag[0]) return;
    int node = blockIdx.x * 4 + (threadIdx.x >> 6);
    int lane = threadIdx.x & 63;
    int beg = rowptr[node], end = rowptr[node + 1];
    float a0 = 0.f, a1 = 0.f;
    for (int j = beg; j < end; ++j) {
        int nbr = col[j];
        ushort2 u = *(const ushort2*)(xv + (size_t)nbr * FDIM + lane * 2);
        a0 += us2f(u.x); a1 += us2f(u.y);
    }
    float inv = 1.f / fmaxf((float)(end - beg), 1.f);
    ushort2 o; o.x = f2bf(a0 * inv); o.y = f2bf(a1 * inv);
    *(ushort2*)(aggm + (size_t)node * FDIM + lane * 2) = o;
}

// ---------------- f32-mode fused SAGE linear (old vector path, gated) -------
template <bool XBF, bool WBF>
__device__ __forceinline__ void sage_body(const float* aggm, const void* xv,
                                          const void* wl, const void* bl,
                                          const void* wr, float* hout) {
    __shared__ float ms[8][FDIM];
    __shared__ float xs[8][FDIM];
    int n0 = blockIdx.x * 8;
    int t = threadIdx.x;
    for (int idx = t; idx < 8 * FDIM; idx += 256) {
        int j = idx >> 7, k = idx & 127;
        int n = n0 + j;
        ms[j][k] = aggm[(size_t)n * FDIM + k];
        xs[j][k] = ldv<XBF>(xv, (size_t)n * FDIM + k);
    }
    __syncthreads();
    int f = t & 127;
    int h = t >> 7;
    float acc[4] = {0.f, 0.f, 0.f, 0.f};
    for (int k = 0; k < FDIM; ++k) {
        float wlv = ldv<WBF>(wl, k * FDIM + f);
        float wrv = ldv<WBF>(wr, k * FDIM + f);
#pragma unroll
        for (int j = 0; j < 4; ++j) {
            int nn = h + j * 2;
            acc[j] += ms[nn][k] * wlv + xs[nn][k] * wrv;
        }
    }
    float bv = ldv<WBF>(bl, f);
#pragma unroll
    for (int j = 0; j < 4; ++j) {
        int nn = h + j * 2;
        float v = acc[j] + bv;
        hout[(size_t)(n0 + nn) * FDIM + f] = v > 0.f ? v : 0.f;
    }
}

__global__ void __launch_bounds__(256) sage_f32_kernel(const float* aggm, const float* x,
                                                       const void* wl, const void* bl,
                                                       const void* wr, float* hout,
                                                       const int* flag) {
    if (flag[0]) return;
    sage_body<false, false>(aggm, x, wl, bl, wr, hout);
}

// ---------------- bf16-mode fused SAGE linear via MFMA ----------------
// h = relu(agg@Wl + x@Wr + b). Wave owns 16 rows; A-frags cached in regs.
// WT is pre-transposed: WT[c][k] = W[k][c].
__global__ void __launch_bounds__(256) sage_mfma_kernel(
        const u16* __restrict__ agg, const u16* __restrict__ x,
        const u16* __restrict__ wtl, const u16* __restrict__ wtr,
        const void* __restrict__ bl, u16* __restrict__ hout,
        const int* __restrict__ flag) {
    if (!flag[0]) return;
    int wid = threadIdx.x >> 6, lane = threadIdx.x & 63;
    int r0 = blockIdx.x * 64 + wid * 16;
    if (r0 >= NN) return;
    int l15 = lane & 15;
    int koff = (lane >> 4) * 8;

    bf16x8 af[4], xf[4];
    const u16* ap = agg + (size_t)(r0 + l15) * FDIM + koff;
    const u16* xp = x   + (size_t)(r0 + l15) * FDIM + koff;
#pragma unroll
    for (int kf = 0; kf < 4; ++kf) {
        af[kf] = *(const bf16x8*)(ap + kf * 32);
        xf[kf] = *(const bf16x8*)(xp + kf * 32);
    }
    int orow = r0 + (lane >> 4) * 4;
    for (int ct = 0; ct < 8; ++ct) {
        int c0 = ct * 16;
        f32x4 acc = {0.f, 0.f, 0.f, 0.f};
        const u16* blp = wtl + (size_t)(c0 + l15) * FDIM + koff;
        const u16* brp = wtr + (size_t)(c0 + l15) * FDIM + koff;
#pragma unroll
        for (int kf = 0; kf < 4; ++kf) {
            bf16x8 bL = *(const bf16x8*)(blp + kf * 32);
            bf16x8 bR = *(const bf16x8*)(brp + kf * 32);
            acc = __builtin_amdgcn_mfma_f32_16x16x32_bf16(af[kf], bL, acc, 0, 0, 0);
            acc = __builtin_amdgcn_mfma_f32_16x16x32_bf16(xf[kf], bR, acc, 0, 0, 0);
        }
        int ocol = c0 + l15;
        float bv = us2f(((const u16*)bl)[ocol]);
#pragma unroll
        for (int i = 0; i < 4; ++i) {
            float v = acc[i] + bv;
            hout[(size_t)(orow + i) * FDIM + ocol] = f2bf(v > 0.f ? v : 0.f);
        }
    }
}

// ---------------- f32-mode head GEMM (old vector path, gated) ----------------
template <int KDIM, bool TANH_IN, bool BF>
__device__ __forceinline__ void head_body(const float* X, const void* W, const void* B,
                                          void* Y, size_t yoff, int fout,
                                          const void* gamma, const void* beta,
                                          const void* rm, const void* rv,
                                          float* pre_ws, int mode) {
    __shared__ float xs[16][KDIM];
    int n0 = blockIdx.x * 16;
    int t = threadIdx.x;
    for (int idx = t; idx < 16 * KDIM; idx += 256) {
        int j = idx / KDIM, k = idx % KDIM;
        float v = X[(size_t)(n0 + j) * KDIM + k];
        xs[j][k] = TANH_IN ? tanhf(v) : v;
    }
    __syncthreads();
    for (int f = t; f < fout; f += 256) {
        float acc[16];
#pragma unroll
        for (int j = 0; j < 16; ++j) acc[j] = 0.f;
        for (int k = 0; k < KDIM; ++k) {
            float wv = ldv<BF>(W, (size_t)k * fout + f);
#pragma unroll
            for (int j = 0; j < 16; ++j) acc[j] += xs[j][k] * wv;
        }
        float bv = ldv<BF>(B, f);
        if (mode == 0) {
#pragma unroll
            for (int j = 0; j < 16; ++j)
                stv<BF>(Y, yoff + (size_t)(n0 + j) * fout + f, acc[j] + bv);
        } else {
            float g  = ldv<BF>(gamma, f);
            float be = ldv<BF>(beta, f);
            float m  = ldv<BF>(rm, f);
            float rs = rsqrtf(ldv<BF>(rv, f) + 1e-5f);
#pragma unroll
            for (int j = 0; j < 16; ++j) {
                float p = g * (acc[j] + bv - m) * rs + be;
                pre_ws[(size_t)(n0 + j) * fout + f] = p;
                stv<BF>(Y, yoff + (size_t)(n0 + j) * fout + f, tanhf(p));
            }
        }
    }
}

template <int KDIM, bool TANH_IN>
__global__ void __launch_bounds__(256) head_f32_kernel(const float* X, const void* W,
                                                       const void* B, void* Y, size_t yoff,
                                                       int fout, const void* gamma,
                                                       const void* beta, const void* rm,
                                                       const void* rv, float* pre_ws,
                                                       int mode, const int* flag) {
    if (flag[0]) return;
    head_body<KDIM, TANH_IN, false>(X, W, B, Y, yoff, fout, gamma, beta, rm, rv, pre_ws, mode);
}

// ---------------- bf16-mode head GEMM via MFMA ----------------
// Y[r][c] = X[r][:] . W[:][c] + b[c], X bf16 [NN x K], WT bf16 [FP x K] (padded, zero-filled)
template <int K, int FP>
__global__ void __launch_bounds__(256) head_mfma_kernel(
        const u16* __restrict__ X, const u16* __restrict__ WT,
        const void* __restrict__ B, void* __restrict__ Y, size_t yoff,
        int fout, const int* __restrict__ flag) {
    if (!flag[0]) return;
    int wid = threadIdx.x >> 6, lane = threadIdx.x & 63;
    int r0 = blockIdx.x * 64 + wid * 16;
    if (r0 >= NN) return;
    int l15 = lane & 15;
    int koff = (lane >> 4) * 8;

    bf16x8 af[K / 32];
    const u16* xp = X + (size_t)(r0 + l15) * K + koff;
#pragma unroll
    for (int kf = 0; kf < K / 32; ++kf) af[kf] = *(const bf16x8*)(xp + kf * 32);

    u16* y = (u16*)Y + yoff;
    int orow = r0 + (lane >> 4) * 4;
    for (int ct = 0; ct < FP / 16; ++ct) {
        int c0 = ct * 16;
        f32x4 acc = {0.f, 0.f, 0.f, 0.f};
        const u16* bp = WT + (size_t)(c0 + l15) * K + koff;
#pragma unroll
        for (int kf = 0; kf < K / 32; ++kf) {
            bf16x8 bF = *(const bf16x8*)(bp + kf * 32);
            acc = __builtin_amdgcn_mfma_f32_16x16x32_bf16(af[kf], bF, acc, 0, 0, 0);
        }
        int ocol = c0 + l15;
        if (ocol < fout) {
            float bv = us2f(((const u16*)B)[ocol]);
#pragma unroll
            for (int i = 0; i < 4; ++i)
                y[(size_t)(orow + i) * fout + ocol] = f2bf(acc[i] + bv);
        }
    }
}

// conv head with fused BN (eval) + tanh; fout = 64 (= NBITS), K = 128
__global__ void __launch_bounds__(256) headconv_mfma_kernel(
        const u16* __restrict__ X, const u16* __restrict__ WT,
        const void* __restrict__ B, const void* __restrict__ gamma,
        const void* __restrict__ beta, const void* __restrict__ rm,
        const void* __restrict__ rv, float* __restrict__ pre,
        void* __restrict__ Y, size_t yoff, const int* __restrict__ flag) {
    if (!flag[0]) return;
    int wid = threadIdx.x >> 6, lane = threadIdx.x & 63;
    int r0 = blockIdx.x * 64 + wid * 16;
    if (r0 >= NN) return;
    int l15 = lane & 15;
    int koff = (lane >> 4) * 8;

    bf16x8 af[4];
    const u16* xp = X + (size_t)(r0 + l15) * FDIM + koff;
#pragma unroll
    for (int kf = 0; kf < 4; ++kf) af[kf] = *(const bf16x8*)(xp + kf * 32);

    u16* y = (u16*)Y + yoff;
    int orow = r0 + (lane >> 4) * 4;
    for (int ct = 0; ct < 4; ++ct) {
        int c0 = ct * 16;
        f32x4 acc = {0.f, 0.f, 0.f, 0.f};
        const u16* bp = WT + (size_t)(c0 + l15) * FDIM + koff;
#pragma unroll
        for (int kf = 0; kf < 4; ++kf) {
            bf16x8 bF = *(const bf16x8*)(bp + kf * 32);
            acc = __builtin_amdgcn_mfma_f32_16x16x32_bf16(af[kf], bF, acc, 0, 0, 0);
        }
        int ocol = c0 + l15;
        float bv = us2f(((const u16*)B)[ocol]);
        float g  = us2f(((const u16*)gamma)[ocol]);
        float be = us2f(((const u16*)beta)[ocol]);
        float m  = us2f(((const u16*)rm)[ocol]);
        float rs = rsqrtf(us2f(((const u16*)rv)[ocol]) + 1e-5f);
#pragma unroll
        for (int i = 0; i < 4; ++i) {
            float p = g * (acc[i] + bv - m) * rs + be;
            pre[(size_t)(orow + i) * NBITS + ocol] = p;
            y[(size_t)(orow + i) * NBITS + ocol] = f2bf(tanhf(p));
        }
    }
}

// ---------------- true_lab: pre @ wtl + btl  (K=64, Fout=1) ----------------
template <bool BF>
__device__ __forceinline__ void tl_body(const float* pre, const void* wtl,
                                        const void* btl, void* y, size_t yoff) {
    int i = blockIdx.x * 256 + threadIdx.x;
    if (i >= NN) return;
    float s = ldv<BF>(btl, 0);
#pragma unroll 8
    for (int k = 0; k < NBITS; ++k) s += pre[(size_t)i * NBITS + k] * ldv<BF>(wtl, k);
    stv<BF>(y, yoff + i, s);
}

__global__ void __launch_bounds__(256) true_lab_f32_kernel(const float* pre, const void* wtl,
                                                           const void* btl, void* y,
                                                           size_t yoff, const int* flag) {
    if (flag[0]) return;
    tl_body<false>(pre, wtl, btl, y, yoff);
}
__global__ void __launch_bounds__(256) true_lab_b16_kernel(const float* pre, const void* wtl,
                                                           const void* btl, void* y,
                                                           size_t yoff, const int* flag) {
    if (!flag[0]) return;
    tl_body<true>(pre, wtl, btl, y, yoff);
}

extern "C" void kernel_launch(void* const* d_in, const int* in_sizes, int n_in,
                              void* d_out, int out_size, void* d_ws, size_t ws_size,
                              hipStream_t stream) {
    const void* feat = d_in[0];
    const int* edges = (const int*)d_in[1];
    const void* w1l = d_in[2];
    const void* b1l = d_in[3];
    const void* w1r = d_in[4];
    const void* w2l = d_in[5];
    const void* b2l = d_in[6];
    const void* w2r = d_in[7];
    const void* whd = d_in[8];
    const void* bhd = d_in[9];
    const void* wclas = d_in[10];
    const void* bclas = d_in[11];
    const void* wconv = d_in[12];
    const void* bconv = d_in[13];
    const void* gamma = d_in[14];
    const void* beta  = d_in[15];
    const void* rm  = d_in[16];
    const void* rv  = d_in[17];
    const void* wtl = d_in[18];
    const void* btl = d_in[19];
    const void* wcv = d_in[20];
    const void* bcv = d_in[21];

    // workspace layout (same total as before):
    //   int: flag[16] | deg[50000] | cursor[50000] | rowptr[50016] | col[800000]
    //   f32: buf1[NN*128] | buf2[NN*128]
    // bf16-mode overlays:
    //   aggb (bf16 NN*128) + hb1 (bf16 NN*128) over buf1
    //   hb2  (bf16 NN*128) + pre_b (f32 NN*64) over buf2
    //   WT (268 KB bf16) over deg+cursor (400 KB, dead after fill; rebuilt per iter)
    int* iw     = (int*)d_ws;
    int* flag   = iw;
    int* deg    = iw + 16;
    int* cursor = deg + NN;
    int* rowptr = cursor + NN;
    int* col    = rowptr + 50016;
    float* buf1 = (float*)(col + NE);
    float* buf2 = buf1 + (size_t)NN * FDIM;
    float* pre_f = buf1;   // f32 mode: pre overlays buf1 (h1 dead after sage2)

    u16* aggb = (u16*)buf1;
    u16* hb1  = aggb + (size_t)NN * FDIM;
    u16* hb2  = (u16*)buf2;
    float* pre_b = buf2 + (size_t)NN * 64;   // second half of buf2 region

    u16* wt = (u16*)deg;   // 134144 elems = 268 KB < 400 KB (deg+cursor)
    u16* wt1l = wt + WT_1L;
    u16* wt1r = wt + WT_1R;
    u16* wt2l = wt + WT_2L;
    u16* wt2r = wt + WT_2R;
    u16* wthd = wt + WT_HD;
    u16* wtcls = wt + WT_CLS;
    u16* wtconv = wt + WT_CONV;
    u16* wtcv = wt + WT_CV;

    const int* src = edges;
    const int* dst = edges + NE;

    // zero flag+deg+cursor (contiguous int region)
    hipMemsetAsync(iw, 0, (size_t)(16 + 2 * NN) * sizeof(int), stream);

    detect_kernel<<<1, 256, 0, stream>>>((const unsigned short*)feat, flag);

    // CSR build
    deg_kernel<<<(NE + 255) / 256, 256, 0, stream>>>(dst, deg);
    scan_kernel<<<1, 1024, 0, stream>>>(deg, rowptr);
    fill_kernel<<<(NE + 255) / 256, 256, 0, stream>>>(src, dst, rowptr, cursor, col);

    // weight transpose/pack (bf16 mode; overlays deg/cursor AFTER fill is done)
    tr_all_kernel<<<(WT_TOTAL + 255) / 256, 256, 0, stream>>>(
        w1l, w1r, w2l, w2r, whd, wclas, wconv, wcv, wt, flag);

    // output element offsets: logists | tanh_out | fea_lab | fea_convert | true_lab
    size_t o_log  = 0;
    size_t o_tanh = (size_t)NN * NCLS;
    size_t o_flab = o_tanh + (size_t)NN * NBITS;
    size_t o_fcv  = o_flab + (size_t)NN * HD;
    size_t o_tl   = o_fcv + (size_t)NN * NCLS;

    const int GR = (3125 + 3) / 4;   // 782 blocks, 4 waves x 16 rows

    // ---------------- bf16 MFMA path ----------------
    aggb_kernel<<<NN / 4, 256, 0, stream>>>((const u16*)feat, rowptr, col, aggb, flag);
    sage_mfma_kernel<<<GR, 256, 0, stream>>>(aggb, (const u16*)feat, wt1l, wt1r, b1l, hb1, flag);
    aggb_kernel<<<NN / 4, 256, 0, stream>>>(hb1, rowptr, col, aggb, flag);
    sage_mfma_kernel<<<GR, 256, 0, stream>>>(aggb, hb1, wt2l, wt2r, b2l, hb2, flag);

    head_mfma_kernel<128, 304><<<GR, 256, 0, stream>>>(hb2, wthd, bhd, d_out, o_flab, HD, flag);
    head_mfma_kernel<128, 112><<<GR, 256, 0, stream>>>(hb2, wtcls, bclas, d_out, o_log, NCLS, flag);
    headconv_mfma_kernel<<<GR, 256, 0, stream>>>(hb2, wtconv, bconv, gamma, beta, rm, rv,
                                                 pre_b, d_out, o_tanh, flag);
    head_mfma_kernel<64, 112><<<GR, 256, 0, stream>>>((const u16*)d_out + o_tanh, wtcv, bcv,
                                                      d_out, o_fcv, NCLS, flag);
    true_lab_b16_kernel<<<(NN + 255) / 256, 256, 0, stream>>>(pre_b, wtl, btl, d_out, o_tl, flag);

    // ---------------- f32 vector path (gated off in bf16 mode) ----------------
    agg_f32_kernel<<<NN / 4, 256, 0, stream>>>((const float*)feat, rowptr, col, buf1, flag);
    sage_f32_kernel<<<NN / 8, 256, 0, stream>>>(buf1, (const float*)feat, w1l, b1l, w1r, buf1, flag);
    agg_f32_kernel<<<NN / 4, 256, 0, stream>>>(buf1, rowptr, col, buf2, flag);
    sage_f32_kernel<<<NN / 8, 256, 0, stream>>>(buf2, buf1, w2l, b2l, w2r, buf2, flag);

    head_f32_kernel<FDIM, false><<<NN / 16, 256, 0, stream>>>(
        buf2, whd, bhd, d_out, o_flab, HD,
        nullptr, nullptr, nullptr, nullptr, nullptr, 0, flag);
    head_f32_kernel<FDIM, false><<<NN / 16, 256, 0, stream>>>(
        buf2, wclas, bclas, d_out, o_log, NCLS,
        nullptr, nullptr, nullptr, nullptr, nullptr, 0, flag);
    head_f32_kernel<FDIM, false><<<NN / 16, 256, 0, stream>>>(
        buf2, wconv, bconv, d_out, o_tanh, NBITS,
        gamma, beta, rm, rv, pre_f, 1, flag);
    head_f32_kernel<NBITS, true><<<NN / 16, 256, 0, stream>>>(
        pre_f, wcv, bcv, d_out, o_fcv, NCLS,
        nullptr, nullptr, nullptr, nullptr, nullptr, 0, flag);
    true_lab_f32_kernel<<<(NN + 255) / 256, 256, 0, stream>>>(pre_f, wtl, btl, d_out, o_tl, flag);
}

// Round 2
// 763.530 us; speedup vs baseline: 1.3145x; 1.3145x over previous
//
#include <hip/hip_runtime.h>
#include <hip/hip_bf16.h>
#include <math.h>

#define NN 50000
#define NE 800000
#define FDIM 128
#define NBITS 64
#define NCLS 100
#define HD 300

typedef unsigned short u16;
typedef __attribute__((ext_vector_type(8))) short bf16x8;
typedef __attribute__((ext_vector_type(4))) float f32x4;

#define MFMA16(a, b, c) __builtin_amdgcn_mfma_f32_16x16x32_bf16((a), (b), (c), 0, 0, 0)

__device__ __forceinline__ float us2f(unsigned short u) {
    union { unsigned int i; float f; } x; x.i = ((unsigned int)u) << 16; return x.f;
}
__device__ __forceinline__ unsigned short f2bf(float f) {
    union { float f; unsigned int i; } x; x.f = f;
    unsigned int i = x.i;
    i += 0x7fffu + ((i >> 16) & 1u);   // round-to-nearest-even
    return (unsigned short)(i >> 16);
}
__device__ __forceinline__ unsigned short f2bf_trunc(float f) {
    union { float f; unsigned int i; } x; x.f = f;
    return (unsigned short)(x.i >> 16);   // round-toward-zero
}

template <bool BF>
__device__ __forceinline__ float ldv(const void* p, size_t i) {
    return BF ? us2f(((const unsigned short*)p)[i]) : ((const float*)p)[i];
}
template <bool BF>
__device__ __forceinline__ void stv(void* p, size_t i, float v) {
    if (BF) ((unsigned short*)p)[i] = f2bf(v);
    else    ((float*)p)[i] = v;
}

// split 8 contiguous f32 into bf16 hi (trunc) + lo (RNE of residual)
__device__ __forceinline__ void splitA(const float* p, bf16x8& hi, bf16x8& lo) {
    float4 a = *(const float4*)p;
    float4 b = *(const float4*)(p + 4);
    float v[8] = {a.x, a.y, a.z, a.w, b.x, b.y, b.z, b.w};
#pragma unroll
    for (int j = 0; j < 8; ++j) {
        u16 h = f2bf_trunc(v[j]);
        float r = v[j] - us2f(h);
        hi[j] = (short)h;
        lo[j] = (short)f2bf(r);
    }
}

// ---------------- dtype detection (flag=1 => bf16 buffers) ----------------
__global__ void __launch_bounds__(256) detect_kernel(const unsigned short* __restrict__ f,
                                                     int* __restrict__ flag) {
    __shared__ int bad;
    if (threadIdx.x == 0) bad = 0;
    __syncthreads();
    int b = 0;
    for (int i = threadIdx.x; i < 4096; i += 256) {
        float v = us2f(f[i]);
        if (!(fabsf(v) < 1e4f)) b = 1;   // catches NaN too
    }
    if (b) atomicOr(&bad, 1);
    __syncthreads();
    if (threadIdx.x == 0) flag[0] = bad ? 0 : 1;
}

// ---------------- CSR build ----------------
__global__ void __launch_bounds__(256) deg_kernel(const int* __restrict__ dst,
                                                  int* __restrict__ deg) {
    int e = blockIdx.x * 256 + threadIdx.x;
    if (e < NE) atomicAdd(&deg[dst[e]], 1);
}

__global__ void __launch_bounds__(1024) scan_kernel(const int* __restrict__ deg,
                                                    int* __restrict__ rowptr) {
    __shared__ int wsum[16];
    __shared__ int carry_sh;
    int t = threadIdx.x;
    int lane = t & 63;
    int w = t >> 6;
    if (t == 0) carry_sh = 0;
    __syncthreads();
    for (int base = 0; base < NN; base += 1024) {
        int i = base + t;
        int v = (i < NN) ? deg[i] : 0;
        int x = v;
#pragma unroll
        for (int off = 1; off < 64; off <<= 1) {
            int u = __shfl_up(x, off);
            if (lane >= off) x += u;
        }
        if (lane == 63) wsum[w] = x;
        __syncthreads();
        if (w == 0) {
            int y = (lane < 16) ? wsum[lane] : 0;
#pragma unroll
            for (int off = 1; off < 16; off <<= 1) {
                int u = __shfl_up(y, off);
                if (lane >= off) y += u;
            }
            if (lane < 16) wsum[lane] = y;
        }
        __syncthreads();
        int woff = (w > 0) ? wsum[w - 1] : 0;
        int incl = x + woff;
        int carry = carry_sh;
        if (i < NN) rowptr[i] = carry + incl - v;   // exclusive
        __syncthreads();
        if (t == 1023) carry_sh = carry + incl;
        __syncthreads();
    }
    if (t == 0) rowptr[NN] = carry_sh;
}

__global__ void __launch_bounds__(256) fill_kernel(const int* __restrict__ src,
                                                   const int* __restrict__ dst,
                                                   const int* __restrict__ rowptr,
                                                   int* __restrict__ cursor,
                                                   int* __restrict__ col) {
    int e = blockIdx.x * 256 + threadIdx.x;
    if (e >= NE) return;
    int d = dst[e];
    int p = atomicAdd(&cursor[d], 1);
    col[rowptr[d] + p] = src[e];
}

// ---------------- weight transpose/pack layout ----------------
// WT layout (elems): wt1l 0 | wt1r 16384 | wt2l 32768 | wt2r 49152 |
//   wthd 65536 (304x128) | wtclas 104448 (112x128) | wtconv 118784 (64x128) |
//   wtcv 126976 (112x64) | end 134144
#define WT_1L   0
#define WT_1R   16384
#define WT_2L   32768
#define WT_2R   49152
#define WT_HD   65536
#define WT_CLS  104448
#define WT_CONV 118784
#define WT_CV   126976
#define WT_TOTAL 134144

// bf16-input mode: single packed WT (overlays deg+cursor)
__global__ void __launch_bounds__(256) tr_all_kernel(
        const void* w1l, const void* w1r, const void* w2l, const void* w2r,
        const void* whd, const void* wclas, const void* wconv, const void* wcv,
        u16* __restrict__ wt, const int* __restrict__ flag) {
    if (!flag[0]) return;
    int idx = blockIdx.x * 256 + threadIdx.x;
    if (idx >= WT_TOTAL) return;
    const u16* src; int K, F, d;
    if      (idx < WT_1R)  { src = (const u16*)w1l;   K = 128; F = 128; d = idx - WT_1L; }
    else if (idx < WT_2L)  { src = (const u16*)w1r;   K = 128; F = 128; d = idx - WT_1R; }
    else if (idx < WT_2R)  { src = (const u16*)w2l;   K = 128; F = 128; d = idx - WT_2L; }
    else if (idx < WT_HD)  { src = (const u16*)w2r;   K = 128; F = 128; d = idx - WT_2R; }
    else if (idx < WT_CLS) { src = (const u16*)whd;   K = 128; F = 300; d = idx - WT_HD; }
    else if (idx < WT_CONV){ src = (const u16*)wclas; K = 128; F = 100; d = idx - WT_CLS; }
    else if (idx < WT_CV)  { src = (const u16*)wconv; K = 128; F = 64;  d = idx - WT_CONV; }
    else                   { src = (const u16*)wcv;   K = 64;  F = 100; d = idx - WT_CV; }
    int lgK = (K == 64) ? 6 : 7;
    int f = d >> lgK;
    int k = d & (K - 1);
    wt[idx] = (f < F) ? src[k * F + f] : (u16)0;
}

// f32-input mode: transposed hi/lo split weights
__global__ void __launch_bounds__(256) tr_f32_kernel(
        const float* w1l, const float* w1r, const float* w2l, const float* w2r,
        const float* whd, const float* wclas, const float* wconv, const float* wcv,
        u16* __restrict__ wth, u16* __restrict__ wtlo, const int* __restrict__ flag) {
    if (flag[0]) return;
    int idx = blockIdx.x * 256 + threadIdx.x;
    if (idx >= WT_TOTAL) return;
    const float* src; int K, F, d;
    if      (idx < WT_1R)  { src = w1l;   K = 128; F = 128; d = idx - WT_1L; }
    else if (idx < WT_2L)  { src = w1r;   K = 128; F = 128; d = idx - WT_1R; }
    else if (idx < WT_2R)  { src = w2l;   K = 128; F = 128; d = idx - WT_2L; }
    else if (idx < WT_HD)  { src = w2r;   K = 128; F = 128; d = idx - WT_2R; }
    else if (idx < WT_CLS) { src = whd;   K = 128; F = 300; d = idx - WT_HD; }
    else if (idx < WT_CONV){ src = wclas; K = 128; F = 100; d = idx - WT_CLS; }
    else if (idx < WT_CV)  { src = wconv; K = 128; F = 64;  d = idx - WT_CONV; }
    else                   { src = wcv;   K = 64;  F = 100; d = idx - WT_CV; }
    int lgK = (K == 64) ? 6 : 7;
    int f = d >> lgK;
    int k = d & (K - 1);
    float v = (f < F) ? src[k * F + f] : 0.f;
    u16 h = f2bf_trunc(v);
    wth[idx]  = h;
    wtlo[idx] = f2bf(v - us2f(h));
}

// ---------------- gather aggregation ----------------
template <bool BF>
__device__ __forceinline__ void agg_body(const void* xv, const int* rowptr,
                                         const int* col, float* aggm) {
    int node = blockIdx.x * 4 + (threadIdx.x >> 6);
    int lane = threadIdx.x & 63;
    int beg = rowptr[node], end = rowptr[node + 1];
    float a0 = 0.f, a1 = 0.f;
    for (int j = beg; j < end; ++j) {
        int nbr = col[j];
        if (BF) {
            ushort2 u = *(const ushort2*)((const unsigned short*)xv + (size_t)nbr * FDIM + lane * 2);
            a0 += us2f(u.x); a1 += us2f(u.y);
        } else {
            float2 u = *(const float2*)((const float*)xv + (size_t)nbr * FDIM + lane * 2);
            a0 += u.x; a1 += u.y;
        }
    }
    float inv = 1.f / fmaxf((float)(end - beg), 1.f);
    float2 o; o.x = a0 * inv; o.y = a1 * inv;
    *(float2*)(aggm + (size_t)node * FDIM + lane * 2) = o;
}

__global__ void __launch_bounds__(256) agg_f32_kernel(const float* __restrict__ x,
                                                      const int* __restrict__ rowptr,
                                                      const int* __restrict__ col,
                                                      float* __restrict__ aggm,
                                                      const int* __restrict__ flag) {
    if (flag[0]) return;
    agg_body<false>(x, rowptr, col, aggm);
}

// bf16 mode gather: bf16 in -> mean (f32 accum) -> bf16 out
__global__ void __launch_bounds__(256) aggb_kernel(const u16* __restrict__ xv,
                                                   const int* __restrict__ rowptr,
                                                   const int* __restrict__ col,
                                                   u16* __restrict__ aggm,
                                                   const int* __restrict__ flag) {
    if (!flag[0]) return;
    int node = blockIdx.x * 4 + (threadIdx.x >> 6);
    int lane = threadIdx.x & 63;
    int beg = rowptr[node], end = rowptr[node + 1];
    float a0 = 0.f, a1 = 0.f;
    for (int j = beg; j < end; ++j) {
        int nbr = col[j];
        ushort2 u = *(const ushort2*)(xv + (size_t)nbr * FDIM + lane * 2);
        a0 += us2f(u.x); a1 += us2f(u.y);
    }
    float inv = 1.f / fmaxf((float)(end - beg), 1.f);
    ushort2 o; o.x = f2bf(a0 * inv); o.y = f2bf(a1 * inv);
    *(ushort2*)(aggm + (size_t)node * FDIM + lane * 2) = o;
}

// ================= f32-input mode: split-bf16 MFMA path =================

// h = relu(agg@Wl + x@Wr + b), f32 in/out, bf16x3 emulated GEMM
__global__ void __launch_bounds__(256) sage_mfma_f32_kernel(
        const float* __restrict__ agg, const float* __restrict__ x,
        const u16* __restrict__ wlh, const u16* __restrict__ wll,
        const u16* __restrict__ wrh, const u16* __restrict__ wrl,
        const float* __restrict__ bl, float* __restrict__ hout,
        const int* __restrict__ flag) {
    if (flag[0]) return;
    int wid = threadIdx.x >> 6, lane = threadIdx.x & 63;
    int r0 = blockIdx.x * 64 + wid * 16;
    if (r0 >= NN) return;
    int l15 = lane & 15;
    int koff = (lane >> 4) * 8;

    bf16x8 ah[4], al[4], xh[4], xl[4];
    const float* ap = agg + (size_t)(r0 + l15) * FDIM + koff;
    const float* xp = x   + (size_t)(r0 + l15) * FDIM + koff;
#pragma unroll
    for (int kf = 0; kf < 4; ++kf) {
        splitA(ap + kf * 32, ah[kf], al[kf]);
        splitA(xp + kf * 32, xh[kf], xl[kf]);
    }
    int orow = r0 + (lane >> 4) * 4;
#pragma unroll
    for (int cp = 0; cp < 4; ++cp) {
        int c0 = cp * 32;
        f32x4 acc0 = {0.f, 0.f, 0.f, 0.f};
        f32x4 acc1 = {0.f, 0.f, 0.f, 0.f};
        const u16* pLh = wlh + (size_t)(c0 + l15) * FDIM + koff;
        const u16* pLl = wll + (size_t)(c0 + l15) * FDIM + koff;
        const u16* pRh = wrh + (size_t)(c0 + l15) * FDIM + koff;
        const u16* pRl = wrl + (size_t)(c0 + l15) * FDIM + koff;
#pragma unroll
        for (int kf = 0; kf < 4; ++kf) {
            int o0 = kf * 32;
            int o1 = o0 + 16 * FDIM;
            bf16x8 bLh = *(const bf16x8*)(pLh + o0);
            bf16x8 bLl = *(const bf16x8*)(pLl + o0);
            bf16x8 bRh = *(const bf16x8*)(pRh + o0);
            bf16x8 bRl = *(const bf16x8*)(pRl + o0);
            bf16x8 cLh = *(const bf16x8*)(pLh + o1);
            bf16x8 cLl = *(const bf16x8*)(pLl + o1);
            bf16x8 cRh = *(const bf16x8*)(pRh + o1);
            bf16x8 cRl = *(const bf16x8*)(pRl + o1);
            acc0 = MFMA16(ah[kf], bLh, acc0);
            acc1 = MFMA16(ah[kf], cLh, acc1);
            acc0 = MFMA16(al[kf], bLh, acc0);
            acc1 = MFMA16(al[kf], cLh, acc1);
            acc0 = MFMA16(ah[kf], bLl, acc0);
            acc1 = MFMA16(ah[kf], cLl, acc1);
            acc0 = MFMA16(xh[kf], bRh, acc0);
            acc1 = MFMA16(xh[kf], cRh, acc1);
            acc0 = MFMA16(xl[kf], bRh, acc0);
            acc1 = MFMA16(xl[kf], cRh, acc1);
            acc0 = MFMA16(xh[kf], bRl, acc0);
            acc1 = MFMA16(xh[kf], cRl, acc1);
        }
        int oc0 = c0 + l15, oc1 = oc0 + 16;
        float bv0 = bl[oc0], bv1 = bl[oc1];
#pragma unroll
        for (int i = 0; i < 4; ++i) {
            float v0 = acc0[i] + bv0;
            float v1 = acc1[i] + bv1;
            hout[(size_t)(orow + i) * FDIM + oc0] = v0 > 0.f ? v0 : 0.f;
            hout[(size_t)(orow + i) * FDIM + oc1] = v1 > 0.f ? v1 : 0.f;
        }
    }
}

// epilogue for the fused 3-head kernel: global col-tile ct in [0,30)
// cols 0..303 -> fea_lab (HD) | 304..415 -> logists (NCLS) | 416..479 -> conv+BN+tanh
__device__ __forceinline__ void heads3_epi(int ct, int l15, int orow, const f32x4& acc,
        const float* bhd, const float* bclas, const float* bconv,
        const float* gamma, const float* beta, const float* rm, const float* rv,
        const float* wtl, float* out, size_t o_flab, size_t o_log, size_t o_tanh,
        float* tl) {
    int gcol = ct * 16 + l15;
    if (gcol < 304) {
        if (gcol < 300) {
            float bv = bhd[gcol];
#pragma unroll
            for (int i = 0; i < 4; ++i)
                out[o_flab + (size_t)(orow + i) * HD + gcol] = acc[i] + bv;
        }
    } else if (gcol < 416) {
        int lc = gcol - 304;
        if (lc < NCLS) {
            float bv = bclas[lc];
#pragma unroll
            for (int i = 0; i < 4; ++i)
                out[o_log + (size_t)(orow + i) * NCLS + lc] = acc[i] + bv;
        }
    } else {
        int lc = gcol - 416;
        float bv = bconv[lc];
        float g  = gamma[lc];
        float be = beta[lc];
        float m  = rm[lc];
        float rs = rsqrtf(rv[lc] + 1e-5f);
        float wv = wtl[lc];
#pragma unroll
        for (int i = 0; i < 4; ++i) {
            float p = g * (acc[i] + bv - m) * rs + be;
            out[o_tanh + (size_t)(orow + i) * NBITS + lc] = tanhf(p);
            tl[i] += p * wv;
        }
    }
}

// fused HD + clas + conv(BN,tanh) + true_lab; X = h2 f32, packed WT rows 0..479
__global__ void __launch_bounds__(256) heads3_f32_kernel(
        const float* __restrict__ X,
        const u16* __restrict__ wh, const u16* __restrict__ wl,
        const float* __restrict__ bhd, const float* __restrict__ bclas,
        const float* __restrict__ bconv,
        const float* __restrict__ gamma, const float* __restrict__ beta,
        const float* __restrict__ rm, const float* __restrict__ rv,
        const float* __restrict__ wtl, const float* __restrict__ btl,
        float* __restrict__ out, size_t o_flab, size_t o_log, size_t o_tanh, size_t o_tl,
        const int* __restrict__ flag) {
    if (flag[0]) return;
    int wid = threadIdx.x >> 6, lane = threadIdx.x & 63;
    int r0 = blockIdx.x * 64 + wid * 16;
    if (r0 >= NN) return;
    int l15 = lane & 15;
    int koff = (lane >> 4) * 8;

    bf16x8 ah[4], al[4];
    const float* xp = X + (size_t)(r0 + l15) * FDIM + koff;
#pragma unroll
    for (int kf = 0; kf < 4; ++kf) splitA(xp + kf * 32, ah[kf], al[kf]);

    int orow = r0 + (lane >> 4) * 4;
    float tl[4] = {0.f, 0.f, 0.f, 0.f};

#pragma unroll
    for (int ct = 0; ct < 30; ct += 2) {
        f32x4 acc0 = {0.f, 0.f, 0.f, 0.f};
        f32x4 acc1 = {0.f, 0.f, 0.f, 0.f};
        const u16* p0h = wh + (size_t)(ct * 16 + l15) * FDIM + koff;
        const u16* p0l = wl + (size_t)(ct * 16 + l15) * FDIM + koff;
#pragma unroll
        for (int kf = 0; kf < 4; ++kf) {
            int o0 = kf * 32;
            int o1 = o0 + 16 * FDIM;
            bf16x8 b0h = *(const bf16x8*)(p0h + o0);
            bf16x8 b0l = *(const bf16x8*)(p0l + o0);
            bf16x8 b1h = *(const bf16x8*)(p0h + o1);
            bf16x8 b1l = *(const bf16x8*)(p0l + o1);
            acc0 = MFMA16(ah[kf], b0h, acc0);
            acc1 = MFMA16(ah[kf], b1h, acc1);
            acc0 = MFMA16(al[kf], b0h, acc0);
            acc1 = MFMA16(al[kf], b1h, acc1);
            acc0 = MFMA16(ah[kf], b0l, acc0);
            acc1 = MFMA16(ah[kf], b1l, acc1);
        }
        heads3_epi(ct,     l15, orow, acc0, bhd, bclas, bconv, gamma, beta, rm, rv,
                   wtl, out, o_flab, o_log, o_tanh, tl);
        heads3_epi(ct + 1, l15, orow, acc1, bhd, bclas, bconv, gamma, beta, rm, rv,
                   wtl, out, o_flab, o_log, o_tanh, tl);
    }

    // true_lab: reduce conv-column partials across the 16 lanes of each row group
    float bt = btl[0];
#pragma unroll
    for (int i = 0; i < 4; ++i) {
        float t = tl[i];
        t += __shfl_xor(t, 1);
        t += __shfl_xor(t, 2);
        t += __shfl_xor(t, 4);
        t += __shfl_xor(t, 8);
        if (l15 == 0) out[o_tl + orow + i] = t + bt;
    }
}

// fea_convert = tanh_out @ wcv + bcv; X = tanh f32 (from d_out), K=64
__global__ void __launch_bounds__(256) headcv_f32_kernel(
        const float* __restrict__ X,
        const u16* __restrict__ wh, const u16* __restrict__ wl,
        const float* __restrict__ bcv, float* __restrict__ out, size_t o_fcv,
        const int* __restrict__ flag) {
    if (flag[0]) return;
    int wid = threadIdx.x >> 6, lane = threadIdx.x & 63;
    int r0 = blockIdx.x * 64 + wid * 16;
    if (r0 >= NN) return;
    int l15 = lane & 15;
    int koff = (lane >> 4) * 8;

    bf16x8 ah[2], al[2];
    const float* xp = X + (size_t)(r0 + l15) * NBITS + koff;
#pragma unroll
    for (int kf = 0; kf < 2; ++kf) splitA(xp + kf * 32, ah[kf], al[kf]);

    int orow = r0 + (lane >> 4) * 4;
#pragma unroll
    for (int ct = 0; ct < 7; ++ct) {
        f32x4 acc = {0.f, 0.f, 0.f, 0.f};
        const u16* ph = wh + (size_t)(ct * 16 + l15) * NBITS + koff;
        const u16* pl = wl + (size_t)(ct * 16 + l15) * NBITS + koff;
#pragma unroll
        for (int kf = 0; kf < 2; ++kf) {
            int o0 = kf * 32;
            bf16x8 bh = *(const bf16x8*)(ph + o0);
            bf16x8 bl2 = *(const bf16x8*)(pl + o0);
            acc = MFMA16(ah[kf], bh, acc);
            acc = MFMA16(al[kf], bh, acc);
            acc = MFMA16(ah[kf], bl2, acc);
        }
        int oc = ct * 16 + l15;
        if (oc < NCLS) {
            float bv = bcv[oc];
#pragma unroll
            for (int i = 0; i < 4; ++i)
                out[o_fcv + (size_t)(orow + i) * NCLS + oc] = acc[i] + bv;
        }
    }
}

// ================= f32 vector fallback (only if workspace too small) ========
template <bool XBF, bool WBF>
__device__ __forceinline__ void sage_body(const float* aggm, const void* xv,
                                          const void* wl, const void* bl,
                                          const void* wr, float* hout) {
    __shared__ float ms[8][FDIM];
    __shared__ float xs[8][FDIM];
    int n0 = blockIdx.x * 8;
    int t = threadIdx.x;
    for (int idx = t; idx < 8 * FDIM; idx += 256) {
        int j = idx >> 7, k = idx & 127;
        int n = n0 + j;
        ms[j][k] = aggm[(size_t)n * FDIM + k];
        xs[j][k] = ldv<XBF>(xv, (size_t)n * FDIM + k);
    }
    __syncthreads();
    int f = t & 127;
    int h = t >> 7;
    float acc[4] = {0.f, 0.f, 0.f, 0.f};
    for (int k = 0; k < FDIM; ++k) {
        float wlv = ldv<WBF>(wl, k * FDIM + f);
        float wrv = ldv<WBF>(wr, k * FDIM + f);
#pragma unroll
        for (int j = 0; j < 4; ++j) {
            int nn = h + j * 2;
            acc[j] += ms[nn][k] * wlv + xs[nn][k] * wrv;
        }
    }
    float bv = ldv<WBF>(bl, f);
#pragma unroll
    for (int j = 0; j < 4; ++j) {
        int nn = h + j * 2;
        float v = acc[j] + bv;
        hout[(size_t)(n0 + nn) * FDIM + f] = v > 0.f ? v : 0.f;
    }
}

__global__ void __launch_bounds__(256) sage_f32_kernel(const float* aggm, const float* x,
                                                       const void* wl, const void* bl,
                                                       const void* wr, float* hout,
                                                       const int* flag) {
    if (flag[0]) return;
    sage_body<false, false>(aggm, x, wl, bl, wr, hout);
}

template <int KDIM, bool TANH_IN, bool BF>
__device__ __forceinline__ void head_body(const float* X, const void* W, const void* B,
                                          void* Y, size_t yoff, int fout,
                                          const void* gamma, const void* beta,
                                          const void* rm, const void* rv,
                                          float* pre_ws, int mode) {
    __shared__ float xs[16][KDIM];
    int n0 = blockIdx.x * 16;
    int t = threadIdx.x;
    for (int idx = t; idx < 16 * KDIM; idx += 256) {
        int j = idx / KDIM, k = idx % KDIM;
        float v = X[(size_t)(n0 + j) * KDIM + k];
        xs[j][k] = TANH_IN ? tanhf(v) : v;
    }
    __syncthreads();
    for (int f = t; f < fout; f += 256) {
        float acc[16];
#pragma unroll
        for (int j = 0; j < 16; ++j) acc[j] = 0.f;
        for (int k = 0; k < KDIM; ++k) {
            float wv = ldv<BF>(W, (size_t)k * fout + f);
#pragma unroll
            for (int j = 0; j < 16; ++j) acc[j] += xs[j][k] * wv;
        }
        float bv = ldv<BF>(B, f);
        if (mode == 0) {
#pragma unroll
            for (int j = 0; j < 16; ++j)
                stv<BF>(Y, yoff + (size_t)(n0 + j) * fout + f, acc[j] + bv);
        } else {
            float g  = ldv<BF>(gamma, f);
            float be = ldv<BF>(beta, f);
            float m  = ldv<BF>(rm, f);
            float rs = rsqrtf(ldv<BF>(rv, f) + 1e-5f);
#pragma unroll
            for (int j = 0; j < 16; ++j) {
                float p = g * (acc[j] + bv - m) * rs + be;
                pre_ws[(size_t)(n0 + j) * fout + f] = p;
                stv<BF>(Y, yoff + (size_t)(n0 + j) * fout + f, tanhf(p));
            }
        }
    }
}

template <int KDIM, bool TANH_IN>
__global__ void __launch_bounds__(256) head_f32_kernel(const float* X, const void* W,
                                                       const void* B, void* Y, size_t yoff,
                                                       int fout, const void* gamma,
                                                       const void* beta, const void* rm,
                                                       const void* rv, float* pre_ws,
                                                       int mode, const int* flag) {
    if (flag[0]) return;
    head_body<KDIM, TANH_IN, false>(X, W, B, Y, yoff, fout, gamma, beta, rm, rv, pre_ws, mode);
}

template <bool BF>
__device__ __forceinline__ void tl_body(const float* pre, const void* wtl,
                                        const void* btl, void* y, size_t yoff) {
    int i = blockIdx.x * 256 + threadIdx.x;
    if (i >= NN) return;
    float s = ldv<BF>(btl, 0);
#pragma unroll 8
    for (int k = 0; k < NBITS; ++k) s += pre[(size_t)i * NBITS + k] * ldv<BF>(wtl, k);
    stv<BF>(y, yoff + i, s);
}

__global__ void __launch_bounds__(256) true_lab_f32_kernel(const float* pre, const void* wtl,
                                                           const void* btl, void* y,
                                                           size_t yoff, const int* flag) {
    if (flag[0]) return;
    tl_body<false>(pre, wtl, btl, y, yoff);
}

// ================= bf16-input mode (flag=1) MFMA path =================
__global__ void __launch_bounds__(256) sage_mfma_kernel(
        const u16* __restrict__ agg, const u16* __restrict__ x,
        const u16* __restrict__ wtl, const u16* __restrict__ wtr,
        const void* __restrict__ bl, u16* __restrict__ hout,
        const int* __restrict__ flag) {
    if (!flag[0]) return;
    int wid = threadIdx.x >> 6, lane = threadIdx.x & 63;
    int r0 = blockIdx.x * 64 + wid * 16;
    if (r0 >= NN) return;
    int l15 = lane & 15;
    int koff = (lane >> 4) * 8;

    bf16x8 af[4], xf[4];
    const u16* ap = agg + (size_t)(r0 + l15) * FDIM + koff;
    const u16* xp = x   + (size_t)(r0 + l15) * FDIM + koff;
#pragma unroll
    for (int kf = 0; kf < 4; ++kf) {
        af[kf] = *(const bf16x8*)(ap + kf * 32);
        xf[kf] = *(const bf16x8*)(xp + kf * 32);
    }
    int orow = r0 + (lane >> 4) * 4;
    for (int ct = 0; ct < 8; ++ct) {
        int c0 = ct * 16;
        f32x4 acc = {0.f, 0.f, 0.f, 0.f};
        const u16* blp = wtl + (size_t)(c0 + l15) * FDIM + koff;
        const u16* brp = wtr + (size_t)(c0 + l15) * FDIM + koff;
#pragma unroll
        for (int kf = 0; kf < 4; ++kf) {
            bf16x8 bL = *(const bf16x8*)(blp + kf * 32);
            bf16x8 bR = *(const bf16x8*)(brp + kf * 32);
            acc = MFMA16(af[kf], bL, acc);
            acc = MFMA16(xf[kf], bR, acc);
        }
        int ocol = c0 + l15;
        float bv = us2f(((const u16*)bl)[ocol]);
#pragma unroll
        for (int i = 0; i < 4; ++i) {
            float v = acc[i] + bv;
            hout[(size_t)(orow + i) * FDIM + ocol] = f2bf(v > 0.f ? v : 0.f);
        }
    }
}

template <int K, int FP>
__global__ void __launch_bounds__(256) head_mfma_kernel(
        const u16* __restrict__ X, const u16* __restrict__ WT,
        const void* __restrict__ B, void* __restrict__ Y, size_t yoff,
        int fout, const int* __restrict__ flag) {
    if (!flag[0]) return;
    int wid = threadIdx.x >> 6, lane = threadIdx.x & 63;
    int r0 = blockIdx.x * 64 + wid * 16;
    if (r0 >= NN) return;
    int l15 = lane & 15;
    int koff = (lane >> 4) * 8;

    bf16x8 af[K / 32];
    const u16* xp = X + (size_t)(r0 + l15) * K + koff;
#pragma unroll
    for (int kf = 0; kf < K / 32; ++kf) af[kf] = *(const bf16x8*)(xp + kf * 32);

    u16* y = (u16*)Y + yoff;
    int orow = r0 + (lane >> 4) * 4;
    for (int ct = 0; ct < FP / 16; ++ct) {
        int c0 = ct * 16;
        f32x4 acc = {0.f, 0.f, 0.f, 0.f};
        const u16* bp = WT + (size_t)(c0 + l15) * K + koff;
#pragma unroll
        for (int kf = 0; kf < K / 32; ++kf) {
            bf16x8 bF = *(const bf16x8*)(bp + kf * 32);
            acc = MFMA16(af[kf], bF, acc);
        }
        int ocol = c0 + l15;
        if (ocol < fout) {
            float bv = us2f(((const u16*)B)[ocol]);
#pragma unroll
            for (int i = 0; i < 4; ++i)
                y[(size_t)(orow + i) * fout + ocol] = f2bf(acc[i] + bv);
        }
    }
}

__global__ void __launch_bounds__(256) headconv_mfma_kernel(
        const u16* __restrict__ X, const u16* __restrict__ WT,
        const void* __restrict__ B, const void* __restrict__ gamma,
        const void* __restrict__ beta, const void* __restrict__ rm,
        const void* __restrict__ rv, float* __restrict__ pre,
        void* __restrict__ Y, size_t yoff, const int* __restrict__ flag) {
    if (!flag[0]) return;
    int wid = threadIdx.x >> 6, lane = threadIdx.x & 63;
    int r0 = blockIdx.x * 64 + wid * 16;
    if (r0 >= NN) return;
    int l15 = lane & 15;
    int koff = (lane >> 4) * 8;

    bf16x8 af[4];
    const u16* xp = X + (size_t)(r0 + l15) * FDIM + koff;
#pragma unroll
    for (int kf = 0; kf < 4; ++kf) af[kf] = *(const bf16x8*)(xp + kf * 32);

    u16* y = (u16*)Y + yoff;
    int orow = r0 + (lane >> 4) * 4;
    for (int ct = 0; ct < 4; ++ct) {
        int c0 = ct * 16;
        f32x4 acc = {0.f, 0.f, 0.f, 0.f};
        const u16* bp = WT + (size_t)(c0 + l15) * FDIM + koff;
#pragma unroll
        for (int kf = 0; kf < 4; ++kf) {
            bf16x8 bF = *(const bf16x8*)(bp + kf * 32);
            acc = MFMA16(af[kf], bF, acc);
        }
        int ocol = c0 + l15;
        float bv = us2f(((const u16*)B)[ocol]);
        float g  = us2f(((const u16*)gamma)[ocol]);
        float be = us2f(((const u16*)beta)[ocol]);
        float m  = us2f(((const u16*)rm)[ocol]);
        float rs = rsqrtf(us2f(((const u16*)rv)[ocol]) + 1e-5f);
#pragma unroll
        for (int i = 0; i < 4; ++i) {
            float p = g * (acc[i] + bv - m) * rs + be;
            pre[(size_t)(orow + i) * NBITS + ocol] = p;
            y[(size_t)(orow + i) * NBITS + ocol] = f2bf(tanhf(p));
        }
    }
}

__global__ void __launch_bounds__(256) true_lab_b16_kernel(const float* pre, const void* wtl,
                                                           const void* btl, void* y,
                                                           size_t yoff, const int* flag) {
    if (!flag[0]) return;
    tl_body<true>(pre, wtl, btl, y, yoff);
}

extern "C" void kernel_launch(void* const* d_in, const int* in_sizes, int n_in,
                              void* d_out, int out_size, void* d_ws, size_t ws_size,
                              hipStream_t stream) {
    const void* feat = d_in[0];
    const int* edges = (const int*)d_in[1];
    const void* w1l = d_in[2];
    const void* b1l = d_in[3];
    const void* w1r = d_in[4];
    const void* w2l = d_in[5];
    const void* b2l = d_in[6];
    const void* w2r = d_in[7];
    const void* whd = d_in[8];
    const void* bhd = d_in[9];
    const void* wclas = d_in[10];
    const void* bclas = d_in[11];
    const void* wconv = d_in[12];
    const void* bconv = d_in[13];
    const void* gamma = d_in[14];
    const void* beta  = d_in[15];
    const void* rm  = d_in[16];
    const void* rv  = d_in[17];
    const void* wtl = d_in[18];
    const void* btl = d_in[19];
    const void* wcv = d_in[20];
    const void* bcv = d_in[21];

    // workspace:
    //   int: flag[16] | deg[50000] | cursor[50000] | rowptr[50016] | col[800000]
    //   f32: buf1[NN*128] | buf2[NN*128]
    //   u16: wtf_hi[WT_TOTAL] | wtf_lo[WT_TOTAL]   (f32-mode split weights, 536 KB)
    // bf16-mode overlays: aggb+hb1 over buf1, hb2+pre_b over buf2, WT over deg+cursor
    int* iw     = (int*)d_ws;
    int* flag   = iw;
    int* deg    = iw + 16;
    int* cursor = deg + NN;
    int* rowptr = cursor + NN;
    int* col    = rowptr + 50016;
    float* buf1 = (float*)(col + NE);
    float* buf2 = buf1 + (size_t)NN * FDIM;
    float* pre_f = buf1;                       // fallback path only

    u16* wtf_hi = (u16*)(buf2 + (size_t)NN * FDIM);
    u16* wtf_lo = wtf_hi + WT_TOTAL;
    size_t need = (size_t)(16 + NN + NN + 50016 + NE) * 4
                + 2 * (size_t)NN * FDIM * 4
                + 2 * (size_t)WT_TOTAL * 2;
    bool mfma_ok = ws_size >= need;

    u16* aggb = (u16*)buf1;
    u16* hb1  = aggb + (size_t)NN * FDIM;
    u16* hb2  = (u16*)buf2;
    float* pre_b = buf2 + (size_t)NN * 64;

    u16* wt = (u16*)deg;   // bf16-mode packed WT (268 KB < 400 KB deg+cursor)

    const int* src = edges;
    const int* dst = edges + NE;

    hipMemsetAsync(iw, 0, (size_t)(16 + 2 * NN) * sizeof(int), stream);

    detect_kernel<<<1, 256, 0, stream>>>((const unsigned short*)feat, flag);

    // CSR build
    deg_kernel<<<(NE + 255) / 256, 256, 0, stream>>>(dst, deg);
    scan_kernel<<<1, 1024, 0, stream>>>(deg, rowptr);
    fill_kernel<<<(NE + 255) / 256, 256, 0, stream>>>(src, dst, rowptr, cursor, col);

    // output element offsets: logists | tanh_out | fea_lab | fea_convert | true_lab
    size_t o_log  = 0;
    size_t o_tanh = (size_t)NN * NCLS;
    size_t o_flab = o_tanh + (size_t)NN * NBITS;
    size_t o_fcv  = o_flab + (size_t)NN * HD;
    size_t o_tl   = o_fcv + (size_t)NN * NCLS;

    const int GR = (NN + 63) / 64;   // 782 blocks, 4 waves x 16 rows

    // ---------------- bf16-input MFMA path (flag=1) ----------------
    tr_all_kernel<<<(WT_TOTAL + 255) / 256, 256, 0, stream>>>(
        w1l, w1r, w2l, w2r, whd, wclas, wconv, wcv, wt, flag);
    aggb_kernel<<<NN / 4, 256, 0, stream>>>((const u16*)feat, rowptr, col, aggb, flag);
    sage_mfma_kernel<<<GR, 256, 0, stream>>>(aggb, (const u16*)feat, wt + WT_1L, wt + WT_1R, b1l, hb1, flag);
    aggb_kernel<<<NN / 4, 256, 0, stream>>>(hb1, rowptr, col, aggb, flag);
    sage_mfma_kernel<<<GR, 256, 0, stream>>>(aggb, hb1, wt + WT_2L, wt + WT_2R, b2l, hb2, flag);
    head_mfma_kernel<128, 304><<<GR, 256, 0, stream>>>(hb2, wt + WT_HD, bhd, d_out, o_flab, HD, flag);
    head_mfma_kernel<128, 112><<<GR, 256, 0, stream>>>(hb2, wt + WT_CLS, bclas, d_out, o_log, NCLS, flag);
    headconv_mfma_kernel<<<GR, 256, 0, stream>>>(hb2, wt + WT_CONV, bconv, gamma, beta, rm, rv,
                                                 pre_b, d_out, o_tanh, flag);
    head_mfma_kernel<64, 112><<<GR, 256, 0, stream>>>((const u16*)d_out + o_tanh, wt + WT_CV, bcv,
                                                      d_out, o_fcv, NCLS, flag);
    true_lab_b16_kernel<<<(NN + 255) / 256, 256, 0, stream>>>(pre_b, wtl, btl, d_out, o_tl, flag);

    // ---------------- f32-input path (flag=0) ----------------
    if (mfma_ok) {
        tr_f32_kernel<<<(WT_TOTAL + 255) / 256, 256, 0, stream>>>(
            (const float*)w1l, (const float*)w1r, (const float*)w2l, (const float*)w2r,
            (const float*)whd, (const float*)wclas, (const float*)wconv, (const float*)wcv,
            wtf_hi, wtf_lo, flag);

        agg_f32_kernel<<<NN / 4, 256, 0, stream>>>((const float*)feat, rowptr, col, buf1, flag);
        sage_mfma_f32_kernel<<<GR, 256, 0, stream>>>(
            buf1, (const float*)feat,
            wtf_hi + WT_1L, wtf_lo + WT_1L, wtf_hi + WT_1R, wtf_lo + WT_1R,
            (const float*)b1l, buf1, flag);
        agg_f32_kernel<<<NN / 4, 256, 0, stream>>>(buf1, rowptr, col, buf2, flag);
        sage_mfma_f32_kernel<<<GR, 256, 0, stream>>>(
            buf2, buf1,
            wtf_hi + WT_2L, wtf_lo + WT_2L, wtf_hi + WT_2R, wtf_lo + WT_2R,
            (const float*)b2l, buf2, flag);

        heads3_f32_kernel<<<GR, 256, 0, stream>>>(
            buf2, wtf_hi + WT_HD, wtf_lo + WT_HD,
            (const float*)bhd, (const float*)bclas, (const float*)bconv,
            (const float*)gamma, (const float*)beta, (const float*)rm, (const float*)rv,
            (const float*)wtl, (const float*)btl,
            (float*)d_out, o_flab, o_log, o_tanh, o_tl, flag);
        headcv_f32_kernel<<<GR, 256, 0, stream>>>(
            (const float*)d_out + o_tanh, wtf_hi + WT_CV, wtf_lo + WT_CV,
            (const float*)bcv, (float*)d_out, o_fcv, flag);
    } else {
        // fallback: original vector path (workspace too small for split weights)
        agg_f32_kernel<<<NN / 4, 256, 0, stream>>>((const float*)feat, rowptr, col, buf1, flag);
        sage_f32_kernel<<<NN / 8, 256, 0, stream>>>(buf1, (const float*)feat, w1l, b1l, w1r, buf1, flag);
        agg_f32_kernel<<<NN / 4, 256, 0, stream>>>(buf1, rowptr, col, buf2, flag);
        sage_f32_kernel<<<NN / 8, 256, 0, stream>>>(buf2, buf1, w2l, b2l, w2r, buf2, flag);

        head_f32_kernel<FDIM, false><<<NN / 16, 256, 0, stream>>>(
            buf2, whd, bhd, d_out, o_flab, HD,
            nullptr, nullptr, nullptr, nullptr, nullptr, 0, flag);
        head_f32_kernel<FDIM, false><<<NN / 16, 256, 0, stream>>>(
            buf2, wclas, bclas, d_out, o_log, NCLS,
            nullptr, nullptr, nullptr, nullptr, nullptr, 0, flag);
        head_f32_kernel<FDIM, false><<<NN / 16, 256, 0, stream>>>(
            buf2, wconv, bconv, d_out, o_tanh, NBITS,
            gamma, beta, rm, rv, pre_f, 1, flag);
        head_f32_kernel<NBITS, true><<<NN / 16, 256, 0, stream>>>(
            pre_f, wcv, bcv, d_out, o_fcv, NCLS,
            nullptr, nullptr, nullptr, nullptr, nullptr, 0, flag);
        true_lab_f32_kernel<<<(NN + 255) / 256, 256, 0, stream>>>(pre_f, wtl, btl, d_out, o_tl, flag);
    }
}

// Round 5
// 704.652 us; speedup vs baseline: 1.4243x; 1.0836x over previous
//
#include <hip/hip_runtime.h>
#include <hip/hip_bf16.h>
#include <math.h>

#define NN 50000
#define NE 800000
#define FDIM 128
#define NBITS 64
#define NCLS 100
#define HD 300

typedef unsigned short u16;
typedef __attribute__((ext_vector_type(8))) short bf16x8;
typedef __attribute__((ext_vector_type(4))) float f32x4;

#define MFMA16(a, b, c) __builtin_amdgcn_mfma_f32_16x16x32_bf16((a), (b), (c), 0, 0, 0)

__device__ __forceinline__ float us2f(unsigned short u) {
    union { unsigned int i; float f; } x; x.i = ((unsigned int)u) << 16; return x.f;
}
__device__ __forceinline__ unsigned short f2bf(float f) {
    union { float f; unsigned int i; } x; x.f = f;
    unsigned int i = x.i;
    i += 0x7fffu + ((i >> 16) & 1u);   // round-to-nearest-even
    return (unsigned short)(i >> 16);
}
__device__ __forceinline__ unsigned short f2bf_trunc(float f) {
    union { float f; unsigned int i; } x; x.f = f;
    return (unsigned short)(x.i >> 16);   // round-toward-zero
}

template <bool BF>
__device__ __forceinline__ float ldv(const void* p, size_t i) {
    return BF ? us2f(((const unsigned short*)p)[i]) : ((const float*)p)[i];
}
template <bool BF>
__device__ __forceinline__ void stv(void* p, size_t i, float v) {
    if (BF) ((unsigned short*)p)[i] = f2bf(v);
    else    ((float*)p)[i] = v;
}

// split 8 contiguous f32 into bf16 hi (trunc) + lo (RNE of residual)
__device__ __forceinline__ void splitA(const float* p, bf16x8& hi, bf16x8& lo) {
    float4 a = *(const float4*)p;
    float4 b = *(const float4*)(p + 4);
    float v[8] = {a.x, a.y, a.z, a.w, b.x, b.y, b.z, b.w};
#pragma unroll
    for (int j = 0; j < 8; ++j) {
        u16 h = f2bf_trunc(v[j]);
        float r = v[j] - us2f(h);
        hi[j] = (short)h;
        lo[j] = (short)f2bf(r);
    }
}

// ---------------- dtype detection (flag=1 => bf16 buffers) ----------------
__global__ void __launch_bounds__(256) detect_kernel(const unsigned short* __restrict__ f,
                                                     int* __restrict__ flag) {
    __shared__ int bad;
    if (threadIdx.x == 0) bad = 0;
    __syncthreads();
    int b = 0;
    for (int i = threadIdx.x; i < 4096; i += 256) {
        float v = us2f(f[i]);
        if (!(fabsf(v) < 1e4f)) b = 1;   // catches NaN too
    }
    if (b) atomicOr(&bad, 1);
    __syncthreads();
    if (threadIdx.x == 0) flag[0] = bad ? 0 : 1;
}

// ---------------- CSR build ----------------
__global__ void __launch_bounds__(256) deg_kernel(const int* __restrict__ dst,
                                                  int* __restrict__ deg) {
    int e = blockIdx.x * 256 + threadIdx.x;
    if (e < NE) atomicAdd(&deg[dst[e]], 1);
}

__global__ void __launch_bounds__(1024) scan_kernel(const int* __restrict__ deg,
                                                    int* __restrict__ rowptr) {
    __shared__ int wsum[16];
    __shared__ int carry_sh;
    int t = threadIdx.x;
    int lane = t & 63;
    int w = t >> 6;
    if (t == 0) carry_sh = 0;
    __syncthreads();
    for (int base = 0; base < NN; base += 1024) {
        int i = base + t;
        int v = (i < NN) ? deg[i] : 0;
        int x = v;
#pragma unroll
        for (int off = 1; off < 64; off <<= 1) {
            int u = __shfl_up(x, off);
            if (lane >= off) x += u;
        }
        if (lane == 63) wsum[w] = x;
        __syncthreads();
        if (w == 0) {
            int y = (lane < 16) ? wsum[lane] : 0;
#pragma unroll
            for (int off = 1; off < 16; off <<= 1) {
                int u = __shfl_up(y, off);
                if (lane >= off) y += u;
            }
            if (lane < 16) wsum[lane] = y;
        }
        __syncthreads();
        int woff = (w > 0) ? wsum[w - 1] : 0;
        int incl = x + woff;
        int carry = carry_sh;
        if (i < NN) rowptr[i] = carry + incl - v;   // exclusive
        __syncthreads();
        if (t == 1023) carry_sh = carry + incl;
        __syncthreads();
    }
    if (t == 0) rowptr[NN] = carry_sh;
}

__global__ void __launch_bounds__(256) fill_kernel(const int* __restrict__ src,
                                                   const int* __restrict__ dst,
                                                   const int* __restrict__ rowptr,
                                                   int* __restrict__ cursor,
                                                   int* __restrict__ col) {
    int e = blockIdx.x * 256 + threadIdx.x;
    if (e >= NE) return;
    int d = dst[e];
    int p = atomicAdd(&cursor[d], 1);
    col[rowptr[d] + p] = src[e];
}

// ---------------- weight transpose/pack layout ----------------
#define WT_1L   0
#define WT_1R   16384
#define WT_2L   32768
#define WT_2R   49152
#define WT_HD   65536
#define WT_CLS  104448
#define WT_CONV 118784
#define WT_CV   126976
#define WT_TOTAL 134144

// bf16-input mode: single packed WT (overlays deg+cursor)
__global__ void __launch_bounds__(256) tr_all_kernel(
        const void* w1l, const void* w1r, const void* w2l, const void* w2r,
        const void* whd, const void* wclas, const void* wconv, const void* wcv,
        u16* __restrict__ wt, const int* __restrict__ flag) {
    if (!flag[0]) return;
    int idx = blockIdx.x * 256 + threadIdx.x;
    if (idx >= WT_TOTAL) return;
    const u16* src; int K, F, d;
    if      (idx < WT_1R)  { src = (const u16*)w1l;   K = 128; F = 128; d = idx - WT_1L; }
    else if (idx < WT_2L)  { src = (const u16*)w1r;   K = 128; F = 128; d = idx - WT_1R; }
    else if (idx < WT_2R)  { src = (const u16*)w2l;   K = 128; F = 128; d = idx - WT_2L; }
    else if (idx < WT_HD)  { src = (const u16*)w2r;   K = 128; F = 128; d = idx - WT_2R; }
    else if (idx < WT_CLS) { src = (const u16*)whd;   K = 128; F = 300; d = idx - WT_HD; }
    else if (idx < WT_CONV){ src = (const u16*)wclas; K = 128; F = 100; d = idx - WT_CLS; }
    else if (idx < WT_CV)  { src = (const u16*)wconv; K = 128; F = 64;  d = idx - WT_CONV; }
    else                   { src = (const u16*)wcv;   K = 64;  F = 100; d = idx - WT_CV; }
    int lgK = (K == 64) ? 6 : 7;
    int f = d >> lgK;
    int k = d & (K - 1);
    wt[idx] = (f < F) ? src[k * F + f] : (u16)0;
}

// f32-input mode: transposed hi/lo split weights
// ROUND-5 FIX: wconv branch base was WT_CV (typo introduced r3) -> WT_CONV.
__global__ void __launch_bounds__(256) tr_f32_kernel(
        const float* w1l, const float* w1r, const float* w2l, const float* w2r,
        const float* whd, const float* wclas, const float* wconv, const float* wcv,
        u16* __restrict__ wth, u16* __restrict__ wtlo, const int* __restrict__ flag) {
    if (flag[0]) return;
    int idx = blockIdx.x * 256 + threadIdx.x;
    if (idx >= WT_TOTAL) return;
    const float* src; int K, F, d;
    if      (idx < WT_1R)  { src = w1l;   K = 128; F = 128; d = idx - WT_1L; }
    else if (idx < WT_2L)  { src = w1r;   K = 128; F = 128; d = idx - WT_1R; }
    else if (idx < WT_2R)  { src = w2l;   K = 128; F = 128; d = idx - WT_2L; }
    else if (idx < WT_HD)  { src = w2r;   K = 128; F = 128; d = idx - WT_2R; }
    else if (idx < WT_CLS) { src = whd;   K = 128; F = 300; d = idx - WT_HD; }
    else if (idx < WT_CONV){ src = wclas; K = 128; F = 100; d = idx - WT_CLS; }
    else if (idx < WT_CV)  { src = wconv; K = 128; F = 64;  d = idx - WT_CONV; }
    else                   { src = wcv;   K = 64;  F = 100; d = idx - WT_CV; }
    int lgK = (K == 64) ? 6 : 7;
    int f = d >> lgK;
    int k = d & (K - 1);
    float v = (f < F) ? src[k * F + f] : 0.f;
    u16 h = f2bf_trunc(v);
    wth[idx]  = h;
    wtlo[idx] = f2bf(v - us2f(h));
}

// ---------------- gather aggregation ----------------
// f32 mode: 2 neighbors/iter (half-wave each), float4 per lane  [validated r3]
__global__ void __launch_bounds__(256) agg_f32_kernel(const float* __restrict__ x,
                                                      const int* __restrict__ rowptr,
                                                      const int* __restrict__ col,
                                                      float* __restrict__ aggm,
                                                      const int* __restrict__ flag) {
    if (flag[0]) return;
    int node = blockIdx.x * 4 + (threadIdx.x >> 6);
    int lane = threadIdx.x & 63;
    int half = lane >> 5;
    int c0 = (lane & 31) * 4;
    int beg = rowptr[node], end = rowptr[node + 1];
    float a0 = 0.f, a1 = 0.f, a2 = 0.f, a3 = 0.f;
    int j = beg;
    for (; j + 2 <= end; j += 2) {
        int nbr = col[j + half];
        float4 u = *(const float4*)(x + (size_t)nbr * FDIM + c0);
        a0 += u.x; a1 += u.y; a2 += u.z; a3 += u.w;
    }
    if (j < end && half == 0) {
        int nbr = col[j];
        float4 u = *(const float4*)(x + (size_t)nbr * FDIM + c0);
        a0 += u.x; a1 += u.y; a2 += u.z; a3 += u.w;
    }
    a0 += __shfl_xor(a0, 32);
    a1 += __shfl_xor(a1, 32);
    a2 += __shfl_xor(a2, 32);
    a3 += __shfl_xor(a3, 32);
    if (half == 0) {
        float inv = 1.f / fmaxf((float)(end - beg), 1.f);
        float4 o; o.x = a0 * inv; o.y = a1 * inv; o.z = a2 * inv; o.w = a3 * inv;
        *(float4*)(aggm + (size_t)node * FDIM + c0) = o;
    }
}

// bf16 mode gather: bf16 in -> mean (f32 accum) -> bf16 out
__global__ void __launch_bounds__(256) aggb_kernel(const u16* __restrict__ xv,
                                                   const int* __restrict__ rowptr,
                                                   const int* __restrict__ col,
                                                   u16* __restrict__ aggm,
                                                   const int* __restrict__ flag) {
    if (!flag[0]) return;
    int node = blockIdx.x * 4 + (threadIdx.x >> 6);
    int lane = threadIdx.x & 63;
    int beg = rowptr[node], end = rowptr[node + 1];
    float a0 = 0.f, a1 = 0.f;
    for (int j = beg; j < end; ++j) {
        int nbr = col[j];
        ushort2 u = *(const ushort2*)(xv + (size_t)nbr * FDIM + lane * 2);
        a0 += us2f(u.x); a1 += us2f(u.y);
    }
    float inv = 1.f / fmaxf((float)(end - beg), 1.f);
    ushort2 o; o.x = f2bf(a0 * inv); o.y = f2bf(a1 * inv);
    *(ushort2*)(aggm + (size_t)node * FDIM + lane * 2) = o;
}

// ================= f32-input mode: split-bf16 MFMA path =================

// h = relu(agg@Wl + x@Wr + b). 16 rows/block, waves split col-tiles.
// In-place safe: barrier after A-loads; blocks own disjoint rows. [validated r3]
__global__ void __launch_bounds__(256) sage_mfma_f32_kernel(
        const float* __restrict__ agg, const float* __restrict__ x,
        const u16* __restrict__ wlh, const u16* __restrict__ wll,
        const u16* __restrict__ wrh, const u16* __restrict__ wrl,
        const float* __restrict__ bl, float* __restrict__ hout,
        const int* __restrict__ flag) {
    if (flag[0]) return;
    int wid = threadIdx.x >> 6, lane = threadIdx.x & 63;
    int r0 = blockIdx.x * 16;
    int l15 = lane & 15;
    int koff = (lane >> 4) * 8;

    bf16x8 ah[4], al[4], xh[4], xl[4];
    const float* ap = agg + (size_t)(r0 + l15) * FDIM + koff;
    const float* xp = x   + (size_t)(r0 + l15) * FDIM + koff;
#pragma unroll
    for (int kf = 0; kf < 4; ++kf) {
        splitA(ap + kf * 32, ah[kf], al[kf]);
        splitA(xp + kf * 32, xh[kf], xl[kf]);
    }
    __syncthreads();   // all reads of this block's rows precede in-place writes
    int orow = r0 + (lane >> 4) * 4;
#pragma unroll
    for (int tt = 0; tt < 2; ++tt) {
        int ct = wid * 2 + tt;
        f32x4 acc = {0.f, 0.f, 0.f, 0.f};
        const u16* pLh = wlh + (size_t)(ct * 16 + l15) * FDIM + koff;
        const u16* pLl = wll + (size_t)(ct * 16 + l15) * FDIM + koff;
        const u16* pRh = wrh + (size_t)(ct * 16 + l15) * FDIM + koff;
        const u16* pRl = wrl + (size_t)(ct * 16 + l15) * FDIM + koff;
#pragma unroll
        for (int kf = 0; kf < 4; ++kf) {
            int o0 = kf * 32;
            bf16x8 bLh = *(const bf16x8*)(pLh + o0);
            bf16x8 bLl = *(const bf16x8*)(pLl + o0);
            bf16x8 bRh = *(const bf16x8*)(pRh + o0);
            bf16x8 bRl = *(const bf16x8*)(pRl + o0);
            acc = MFMA16(ah[kf], bLh, acc);
            acc = MFMA16(al[kf], bLh, acc);
            acc = MFMA16(ah[kf], bLl, acc);
            acc = MFMA16(xh[kf], bRh, acc);
            acc = MFMA16(xl[kf], bRh, acc);
            acc = MFMA16(xh[kf], bRl, acc);
        }
        int oc = ct * 16 + l15;
        float bv = bl[oc];
#pragma unroll
        for (int i = 0; i < 4; ++i) {
            float v = acc[i] + bv;
            hout[(size_t)(orow + i) * FDIM + oc] = v > 0.f ? v : 0.f;
        }
    }
}

// epilogue for the fused 3-head kernel: global col-tile ct in [0,30)
// cols 0..303 -> fea_lab (HD) | 304..415 -> logists (NCLS) | 416..479 -> conv+BN+tanh
__device__ __forceinline__ void heads3_epi(int ct, int l15, int orow, const f32x4& acc,
        const float* bhd, const float* bclas, const float* bconv,
        const float* gamma, const float* beta, const float* rm, const float* rv,
        const float* wtl, float* out, size_t o_flab, size_t o_log, size_t o_tanh,
        float* tl) {
    int gcol = ct * 16 + l15;
    if (gcol < 304) {
        if (gcol < 300) {
            float bv = bhd[gcol];
#pragma unroll
            for (int i = 0; i < 4; ++i)
                out[o_flab + (size_t)(orow + i) * HD + gcol] = acc[i] + bv;
        }
    } else if (gcol < 416) {
        int lc = gcol - 304;
        if (lc < NCLS) {
            float bv = bclas[lc];
#pragma unroll
            for (int i = 0; i < 4; ++i)
                out[o_log + (size_t)(orow + i) * NCLS + lc] = acc[i] + bv;
        }
    } else {
        int lc = gcol - 416;
        float bv = bconv[lc];
        float g  = gamma[lc];
        float be = beta[lc];
        float m  = rm[lc];
        float rs = rsqrtf(rv[lc] + 1e-5f);
        float wv = wtl[lc];
#pragma unroll
        for (int i = 0; i < 4; ++i) {
            float p = g * (acc[i] + bv - m) * rs + be;
            out[o_tanh + (size_t)(orow + i) * NBITS + lc] = tanhf(p);
            tl[i] += p * wv;
        }
    }
}

// round-2-verbatim tile-pair loop over [T0, T0+10), compile-time bounds.
template <int T0, bool DO_TL>
__device__ __forceinline__ void heads3_tiles(
        const bf16x8* ah, const bf16x8* al, int l15, int koff, int orow, int lane,
        const u16* wh, const u16* wl,
        const float* bhd, const float* bclas, const float* bconv,
        const float* gamma, const float* beta, const float* rm, const float* rv,
        const float* wtl, const float* btl,
        float* out, size_t o_flab, size_t o_log, size_t o_tanh, size_t o_tl) {
    float tl[4] = {0.f, 0.f, 0.f, 0.f};
#pragma unroll
    for (int tt = 0; tt < 10; tt += 2) {
        int ct = T0 + tt;
        f32x4 acc0 = {0.f, 0.f, 0.f, 0.f};
        f32x4 acc1 = {0.f, 0.f, 0.f, 0.f};
        const u16* p0h = wh + (size_t)(ct * 16 + l15) * FDIM + koff;
        const u16* p0l = wl + (size_t)(ct * 16 + l15) * FDIM + koff;
#pragma unroll
        for (int kf = 0; kf < 4; ++kf) {
            int o0 = kf * 32;
            int o1 = o0 + 16 * FDIM;
            bf16x8 b0h = *(const bf16x8*)(p0h + o0);
            bf16x8 b0l = *(const bf16x8*)(p0l + o0);
            bf16x8 b1h = *(const bf16x8*)(p0h + o1);
            bf16x8 b1l = *(const bf16x8*)(p0l + o1);
            acc0 = MFMA16(ah[kf], b0h, acc0);
            acc1 = MFMA16(ah[kf], b1h, acc1);
            acc0 = MFMA16(al[kf], b0h, acc0);
            acc1 = MFMA16(al[kf], b1h, acc1);
            acc0 = MFMA16(ah[kf], b0l, acc0);
            acc1 = MFMA16(ah[kf], b1l, acc1);
        }
        heads3_epi(ct,     l15, orow, acc0, bhd, bclas, bconv, gamma, beta, rm, rv,
                   wtl, out, o_flab, o_log, o_tanh, tl);
        heads3_epi(ct + 1, l15, orow, acc1, bhd, bclas, bconv, gamma, beta, rm, rv,
                   wtl, out, o_flab, o_log, o_tanh, tl);
    }
    if (DO_TL) {   // conv tiles (26-29) all live in the T0=20 part
        float bt = btl[0];
#pragma unroll
        for (int i = 0; i < 4; ++i) {
            float t = tl[i];
            t += __shfl_xor(t, 1);
            t += __shfl_xor(t, 2);
            t += __shfl_xor(t, 4);
            t += __shfl_xor(t, 8);
            if (l15 == 0) out[o_tl + orow + i] = t + bt;
        }
    }
}

// fused HD + clas + conv(BN,tanh) + true_lab. Round-2 wave body; columns
// split 3-way across blockIdx.y for occupancy. Grid (ceil(NN/64), 3).
__global__ void __launch_bounds__(256) heads3_f32_kernel(
        const float* __restrict__ X,
        const u16* __restrict__ wh, const u16* __restrict__ wl,
        const float* __restrict__ bhd, const float* __restrict__ bclas,
        const float* __restrict__ bconv,
        const float* __restrict__ gamma, const float* __restrict__ beta,
        const float* __restrict__ rm, const float* __restrict__ rv,
        const float* __restrict__ wtl, const float* __restrict__ btl,
        float* __restrict__ out, size_t o_flab, size_t o_log, size_t o_tanh, size_t o_tl,
        const int* __restrict__ flag) {
    if (flag[0]) return;
    int wid = threadIdx.x >> 6, lane = threadIdx.x & 63;
    int r0 = blockIdx.x * 64 + wid * 16;
    if (r0 >= NN) return;
    int l15 = lane & 15;
    int koff = (lane >> 4) * 8;

    bf16x8 ah[4], al[4];
    const float* xp = X + (size_t)(r0 + l15) * FDIM + koff;
#pragma unroll
    for (int kf = 0; kf < 4; ++kf) splitA(xp + kf * 32, ah[kf], al[kf]);

    int orow = r0 + (lane >> 4) * 4;

    if (blockIdx.y == 0) {
        heads3_tiles<0, false>(ah, al, l15, koff, orow, lane, wh, wl, bhd, bclas, bconv,
                               gamma, beta, rm, rv, wtl, btl, out, o_flab, o_log, o_tanh, o_tl);
    } else if (blockIdx.y == 1) {
        heads3_tiles<10, false>(ah, al, l15, koff, orow, lane, wh, wl, bhd, bclas, bconv,
                                gamma, beta, rm, rv, wtl, btl, out, o_flab, o_log, o_tanh, o_tl);
    } else {
        heads3_tiles<20, true>(ah, al, l15, koff, orow, lane, wh, wl, bhd, bclas, bconv,
                               gamma, beta, rm, rv, wtl, btl, out, o_flab, o_log, o_tanh, o_tl);
    }
}

// fea_convert = tanh_out @ wcv + bcv; X = tanh f32 (from d_out), K=64
// round-2 version (wave owns rows, all 7 tiles)
__global__ void __launch_bounds__(256) headcv_f32_kernel(
        const float* __restrict__ X,
        const u16* __restrict__ wh, const u16* __restrict__ wl,
        const float* __restrict__ bcv, float* __restrict__ out, size_t o_fcv,
        const int* __restrict__ flag) {
    if (flag[0]) return;
    int wid = threadIdx.x >> 6, lane = threadIdx.x & 63;
    int r0 = blockIdx.x * 64 + wid * 16;
    if (r0 >= NN) return;
    int l15 = lane & 15;
    int koff = (lane >> 4) * 8;

    bf16x8 ah[2], al[2];
    const float* xp = X + (size_t)(r0 + l15) * NBITS + koff;
#pragma unroll
    for (int kf = 0; kf < 2; ++kf) splitA(xp + kf * 32, ah[kf], al[kf]);

    int orow = r0 + (lane >> 4) * 4;
#pragma unroll
    for (int ct = 0; ct < 7; ++ct) {
        f32x4 acc = {0.f, 0.f, 0.f, 0.f};
        const u16* ph = wh + (size_t)(ct * 16 + l15) * NBITS + koff;
        const u16* pl = wl + (size_t)(ct * 16 + l15) * NBITS + koff;
#pragma unroll
        for (int kf = 0; kf < 2; ++kf) {
            int o0 = kf * 32;
            bf16x8 bh = *(const bf16x8*)(ph + o0);
            bf16x8 bl2 = *(const bf16x8*)(pl + o0);
            acc = MFMA16(ah[kf], bh, acc);
            acc = MFMA16(al[kf], bh, acc);
            acc = MFMA16(ah[kf], bl2, acc);
        }
        int oc = ct * 16 + l15;
        if (oc < NCLS) {
            float bv = bcv[oc];
#pragma unroll
            for (int i = 0; i < 4; ++i)
                out[o_fcv + (size_t)(orow + i) * NCLS + oc] = acc[i] + bv;
        }
    }
}

// ================= f32 vector fallback (only if workspace too small) ========
template <bool XBF, bool WBF>
__device__ __forceinline__ void sage_body(const float* aggm, const void* xv,
                                          const void* wl, const void* bl,
                                          const void* wr, float* hout) {
    __shared__ float ms[8][FDIM];
    __shared__ float xs[8][FDIM];
    int n0 = blockIdx.x * 8;
    int t = threadIdx.x;
    for (int idx = t; idx < 8 * FDIM; idx += 256) {
        int j = idx >> 7, k = idx & 127;
        int n = n0 + j;
        ms[j][k] = aggm[(size_t)n * FDIM + k];
        xs[j][k] = ldv<XBF>(xv, (size_t)n * FDIM + k);
    }
    __syncthreads();
    int f = t & 127;
    int h = t >> 7;
    float acc[4] = {0.f, 0.f, 0.f, 0.f};
    for (int k = 0; k < FDIM; ++k) {
        float wlv = ldv<WBF>(wl, k * FDIM + f);
        float wrv = ldv<WBF>(wr, k * FDIM + f);
#pragma unroll
        for (int j = 0; j < 4; ++j) {
            int nn = h + j * 2;
            acc[j] += ms[nn][k] * wlv + xs[nn][k] * wrv;
        }
    }
    float bv = ldv<WBF>(bl, f);
#pragma unroll
    for (int j = 0; j < 4; ++j) {
        int nn = h + j * 2;
        float v = acc[j] + bv;
        hout[(size_t)(n0 + nn) * FDIM + f] = v > 0.f ? v : 0.f;
    }
}

__global__ void __launch_bounds__(256) sage_f32_kernel(const float* aggm, const float* x,
                                                       const void* wl, const void* bl,
                                                       const void* wr, float* hout,
                                                       const int* flag) {
    if (flag[0]) return;
    sage_body<false, false>(aggm, x, wl, bl, wr, hout);
}

template <int KDIM, bool TANH_IN, bool BF>
__device__ __forceinline__ void head_body(const float* X, const void* W, const void* B,
                                          void* Y, size_t yoff, int fout,
                                          const void* gamma, const void* beta,
                                          const void* rm, const void* rv,
                                          float* pre_ws, int mode) {
    __shared__ float xs[16][KDIM];
    int n0 = blockIdx.x * 16;
    int t = threadIdx.x;
    for (int idx = t; idx < 16 * KDIM; idx += 256) {
        int j = idx / KDIM, k = idx % KDIM;
        float v = X[(size_t)(n0 + j) * KDIM + k];
        xs[j][k] = TANH_IN ? tanhf(v) : v;
    }
    __syncthreads();
    for (int f = t; f < fout; f += 256) {
        float acc[16];
#pragma unroll
        for (int j = 0; j < 16; ++j) acc[j] = 0.f;
        for (int k = 0; k < KDIM; ++k) {
            float wv = ldv<BF>(W, (size_t)k * fout + f);
#pragma unroll
            for (int j = 0; j < 16; ++j) acc[j] += xs[j][k] * wv;
        }
        float bv = ldv<BF>(B, f);
        if (mode == 0) {
#pragma unroll
            for (int j = 0; j < 16; ++j)
                stv<BF>(Y, yoff + (size_t)(n0 + j) * fout + f, acc[j] + bv);
        } else {
            float g  = ldv<BF>(gamma, f);
            float be = ldv<BF>(beta, f);
            float m  = ldv<BF>(rm, f);
            float rs = rsqrtf(ldv<BF>(rv, f) + 1e-5f);
#pragma unroll
            for (int j = 0; j < 16; ++j) {
                float p = g * (acc[j] + bv - m) * rs + be;
                pre_ws[(size_t)(n0 + j) * fout + f] = p;
                stv<BF>(Y, yoff + (size_t)(n0 + j) * fout + f, tanhf(p));
            }
        }
    }
}

template <int KDIM, bool TANH_IN>
__global__ void __launch_bounds__(256) head_f32_kernel(const float* X, const void* W,
                                                       const void* B, void* Y, size_t yoff,
                                                       int fout, const void* gamma,
                                                       const void* beta, const void* rm,
                                                       const void* rv, float* pre_ws,
                                                       int mode, const int* flag) {
    if (flag[0]) return;
    head_body<KDIM, TANH_IN, false>(X, W, B, Y, yoff, fout, gamma, beta, rm, rv, pre_ws, mode);
}

template <bool BF>
__device__ __forceinline__ void tl_body(const float* pre, const void* wtl,
                                        const void* btl, void* y, size_t yoff) {
    int i = blockIdx.x * 256 + threadIdx.x;
    if (i >= NN) return;
    float s = ldv<BF>(btl, 0);
#pragma unroll 8
    for (int k = 0; k < NBITS; ++k) s += pre[(size_t)i * NBITS + k] * ldv<BF>(wtl, k);
    stv<BF>(y, yoff + i, s);
}

__global__ void __launch_bounds__(256) true_lab_f32_kernel(const float* pre, const void* wtl,
                                                           const void* btl, void* y,
                                                           size_t yoff, const int* flag) {
    if (flag[0]) return;
    tl_body<false>(pre, wtl, btl, y, yoff);
}

// ================= bf16-input mode (flag=1) MFMA path =================
__global__ void __launch_bounds__(256) sage_mfma_kernel(
        const u16* __restrict__ agg, const u16* __restrict__ x,
        const u16* __restrict__ wtl, const u16* __restrict__ wtr,
        const void* __restrict__ bl, u16* __restrict__ hout,
        const int* __restrict__ flag) {
    if (!flag[0]) return;
    int wid = threadIdx.x >> 6, lane = threadIdx.x & 63;
    int r0 = blockIdx.x * 64 + wid * 16;
    if (r0 >= NN) return;
    int l15 = lane & 15;
    int koff = (lane >> 4) * 8;

    bf16x8 af[4], xf[4];
    const u16* ap = agg + (size_t)(r0 + l15) * FDIM + koff;
    const u16* xp = x   + (size_t)(r0 + l15) * FDIM + koff;
#pragma unroll
    for (int kf = 0; kf < 4; ++kf) {
        af[kf] = *(const bf16x8*)(ap + kf * 32);
        xf[kf] = *(const bf16x8*)(xp + kf * 32);
    }
    int orow = r0 + (lane >> 4) * 4;
    for (int ct = 0; ct < 8; ++ct) {
        int c0 = ct * 16;
        f32x4 acc = {0.f, 0.f, 0.f, 0.f};
        const u16* blp = wtl + (size_t)(c0 + l15) * FDIM + koff;
        const u16* brp = wtr + (size_t)(c0 + l15) * FDIM + koff;
#pragma unroll
        for (int kf = 0; kf < 4; ++kf) {
            bf16x8 bL = *(const bf16x8*)(blp + kf * 32);
            bf16x8 bR = *(const bf16x8*)(brp + kf * 32);
            acc = MFMA16(af[kf], bL, acc);
            acc = MFMA16(xf[kf], bR, acc);
        }
        int ocol = c0 + l15;
        float bv = us2f(((const u16*)bl)[ocol]);
#pragma unroll
        for (int i = 0; i < 4; ++i) {
            float v = acc[i] + bv;
            hout[(size_t)(orow + i) * FDIM + ocol] = f2bf(v > 0.f ? v : 0.f);
        }
    }
}

template <int K, int FP>
__global__ void __launch_bounds__(256) head_mfma_kernel(
        const u16* __restrict__ X, const u16* __restrict__ WT,
        const void* __restrict__ B, void* __restrict__ Y, size_t yoff,
        int fout, const int* __restrict__ flag) {
    if (!flag[0]) return;
    int wid = threadIdx.x >> 6, lane = threadIdx.x & 63;
    int r0 = blockIdx.x * 64 + wid * 16;
    if (r0 >= NN) return;
    int l15 = lane & 15;
    int koff = (lane >> 4) * 8;

    bf16x8 af[K / 32];
    const u16* xp = X + (size_t)(r0 + l15) * K + koff;
#pragma unroll
    for (int kf = 0; kf < K / 32; ++kf) af[kf] = *(const bf16x8*)(xp + kf * 32);

    u16* y = (u16*)Y + yoff;
    int orow = r0 + (lane >> 4) * 4;
    for (int ct = 0; ct < FP / 16; ++ct) {
        int c0 = ct * 16;
        f32x4 acc = {0.f, 0.f, 0.f, 0.f};
        const u16* bp = WT + (size_t)(c0 + l15) * K + koff;
#pragma unroll
        for (int kf = 0; kf < K / 32; ++kf) {
            bf16x8 bF = *(const bf16x8*)(bp + kf * 32);
            acc = MFMA16(af[kf], bF, acc);
        }
        int ocol = c0 + l15;
        if (ocol < fout) {
            float bv = us2f(((const u16*)B)[ocol]);
#pragma unroll
            for (int i = 0; i < 4; ++i)
                y[(size_t)(orow + i) * fout + ocol] = f2bf(acc[i] + bv);
        }
    }
}

__global__ void __launch_bounds__(256) headconv_mfma_kernel(
        const u16* __restrict__ X, const u16* __restrict__ WT,
        const void* __restrict__ B, const void* __restrict__ gamma,
        const void* __restrict__ beta, const void* __restrict__ rm,
        const void* __restrict__ rv, float* __restrict__ pre,
        void* __restrict__ Y, size_t yoff, const int* __restrict__ flag) {
    if (!flag[0]) return;
    int wid = threadIdx.x >> 6, lane = threadIdx.x & 63;
    int r0 = blockIdx.x * 64 + wid * 16;
    if (r0 >= NN) return;
    int l15 = lane & 15;
    int koff = (lane >> 4) * 8;

    bf16x8 af[4];
    const u16* xp = X + (size_t)(r0 + l15) * FDIM + koff;
#pragma unroll
    for (int kf = 0; kf < 4; ++kf) af[kf] = *(const bf16x8*)(xp + kf * 32);

    u16* y = (u16*)Y + yoff;
    int orow = r0 + (lane >> 4) * 4;
    for (int ct = 0; ct < 4; ++ct) {
        int c0 = ct * 16;
        f32x4 acc = {0.f, 0.f, 0.f, 0.f};
        const u16* bp = WT + (size_t)(c0 + l15) * FDIM + koff;
#pragma unroll
        for (int kf = 0; kf < 4; ++kf) {
            bf16x8 bF = *(const bf16x8*)(bp + kf * 32);
            acc = MFMA16(af[kf], bF, acc);
        }
        int ocol = c0 + l15;
        float bv = us2f(((const u16*)B)[ocol]);
        float g  = us2f(((const u16*)gamma)[ocol]);
        float be = us2f(((const u16*)beta)[ocol]);
        float m  = us2f(((const u16*)rm)[ocol]);
        float rs = rsqrtf(us2f(((const u16*)rv)[ocol]) + 1e-5f);
#pragma unroll
        for (int i = 0; i < 4; ++i) {
            float p = g * (acc[i] + bv - m) * rs + be;
            pre[(size_t)(orow + i) * NBITS + ocol] = p;
            y[(size_t)(orow + i) * NBITS + ocol] = f2bf(tanhf(p));
        }
    }
}

__global__ void __launch_bounds__(256) true_lab_b16_kernel(const float* pre, const void* wtl,
                                                           const void* btl, void* y,
                                                           size_t yoff, const int* flag) {
    if (!flag[0]) return;
    tl_body<true>(pre, wtl, btl, y, yoff);
}

extern "C" void kernel_launch(void* const* d_in, const int* in_sizes, int n_in,
                              void* d_out, int out_size, void* d_ws, size_t ws_size,
                              hipStream_t stream) {
    const void* feat = d_in[0];
    const int* edges = (const int*)d_in[1];
    const void* w1l = d_in[2];
    const void* b1l = d_in[3];
    const void* w1r = d_in[4];
    const void* w2l = d_in[5];
    const void* b2l = d_in[6];
    const void* w2r = d_in[7];
    const void* whd = d_in[8];
    const void* bhd = d_in[9];
    const void* wclas = d_in[10];
    const void* bclas = d_in[11];
    const void* wconv = d_in[12];
    const void* bconv = d_in[13];
    const void* gamma = d_in[14];
    const void* beta  = d_in[15];
    const void* rm  = d_in[16];
    const void* rv  = d_in[17];
    const void* wtl = d_in[18];
    const void* btl = d_in[19];
    const void* wcv = d_in[20];
    const void* bcv = d_in[21];

    int* iw     = (int*)d_ws;
    int* flag   = iw;
    int* deg    = iw + 16;
    int* cursor = deg + NN;
    int* rowptr = cursor + NN;
    int* col    = rowptr + 50016;
    float* buf1 = (float*)(col + NE);
    float* buf2 = buf1 + (size_t)NN * FDIM;
    float* pre_f = buf1;                       // fallback path only

    u16* wtf_hi = (u16*)(buf2 + (size_t)NN * FDIM);
    u16* wtf_lo = wtf_hi + WT_TOTAL;
    size_t need = (size_t)(16 + NN + NN + 50016 + NE) * 4
                + 2 * (size_t)NN * FDIM * 4
                + 2 * (size_t)WT_TOTAL * 2;
    bool mfma_ok = ws_size >= need;

    u16* aggb = (u16*)buf1;
    u16* hb1  = aggb + (size_t)NN * FDIM;
    u16* hb2  = (u16*)buf2;
    float* pre_b = buf2 + (size_t)NN * 64;

    u16* wt = (u16*)deg;   // bf16-mode packed WT (268 KB < 400 KB deg+cursor)

    const int* src = edges;
    const int* dst = edges + NE;

    hipMemsetAsync(iw, 0, (size_t)(16 + 2 * NN) * sizeof(int), stream);

    detect_kernel<<<1, 256, 0, stream>>>((const unsigned short*)feat, flag);

    // CSR build
    deg_kernel<<<(NE + 255) / 256, 256, 0, stream>>>(dst, deg);
    scan_kernel<<<1, 1024, 0, stream>>>(deg, rowptr);
    fill_kernel<<<(NE + 255) / 256, 256, 0, stream>>>(src, dst, rowptr, cursor, col);

    // output element offsets: logists | tanh_out | fea_lab | fea_convert | true_lab
    size_t o_log  = 0;
    size_t o_tanh = (size_t)NN * NCLS;
    size_t o_flab = o_tanh + (size_t)NN * NBITS;
    size_t o_fcv  = o_flab + (size_t)NN * HD;
    size_t o_tl   = o_fcv + (size_t)NN * NCLS;

    const int GR = (NN + 63) / 64;    // 64 rows/block kernels
    const int RB = NN / 16;           // 16 rows/block sage kernels = 3125

    // ---------------- bf16-input MFMA path (flag=1) ----------------
    tr_all_kernel<<<(WT_TOTAL + 255) / 256, 256, 0, stream>>>(
        w1l, w1r, w2l, w2r, whd, wclas, wconv, wcv, wt, flag);
    aggb_kernel<<<NN / 4, 256, 0, stream>>>((const u16*)feat, rowptr, col, aggb, flag);
    sage_mfma_kernel<<<GR, 256, 0, stream>>>(aggb, (const u16*)feat, wt + WT_1L, wt + WT_1R, b1l, hb1, flag);
    aggb_kernel<<<NN / 4, 256, 0, stream>>>(hb1, rowptr, col, aggb, flag);
    sage_mfma_kernel<<<GR, 256, 0, stream>>>(aggb, hb1, wt + WT_2L, wt + WT_2R, b2l, hb2, flag);
    head_mfma_kernel<128, 304><<<GR, 256, 0, stream>>>(hb2, wt + WT_HD, bhd, d_out, o_flab, HD, flag);
    head_mfma_kernel<128, 112><<<GR, 256, 0, stream>>>(hb2, wt + WT_CLS, bclas, d_out, o_log, NCLS, flag);
    headconv_mfma_kernel<<<GR, 256, 0, stream>>>(hb2, wt + WT_CONV, bconv, gamma, beta, rm, rv,
                                                 pre_b, d_out, o_tanh, flag);
    head_mfma_kernel<64, 112><<<GR, 256, 0, stream>>>((const u16*)d_out + o_tanh, wt + WT_CV, bcv,
                                                      d_out, o_fcv, NCLS, flag);
    true_lab_b16_kernel<<<(NN + 255) / 256, 256, 0, stream>>>(pre_b, wtl, btl, d_out, o_tl, flag);

    // ---------------- f32-input path (flag=0) ----------------
    if (mfma_ok) {
        tr_f32_kernel<<<(WT_TOTAL + 255) / 256, 256, 0, stream>>>(
            (const float*)w1l, (const float*)w1r, (const float*)w2l, (const float*)w2r,
            (const float*)whd, (const float*)wclas, (const float*)wconv, (const float*)wcv,
            wtf_hi, wtf_lo, flag);

        agg_f32_kernel<<<NN / 4, 256, 0, stream>>>((const float*)feat, rowptr, col, buf1, flag);
        sage_mfma_f32_kernel<<<RB, 256, 0, stream>>>(
            buf1, (const float*)feat,
            wtf_hi + WT_1L, wtf_lo + WT_1L, wtf_hi + WT_1R, wtf_lo + WT_1R,
            (const float*)b1l, buf1, flag);
        agg_f32_kernel<<<NN / 4, 256, 0, stream>>>(buf1, rowptr, col, buf2, flag);
        sage_mfma_f32_kernel<<<RB, 256, 0, stream>>>(
            buf2, buf1,
            wtf_hi + WT_2L, wtf_lo + WT_2L, wtf_hi + WT_2R, wtf_lo + WT_2R,
            (const float*)b2l, buf2, flag);

        heads3_f32_kernel<<<dim3(GR, 3), 256, 0, stream>>>(
            buf2, wtf_hi + WT_HD, wtf_lo + WT_HD,
            (const float*)bhd, (const float*)bclas, (const float*)bconv,
            (const float*)gamma, (const float*)beta, (const float*)rm, (const float*)rv,
            (const float*)wtl, (const float*)btl,
            (float*)d_out, o_flab, o_log, o_tanh, o_tl, flag);
        headcv_f32_kernel<<<GR, 256, 0, stream>>>(
            (const float*)d_out + o_tanh, wtf_hi + WT_CV, wtf_lo + WT_CV,
            (const float*)bcv, (float*)d_out, o_fcv, flag);
    } else {
        // fallback: original vector path (workspace too small for split weights)
        agg_f32_kernel<<<NN / 4, 256, 0, stream>>>((const float*)feat, rowptr, col, buf1, flag);
        sage_f32_kernel<<<NN / 8, 256, 0, stream>>>(buf1, (const float*)feat, w1l, b1l, w1r, buf1, flag);
        agg_f32_kernel<<<NN / 4, 256, 0, stream>>>(buf1, rowptr, col, buf2, flag);
        sage_f32_kernel<<<NN / 8, 256, 0, stream>>>(buf2, buf1, w2l, b2l, w2r, buf2, flag);

        head_f32_kernel<FDIM, false><<<NN / 16, 256, 0, stream>>>(
            buf2, whd, bhd, d_out, o_flab, HD,
            nullptr, nullptr, nullptr, nullptr, nullptr, 0, flag);
        head_f32_kernel<FDIM, false><<<NN / 16, 256, 0, stream>>>(
            buf2, wclas, bclas, d_out, o_log, NCLS,
            nullptr, nullptr, nullptr, nullptr, nullptr, 0, flag);
        head_f32_kernel<FDIM, false><<<NN / 16, 256, 0, stream>>>(
            buf2, wconv, bconv, d_out, o_tanh, NBITS,
            gamma, beta, rm, rv, pre_f, 1, flag);
        head_f32_kernel<NBITS, true><<<NN / 16, 256, 0, stream>>>(
            pre_f, wcv, bcv, d_out, o_fcv, NCLS,
            nullptr, nullptr, nullptr, nullptr, nullptr, 0, flag);
        true_lab_f32_kernel<<<(NN + 255) / 256, 256, 0, stream>>>(pre_f, wtl, btl, d_out, o_tl, flag);
    }
}

// Round 6
// 699.997 us; speedup vs baseline: 1.4338x; 1.0066x over previous
//
#include <hip/hip_runtime.h>
#include <hip/hip_bf16.h>
#include <math.h>

#define NN 50000
#define NE 800000
#define FDIM 128
#define NBITS 64
#define NCLS 100
#define HD 300

typedef unsigned short u16;
typedef __attribute__((ext_vector_type(8))) short bf16x8;
typedef __attribute__((ext_vector_type(4))) float f32x4;

#define MFMA16(a, b, c) __builtin_amdgcn_mfma_f32_16x16x32_bf16((a), (b), (c), 0, 0, 0)

__device__ __forceinline__ float us2f(unsigned short u) {
    union { unsigned int i; float f; } x; x.i = ((unsigned int)u) << 16; return x.f;
}
__device__ __forceinline__ unsigned short f2bf(float f) {
    union { float f; unsigned int i; } x; x.f = f;
    unsigned int i = x.i;
    i += 0x7fffu + ((i >> 16) & 1u);   // round-to-nearest-even
    return (unsigned short)(i >> 16);
}
__device__ __forceinline__ unsigned short f2bf_trunc(float f) {
    union { float f; unsigned int i; } x; x.f = f;
    return (unsigned short)(x.i >> 16);   // round-toward-zero
}

template <bool BF>
__device__ __forceinline__ float ldv(const void* p, size_t i) {
    return BF ? us2f(((const unsigned short*)p)[i]) : ((const float*)p)[i];
}
template <bool BF>
__device__ __forceinline__ void stv(void* p, size_t i, float v) {
    if (BF) ((unsigned short*)p)[i] = f2bf(v);
    else    ((float*)p)[i] = v;
}

// split 8 contiguous f32 into bf16 hi (trunc) + lo (RNE of residual)
__device__ __forceinline__ void splitA(const float* p, bf16x8& hi, bf16x8& lo) {
    float4 a = *(const float4*)p;
    float4 b = *(const float4*)(p + 4);
    float v[8] = {a.x, a.y, a.z, a.w, b.x, b.y, b.z, b.w};
#pragma unroll
    for (int j = 0; j < 8; ++j) {
        u16 h = f2bf_trunc(v[j]);
        float r = v[j] - us2f(h);
        hi[j] = (short)h;
        lo[j] = (short)f2bf(r);
    }
}

// quarter-group reduction: sum across the 4 sixteen-lane groups of a wave
__device__ __forceinline__ float qred(float v) {
    v += __shfl_xor(v, 16);
    v += __shfl_xor(v, 32);
    return v;
}

// ---------------- dtype detection (flag=1 => bf16 buffers) ----------------
__global__ void __launch_bounds__(256) detect_kernel(const unsigned short* __restrict__ f,
                                                     int* __restrict__ flag) {
    __shared__ int bad;
    if (threadIdx.x == 0) bad = 0;
    __syncthreads();
    int b = 0;
    for (int i = threadIdx.x; i < 4096; i += 256) {
        float v = us2f(f[i]);
        if (!(fabsf(v) < 1e4f)) b = 1;   // catches NaN too
    }
    if (b) atomicOr(&bad, 1);
    __syncthreads();
    if (threadIdx.x == 0) flag[0] = bad ? 0 : 1;
}

// ---------------- CSR build ----------------
__global__ void __launch_bounds__(256) deg_kernel(const int* __restrict__ dst,
                                                  int* __restrict__ deg) {
    int e = blockIdx.x * 256 + threadIdx.x;
    if (e < NE) atomicAdd(&deg[dst[e]], 1);
}

__global__ void __launch_bounds__(1024) scan_kernel(const int* __restrict__ deg,
                                                    int* __restrict__ rowptr) {
    __shared__ int wsum[16];
    __shared__ int carry_sh;
    int t = threadIdx.x;
    int lane = t & 63;
    int w = t >> 6;
    if (t == 0) carry_sh = 0;
    __syncthreads();
    for (int base = 0; base < NN; base += 1024) {
        int i = base + t;
        int v = (i < NN) ? deg[i] : 0;
        int x = v;
#pragma unroll
        for (int off = 1; off < 64; off <<= 1) {
            int u = __shfl_up(x, off);
            if (lane >= off) x += u;
        }
        if (lane == 63) wsum[w] = x;
        __syncthreads();
        if (w == 0) {
            int y = (lane < 16) ? wsum[lane] : 0;
#pragma unroll
            for (int off = 1; off < 16; off <<= 1) {
                int u = __shfl_up(y, off);
                if (lane >= off) y += u;
            }
            if (lane < 16) wsum[lane] = y;
        }
        __syncthreads();
        int woff = (w > 0) ? wsum[w - 1] : 0;
        int incl = x + woff;
        int carry = carry_sh;
        if (i < NN) rowptr[i] = carry + incl - v;   // exclusive
        __syncthreads();
        if (t == 1023) carry_sh = carry + incl;
        __syncthreads();
    }
    if (t == 0) rowptr[NN] = carry_sh;
}

__global__ void __launch_bounds__(256) fill_kernel(const int* __restrict__ src,
                                                   const int* __restrict__ dst,
                                                   const int* __restrict__ rowptr,
                                                   int* __restrict__ cursor,
                                                   int* __restrict__ col) {
    int e = blockIdx.x * 256 + threadIdx.x;
    if (e >= NE) return;
    int d = dst[e];
    int p = atomicAdd(&cursor[d], 1);
    col[rowptr[d] + p] = src[e];
}

// ---------------- weight transpose/pack layout ----------------
#define WT_1L   0
#define WT_1R   16384
#define WT_2L   32768
#define WT_2R   49152
#define WT_HD   65536
#define WT_CLS  104448
#define WT_CONV 118784
#define WT_CV   126976
#define WT_TOTAL 134144

// bf16-input mode: single packed WT (overlays deg+cursor)
__global__ void __launch_bounds__(256) tr_all_kernel(
        const void* w1l, const void* w1r, const void* w2l, const void* w2r,
        const void* whd, const void* wclas, const void* wconv, const void* wcv,
        u16* __restrict__ wt, const int* __restrict__ flag) {
    if (!flag[0]) return;
    int idx = blockIdx.x * 256 + threadIdx.x;
    if (idx >= WT_TOTAL) return;
    const u16* src; int K, F, d;
    if      (idx < WT_1R)  { src = (const u16*)w1l;   K = 128; F = 128; d = idx - WT_1L; }
    else if (idx < WT_2L)  { src = (const u16*)w1r;   K = 128; F = 128; d = idx - WT_1R; }
    else if (idx < WT_2R)  { src = (const u16*)w2l;   K = 128; F = 128; d = idx - WT_2L; }
    else if (idx < WT_HD)  { src = (const u16*)w2r;   K = 128; F = 128; d = idx - WT_2R; }
    else if (idx < WT_CLS) { src = (const u16*)whd;   K = 128; F = 300; d = idx - WT_HD; }
    else if (idx < WT_CONV){ src = (const u16*)wclas; K = 128; F = 100; d = idx - WT_CLS; }
    else if (idx < WT_CV)  { src = (const u16*)wconv; K = 128; F = 64;  d = idx - WT_CONV; }
    else                   { src = (const u16*)wcv;   K = 64;  F = 100; d = idx - WT_CV; }
    int lgK = (K == 64) ? 6 : 7;
    int f = d >> lgK;
    int k = d & (K - 1);
    wt[idx] = (f < F) ? src[k * F + f] : (u16)0;
}

// f32-input mode: transposed hi/lo split weights (WT_CONV base fixed in r5)
__global__ void __launch_bounds__(256) tr_f32_kernel(
        const float* w1l, const float* w1r, const float* w2l, const float* w2r,
        const float* whd, const float* wclas, const float* wconv, const float* wcv,
        u16* __restrict__ wth, u16* __restrict__ wtlo, const int* __restrict__ flag) {
    if (flag[0]) return;
    int idx = blockIdx.x * 256 + threadIdx.x;
    if (idx >= WT_TOTAL) return;
    const float* src; int K, F, d;
    if      (idx < WT_1R)  { src = w1l;   K = 128; F = 128; d = idx - WT_1L; }
    else if (idx < WT_2L)  { src = w1r;   K = 128; F = 128; d = idx - WT_1R; }
    else if (idx < WT_2R)  { src = w2l;   K = 128; F = 128; d = idx - WT_2L; }
    else if (idx < WT_HD)  { src = w2r;   K = 128; F = 128; d = idx - WT_2R; }
    else if (idx < WT_CLS) { src = whd;   K = 128; F = 300; d = idx - WT_HD; }
    else if (idx < WT_CONV){ src = wclas; K = 128; F = 100; d = idx - WT_CLS; }
    else if (idx < WT_CV)  { src = wconv; K = 128; F = 64;  d = idx - WT_CONV; }
    else                   { src = wcv;   K = 64;  F = 100; d = idx - WT_CV; }
    int lgK = (K == 64) ? 6 : 7;
    int f = d >> lgK;
    int k = d & (K - 1);
    float v = (f < F) ? src[k * F + f] : 0.f;
    u16 h = f2bf_trunc(v);
    wth[idx]  = h;
    wtlo[idx] = f2bf(v - us2f(h));
}

// ---------------- gather aggregation ----------------
// ROUND-6: 4 neighbors/iter (16-lane groups, 8 floats/lane) for deeper MLP.
__global__ void __launch_bounds__(256) agg_f32_kernel(const float* __restrict__ x,
                                                      const int* __restrict__ rowptr,
                                                      const int* __restrict__ col,
                                                      float* __restrict__ aggm,
                                                      const int* __restrict__ flag) {
    if (flag[0]) return;
    int node = blockIdx.x * 4 + (threadIdx.x >> 6);
    int lane = threadIdx.x & 63;
    int q  = lane >> 4;           // quarter-group 0..3, one neighbor each
    int c0 = (lane & 15) * 8;     // 8 channels per lane
    int beg = rowptr[node], end = rowptr[node + 1];
    float4 s0 = {0.f, 0.f, 0.f, 0.f};
    float4 s1 = {0.f, 0.f, 0.f, 0.f};
    int j = beg;
    for (; j + 4 <= end; j += 4) {
        int nbr = col[j + q];
        const float* r = x + (size_t)nbr * FDIM + c0;
        float4 u0 = *(const float4*)r;
        float4 u1 = *(const float4*)(r + 4);
        s0.x += u0.x; s0.y += u0.y; s0.z += u0.z; s0.w += u0.w;
        s1.x += u1.x; s1.y += u1.y; s1.z += u1.z; s1.w += u1.w;
    }
    int rem = end - j;
    if (q < rem) {
        int nbr = col[j + q];
        const float* r = x + (size_t)nbr * FDIM + c0;
        float4 u0 = *(const float4*)r;
        float4 u1 = *(const float4*)(r + 4);
        s0.x += u0.x; s0.y += u0.y; s0.z += u0.z; s0.w += u0.w;
        s1.x += u1.x; s1.y += u1.y; s1.z += u1.z; s1.w += u1.w;
    }
    s0.x = qred(s0.x); s0.y = qred(s0.y); s0.z = qred(s0.z); s0.w = qred(s0.w);
    s1.x = qred(s1.x); s1.y = qred(s1.y); s1.z = qred(s1.z); s1.w = qred(s1.w);
    if (q == 0) {
        float inv = 1.f / fmaxf((float)(end - beg), 1.f);
        float4 o0; o0.x = s0.x * inv; o0.y = s0.y * inv; o0.z = s0.z * inv; o0.w = s0.w * inv;
        float4 o1; o1.x = s1.x * inv; o1.y = s1.y * inv; o1.z = s1.z * inv; o1.w = s1.w * inv;
        float* w = aggm + (size_t)node * FDIM + c0;
        *(float4*)w = o0;
        *(float4*)(w + 4) = o1;
    }
}

// bf16 mode gather: bf16 in -> mean (f32 accum) -> bf16 out
__global__ void __launch_bounds__(256) aggb_kernel(const u16* __restrict__ xv,
                                                   const int* __restrict__ rowptr,
                                                   const int* __restrict__ col,
                                                   u16* __restrict__ aggm,
                                                   const int* __restrict__ flag) {
    if (!flag[0]) return;
    int node = blockIdx.x * 4 + (threadIdx.x >> 6);
    int lane = threadIdx.x & 63;
    int beg = rowptr[node], end = rowptr[node + 1];
    float a0 = 0.f, a1 = 0.f;
    for (int j = beg; j < end; ++j) {
        int nbr = col[j];
        ushort2 u = *(const ushort2*)(xv + (size_t)nbr * FDIM + lane * 2);
        a0 += us2f(u.x); a1 += us2f(u.y);
    }
    float inv = 1.f / fmaxf((float)(end - beg), 1.f);
    ushort2 o; o.x = f2bf(a0 * inv); o.y = f2bf(a1 * inv);
    *(ushort2*)(aggm + (size_t)node * FDIM + lane * 2) = o;
}

// ================= f32-input mode: split-bf16 MFMA path =================

// h = relu(agg@Wl + x@Wr + b). 16 rows/block, waves split col-tiles.
// In-place safe: barrier after A-loads; blocks own disjoint rows. [validated r3/r5]
__global__ void __launch_bounds__(256) sage_mfma_f32_kernel(
        const float* __restrict__ agg, const float* __restrict__ x,
        const u16* __restrict__ wlh, const u16* __restrict__ wll,
        const u16* __restrict__ wrh, const u16* __restrict__ wrl,
        const float* __restrict__ bl, float* __restrict__ hout,
        const int* __restrict__ flag) {
    if (flag[0]) return;
    int wid = threadIdx.x >> 6, lane = threadIdx.x & 63;
    int r0 = blockIdx.x * 16;
    int l15 = lane & 15;
    int koff = (lane >> 4) * 8;

    bf16x8 ah[4], al[4], xh[4], xl[4];
    const float* ap = agg + (size_t)(r0 + l15) * FDIM + koff;
    const float* xp = x   + (size_t)(r0 + l15) * FDIM + koff;
#pragma unroll
    for (int kf = 0; kf < 4; ++kf) {
        splitA(ap + kf * 32, ah[kf], al[kf]);
        splitA(xp + kf * 32, xh[kf], xl[kf]);
    }
    __syncthreads();   // all reads of this block's rows precede in-place writes
    int orow = r0 + (lane >> 4) * 4;
#pragma unroll
    for (int tt = 0; tt < 2; ++tt) {
        int ct = wid * 2 + tt;
        f32x4 acc = {0.f, 0.f, 0.f, 0.f};
        const u16* pLh = wlh + (size_t)(ct * 16 + l15) * FDIM + koff;
        const u16* pLl = wll + (size_t)(ct * 16 + l15) * FDIM + koff;
        const u16* pRh = wrh + (size_t)(ct * 16 + l15) * FDIM + koff;
        const u16* pRl = wrl + (size_t)(ct * 16 + l15) * FDIM + koff;
#pragma unroll
        for (int kf = 0; kf < 4; ++kf) {
            int o0 = kf * 32;
            bf16x8 bLh = *(const bf16x8*)(pLh + o0);
            bf16x8 bLl = *(const bf16x8*)(pLl + o0);
            bf16x8 bRh = *(const bf16x8*)(pRh + o0);
            bf16x8 bRl = *(const bf16x8*)(pRl + o0);
            acc = MFMA16(ah[kf], bLh, acc);
            acc = MFMA16(al[kf], bLh, acc);
            acc = MFMA16(ah[kf], bLl, acc);
            acc = MFMA16(xh[kf], bRh, acc);
            acc = MFMA16(xl[kf], bRh, acc);
            acc = MFMA16(xh[kf], bRl, acc);
        }
        int oc = ct * 16 + l15;
        float bv = bl[oc];
#pragma unroll
        for (int i = 0; i < 4; ++i) {
            float v = acc[i] + bv;
            hout[(size_t)(orow + i) * FDIM + oc] = v > 0.f ? v : 0.f;
        }
    }
}

// epilogue for the fused 3-head kernel: global col-tile ct in [0,30)
// cols 0..303 -> fea_lab (HD) | 304..415 -> logists (NCLS) | 416..479 -> conv+BN+tanh
__device__ __forceinline__ void heads3_epi(int ct, int l15, int orow, const f32x4& acc,
        const float* bhd, const float* bclas, const float* bconv,
        const float* gamma, const float* beta, const float* rm, const float* rv,
        const float* wtl, float* out, size_t o_flab, size_t o_log, size_t o_tanh,
        float* tl) {
    int gcol = ct * 16 + l15;
    if (gcol < 304) {
        if (gcol < 300) {
            float bv = bhd[gcol];
#pragma unroll
            for (int i = 0; i < 4; ++i)
                out[o_flab + (size_t)(orow + i) * HD + gcol] = acc[i] + bv;
        }
    } else if (gcol < 416) {
        int lc = gcol - 304;
        if (lc < NCLS) {
            float bv = bclas[lc];
#pragma unroll
            for (int i = 0; i < 4; ++i)
                out[o_log + (size_t)(orow + i) * NCLS + lc] = acc[i] + bv;
        }
    } else {
        int lc = gcol - 416;
        float bv = bconv[lc];
        float g  = gamma[lc];
        float be = beta[lc];
        float m  = rm[lc];
        float rs = rsqrtf(rv[lc] + 1e-5f);
        float wv = wtl[lc];
#pragma unroll
        for (int i = 0; i < 4; ++i) {
            float p = g * (acc[i] + bv - m) * rs + be;
            out[o_tanh + (size_t)(orow + i) * NBITS + lc] = tanhf(p);
            tl[i] += p * wv;
        }
    }
}

// ROUND-6: fused HD + clas + conv(BN,tanh) + true_lab; r3 structure (typo-free
// weights now): 16 rows/block, waves split tiles {0-7},{8-15},{16-22},{23-29}.
// Single acc -> low VGPR -> high occupancy. Grid NN/16 = 3125.
__global__ void __launch_bounds__(256) heads3_f32_kernel(
        const float* __restrict__ X,
        const u16* __restrict__ wh, const u16* __restrict__ wl,
        const float* __restrict__ bhd, const float* __restrict__ bclas,
        const float* __restrict__ bconv,
        const float* __restrict__ gamma, const float* __restrict__ beta,
        const float* __restrict__ rm, const float* __restrict__ rv,
        const float* __restrict__ wtl, const float* __restrict__ btl,
        float* __restrict__ out, size_t o_flab, size_t o_log, size_t o_tanh, size_t o_tl,
        const int* __restrict__ flag) {
    if (flag[0]) return;
    int wid = threadIdx.x >> 6, lane = threadIdx.x & 63;
    int r0 = blockIdx.x * 16;
    int l15 = lane & 15;
    int koff = (lane >> 4) * 8;

    bf16x8 ah[4], al[4];
    const float* xp = X + (size_t)(r0 + l15) * FDIM + koff;
#pragma unroll
    for (int kf = 0; kf < 4; ++kf) splitA(xp + kf * 32, ah[kf], al[kf]);

    int orow = r0 + (lane >> 4) * 4;
    float tl[4] = {0.f, 0.f, 0.f, 0.f};

    int t0 = (wid == 0) ? 0 : (wid == 1) ? 8 : (wid == 2) ? 16 : 23;
    int t1 = (wid == 0) ? 8 : (wid == 1) ? 16 : (wid == 2) ? 23 : 30;
    for (int ct = t0; ct < t1; ++ct) {
        f32x4 acc = {0.f, 0.f, 0.f, 0.f};
        const u16* ph = wh + (size_t)(ct * 16 + l15) * FDIM + koff;
        const u16* pl = wl + (size_t)(ct * 16 + l15) * FDIM + koff;
#pragma unroll
        for (int kf = 0; kf < 4; ++kf) {
            int o0 = kf * 32;
            bf16x8 bh = *(const bf16x8*)(ph + o0);
            bf16x8 bl2 = *(const bf16x8*)(pl + o0);
            acc = MFMA16(ah[kf], bh, acc);
            acc = MFMA16(al[kf], bh, acc);
            acc = MFMA16(ah[kf], bl2, acc);
        }
        heads3_epi(ct, l15, orow, acc, bhd, bclas, bconv, gamma, beta, rm, rv,
                   wtl, out, o_flab, o_log, o_tanh, tl);
    }

    if (wid == 3) {   // true_lab: conv tiles (26-29) are wave-3-local
        float bt = btl[0];
#pragma unroll
        for (int i = 0; i < 4; ++i) {
            float t = tl[i];
            t += __shfl_xor(t, 1);
            t += __shfl_xor(t, 2);
            t += __shfl_xor(t, 4);
            t += __shfl_xor(t, 8);
            if (l15 == 0) out[o_tl + orow + i] = t + bt;
        }
    }
}

// fea_convert = tanh_out @ wcv + bcv; X = tanh f32 (from d_out), K=64
// round-2 version (wave owns rows, all 7 tiles)
__global__ void __launch_bounds__(256) headcv_f32_kernel(
        const float* __restrict__ X,
        const u16* __restrict__ wh, const u16* __restrict__ wl,
        const float* __restrict__ bcv, float* __restrict__ out, size_t o_fcv,
        const int* __restrict__ flag) {
    if (flag[0]) return;
    int wid = threadIdx.x >> 6, lane = threadIdx.x & 63;
    int r0 = blockIdx.x * 64 + wid * 16;
    if (r0 >= NN) return;
    int l15 = lane & 15;
    int koff = (lane >> 4) * 8;

    bf16x8 ah[2], al[2];
    const float* xp = X + (size_t)(r0 + l15) * NBITS + koff;
#pragma unroll
    for (int kf = 0; kf < 2; ++kf) splitA(xp + kf * 32, ah[kf], al[kf]);

    int orow = r0 + (lane >> 4) * 4;
#pragma unroll
    for (int ct = 0; ct < 7; ++ct) {
        f32x4 acc = {0.f, 0.f, 0.f, 0.f};
        const u16* ph = wh + (size_t)(ct * 16 + l15) * NBITS + koff;
        const u16* pl = wl + (size_t)(ct * 16 + l15) * NBITS + koff;
#pragma unroll
        for (int kf = 0; kf < 2; ++kf) {
            int o0 = kf * 32;
            bf16x8 bh = *(const bf16x8*)(ph + o0);
            bf16x8 bl2 = *(const bf16x8*)(pl + o0);
            acc = MFMA16(ah[kf], bh, acc);
            acc = MFMA16(al[kf], bh, acc);
            acc = MFMA16(ah[kf], bl2, acc);
        }
        int oc = ct * 16 + l15;
        if (oc < NCLS) {
            float bv = bcv[oc];
#pragma unroll
            for (int i = 0; i < 4; ++i)
                out[o_fcv + (size_t)(orow + i) * NCLS + oc] = acc[i] + bv;
        }
    }
}

// ================= f32 vector fallback (only if workspace too small) ========
template <bool XBF, bool WBF>
__device__ __forceinline__ void sage_body(const float* aggm, const void* xv,
                                          const void* wl, const void* bl,
                                          const void* wr, float* hout) {
    __shared__ float ms[8][FDIM];
    __shared__ float xs[8][FDIM];
    int n0 = blockIdx.x * 8;
    int t = threadIdx.x;
    for (int idx = t; idx < 8 * FDIM; idx += 256) {
        int j = idx >> 7, k = idx & 127;
        int n = n0 + j;
        ms[j][k] = aggm[(size_t)n * FDIM + k];
        xs[j][k] = ldv<XBF>(xv, (size_t)n * FDIM + k);
    }
    __syncthreads();
    int f = t & 127;
    int h = t >> 7;
    float acc[4] = {0.f, 0.f, 0.f, 0.f};
    for (int k = 0; k < FDIM; ++k) {
        float wlv = ldv<WBF>(wl, k * FDIM + f);
        float wrv = ldv<WBF>(wr, k * FDIM + f);
#pragma unroll
        for (int j = 0; j < 4; ++j) {
            int nn = h + j * 2;
            acc[j] += ms[nn][k] * wlv + xs[nn][k] * wrv;
        }
    }
    float bv = ldv<WBF>(bl, f);
#pragma unroll
    for (int j = 0; j < 4; ++j) {
        int nn = h + j * 2;
        float v = acc[j] + bv;
        hout[(size_t)(n0 + nn) * FDIM + f] = v > 0.f ? v : 0.f;
    }
}

__global__ void __launch_bounds__(256) sage_f32_kernel(const float* aggm, const float* x,
                                                       const void* wl, const void* bl,
                                                       const void* wr, float* hout,
                                                       const int* flag) {
    if (flag[0]) return;
    sage_body<false, false>(aggm, x, wl, bl, wr, hout);
}

template <int KDIM, bool TANH_IN, bool BF>
__device__ __forceinline__ void head_body(const float* X, const void* W, const void* B,
                                          void* Y, size_t yoff, int fout,
                                          const void* gamma, const void* beta,
                                          const void* rm, const void* rv,
                                          float* pre_ws, int mode) {
    __shared__ float xs[16][KDIM];
    int n0 = blockIdx.x * 16;
    int t = threadIdx.x;
    for (int idx = t; idx < 16 * KDIM; idx += 256) {
        int j = idx / KDIM, k = idx % KDIM;
        float v = X[(size_t)(n0 + j) * KDIM + k];
        xs[j][k] = TANH_IN ? tanhf(v) : v;
    }
    __syncthreads();
    for (int f = t; f < fout; f += 256) {
        float acc[16];
#pragma unroll
        for (int j = 0; j < 16; ++j) acc[j] = 0.f;
        for (int k = 0; k < KDIM; ++k) {
            float wv = ldv<BF>(W, (size_t)k * fout + f);
#pragma unroll
            for (int j = 0; j < 16; ++j) acc[j] += xs[j][k] * wv;
        }
        float bv = ldv<BF>(B, f);
        if (mode == 0) {
#pragma unroll
            for (int j = 0; j < 16; ++j)
                stv<BF>(Y, yoff + (size_t)(n0 + j) * fout + f, acc[j] + bv);
        } else {
            float g  = ldv<BF>(gamma, f);
            float be = ldv<BF>(beta, f);
            float m  = ldv<BF>(rm, f);
            float rs = rsqrtf(ldv<BF>(rv, f) + 1e-5f);
#pragma unroll
            for (int j = 0; j < 16; ++j) {
                float p = g * (acc[j] + bv - m) * rs + be;
                pre_ws[(size_t)(n0 + j) * fout + f] = p;
                stv<BF>(Y, yoff + (size_t)(n0 + j) * fout + f, tanhf(p));
            }
        }
    }
}

template <int KDIM, bool TANH_IN>
__global__ void __launch_bounds__(256) head_f32_kernel(const float* X, const void* W,
                                                       const void* B, void* Y, size_t yoff,
                                                       int fout, const void* gamma,
                                                       const void* beta, const void* rm,
                                                       const void* rv, float* pre_ws,
                                                       int mode, const int* flag) {
    if (flag[0]) return;
    head_body<KDIM, TANH_IN, false>(X, W, B, Y, yoff, fout, gamma, beta, rm, rv, pre_ws, mode);
}

template <bool BF>
__device__ __forceinline__ void tl_body(const float* pre, const void* wtl,
                                        const void* btl, void* y, size_t yoff) {
    int i = blockIdx.x * 256 + threadIdx.x;
    if (i >= NN) return;
    float s = ldv<BF>(btl, 0);
#pragma unroll 8
    for (int k = 0; k < NBITS; ++k) s += pre[(size_t)i * NBITS + k] * ldv<BF>(wtl, k);
    stv<BF>(y, yoff + i, s);
}

__global__ void __launch_bounds__(256) true_lab_f32_kernel(const float* pre, const void* wtl,
                                                           const void* btl, void* y,
                                                           size_t yoff, const int* flag) {
    if (flag[0]) return;
    tl_body<false>(pre, wtl, btl, y, yoff);
}

// ================= bf16-input mode (flag=1) MFMA path =================
__global__ void __launch_bounds__(256) sage_mfma_kernel(
        const u16* __restrict__ agg, const u16* __restrict__ x,
        const u16* __restrict__ wtl, const u16* __restrict__ wtr,
        const void* __restrict__ bl, u16* __restrict__ hout,
        const int* __restrict__ flag) {
    if (!flag[0]) return;
    int wid = threadIdx.x >> 6, lane = threadIdx.x & 63;
    int r0 = blockIdx.x * 64 + wid * 16;
    if (r0 >= NN) return;
    int l15 = lane & 15;
    int koff = (lane >> 4) * 8;

    bf16x8 af[4], xf[4];
    const u16* ap = agg + (size_t)(r0 + l15) * FDIM + koff;
    const u16* xp = x   + (size_t)(r0 + l15) * FDIM + koff;
#pragma unroll
    for (int kf = 0; kf < 4; ++kf) {
        af[kf] = *(const bf16x8*)(ap + kf * 32);
        xf[kf] = *(const bf16x8*)(xp + kf * 32);
    }
    int orow = r0 + (lane >> 4) * 4;
    for (int ct = 0; ct < 8; ++ct) {
        int c0 = ct * 16;
        f32x4 acc = {0.f, 0.f, 0.f, 0.f};
        const u16* blp = wtl + (size_t)(c0 + l15) * FDIM + koff;
        const u16* brp = wtr + (size_t)(c0 + l15) * FDIM + koff;
#pragma unroll
        for (int kf = 0; kf < 4; ++kf) {
            bf16x8 bL = *(const bf16x8*)(blp + kf * 32);
            bf16x8 bR = *(const bf16x8*)(brp + kf * 32);
            acc = MFMA16(af[kf], bL, acc);
            acc = MFMA16(xf[kf], bR, acc);
        }
        int ocol = c0 + l15;
        float bv = us2f(((const u16*)bl)[ocol]);
#pragma unroll
        for (int i = 0; i < 4; ++i) {
            float v = acc[i] + bv;
            hout[(size_t)(orow + i) * FDIM + ocol] = f2bf(v > 0.f ? v : 0.f);
        }
    }
}

template <int K, int FP>
__global__ void __launch_bounds__(256) head_mfma_kernel(
        const u16* __restrict__ X, const u16* __restrict__ WT,
        const void* __restrict__ B, void* __restrict__ Y, size_t yoff,
        int fout, const int* __restrict__ flag) {
    if (!flag[0]) return;
    int wid = threadIdx.x >> 6, lane = threadIdx.x & 63;
    int r0 = blockIdx.x * 64 + wid * 16;
    if (r0 >= NN) return;
    int l15 = lane & 15;
    int koff = (lane >> 4) * 8;

    bf16x8 af[K / 32];
    const u16* xp = X + (size_t)(r0 + l15) * K + koff;
#pragma unroll
    for (int kf = 0; kf < K / 32; ++kf) af[kf] = *(const bf16x8*)(xp + kf * 32);

    u16* y = (u16*)Y + yoff;
    int orow = r0 + (lane >> 4) * 4;
    for (int ct = 0; ct < FP / 16; ++ct) {
        int c0 = ct * 16;
        f32x4 acc = {0.f, 0.f, 0.f, 0.f};
        const u16* bp = WT + (size_t)(c0 + l15) * K + koff;
#pragma unroll
        for (int kf = 0; kf < K / 32; ++kf) {
            bf16x8 bF = *(const bf16x8*)(bp + kf * 32);
            acc = MFMA16(af[kf], bF, acc);
        }
        int ocol = c0 + l15;
        if (ocol < fout) {
            float bv = us2f(((const u16*)B)[ocol]);
#pragma unroll
            for (int i = 0; i < 4; ++i)
                y[(size_t)(orow + i) * fout + ocol] = f2bf(acc[i] + bv);
        }
    }
}

__global__ void __launch_bounds__(256) headconv_mfma_kernel(
        const u16* __restrict__ X, const u16* __restrict__ WT,
        const void* __restrict__ B, const void* __restrict__ gamma,
        const void* __restrict__ beta, const void* __restrict__ rm,
        const void* __restrict__ rv, float* __restrict__ pre,
        void* __restrict__ Y, size_t yoff, const int* __restrict__ flag) {
    if (!flag[0]) return;
    int wid = threadIdx.x >> 6, lane = threadIdx.x & 63;
    int r0 = blockIdx.x * 64 + wid * 16;
    if (r0 >= NN) return;
    int l15 = lane & 15;
    int koff = (lane >> 4) * 8;

    bf16x8 af[4];
    const u16* xp = X + (size_t)(r0 + l15) * FDIM + koff;
#pragma unroll
    for (int kf = 0; kf < 4; ++kf) af[kf] = *(const bf16x8*)(xp + kf * 32);

    u16* y = (u16*)Y + yoff;
    int orow = r0 + (lane >> 4) * 4;
    for (int ct = 0; ct < 4; ++ct) {
        int c0 = ct * 16;
        f32x4 acc = {0.f, 0.f, 0.f, 0.f};
        const u16* bp = WT + (size_t)(c0 + l15) * FDIM + koff;
#pragma unroll
        for (int kf = 0; kf < 4; ++kf) {
            bf16x8 bF = *(const bf16x8*)(bp + kf * 32);
            acc = MFMA16(af[kf], bF, acc);
        }
        int ocol = c0 + l15;
        float bv = us2f(((const u16*)B)[ocol]);
        float g  = us2f(((const u16*)gamma)[ocol]);
        float be = us2f(((const u16*)beta)[ocol]);
        float m  = us2f(((const u16*)rm)[ocol]);
        float rs = rsqrtf(us2f(((const u16*)rv)[ocol]) + 1e-5f);
#pragma unroll
        for (int i = 0; i < 4; ++i) {
            float p = g * (acc[i] + bv - m) * rs + be;
            pre[(size_t)(orow + i) * NBITS + ocol] = p;
            y[(size_t)(orow + i) * NBITS + ocol] = f2bf(tanhf(p));
        }
    }
}

__global__ void __launch_bounds__(256) true_lab_b16_kernel(const float* pre, const void* wtl,
                                                           const void* btl, void* y,
                                                           size_t yoff, const int* flag) {
    if (!flag[0]) return;
    tl_body<true>(pre, wtl, btl, y, yoff);
}

extern "C" void kernel_launch(void* const* d_in, const int* in_sizes, int n_in,
                              void* d_out, int out_size, void* d_ws, size_t ws_size,
                              hipStream_t stream) {
    const void* feat = d_in[0];
    const int* edges = (const int*)d_in[1];
    const void* w1l = d_in[2];
    const void* b1l = d_in[3];
    const void* w1r = d_in[4];
    const void* w2l = d_in[5];
    const void* b2l = d_in[6];
    const void* w2r = d_in[7];
    const void* whd = d_in[8];
    const void* bhd = d_in[9];
    const void* wclas = d_in[10];
    const void* bclas = d_in[11];
    const void* wconv = d_in[12];
    const void* bconv = d_in[13];
    const void* gamma = d_in[14];
    const void* beta  = d_in[15];
    const void* rm  = d_in[16];
    const void* rv  = d_in[17];
    const void* wtl = d_in[18];
    const void* btl = d_in[19];
    const void* wcv = d_in[20];
    const void* bcv = d_in[21];

    int* iw     = (int*)d_ws;
    int* flag   = iw;
    int* deg    = iw + 16;
    int* cursor = deg + NN;
    int* rowptr = cursor + NN;
    int* col    = rowptr + 50016;
    float* buf1 = (float*)(col + NE);
    float* buf2 = buf1 + (size_t)NN * FDIM;
    float* pre_f = buf1;                       // fallback path only

    u16* wtf_hi = (u16*)(buf2 + (size_t)NN * FDIM);
    u16* wtf_lo = wtf_hi + WT_TOTAL;
    size_t need = (size_t)(16 + NN + NN + 50016 + NE) * 4
                + 2 * (size_t)NN * FDIM * 4
                + 2 * (size_t)WT_TOTAL * 2;
    bool mfma_ok = ws_size >= need;

    u16* aggb = (u16*)buf1;
    u16* hb1  = aggb + (size_t)NN * FDIM;
    u16* hb2  = (u16*)buf2;
    float* pre_b = buf2 + (size_t)NN * 64;

    u16* wt = (u16*)deg;   // bf16-mode packed WT (268 KB < 400 KB deg+cursor)

    const int* src = edges;
    const int* dst = edges + NE;

    hipMemsetAsync(iw, 0, (size_t)(16 + 2 * NN) * sizeof(int), stream);

    detect_kernel<<<1, 256, 0, stream>>>((const unsigned short*)feat, flag);

    // CSR build
    deg_kernel<<<(NE + 255) / 256, 256, 0, stream>>>(dst, deg);
    scan_kernel<<<1, 1024, 0, stream>>>(deg, rowptr);
    fill_kernel<<<(NE + 255) / 256, 256, 0, stream>>>(src, dst, rowptr, cursor, col);

    // output element offsets: logists | tanh_out | fea_lab | fea_convert | true_lab
    size_t o_log  = 0;
    size_t o_tanh = (size_t)NN * NCLS;
    size_t o_flab = o_tanh + (size_t)NN * NBITS;
    size_t o_fcv  = o_flab + (size_t)NN * HD;
    size_t o_tl   = o_fcv + (size_t)NN * NCLS;

    const int GR = (NN + 63) / 64;    // 64 rows/block kernels
    const int RB = NN / 16;           // 16 rows/block kernels = 3125

    // ---------------- bf16-input MFMA path (flag=1) ----------------
    tr_all_kernel<<<(WT_TOTAL + 255) / 256, 256, 0, stream>>>(
        w1l, w1r, w2l, w2r, whd, wclas, wconv, wcv, wt, flag);
    aggb_kernel<<<NN / 4, 256, 0, stream>>>((const u16*)feat, rowptr, col, aggb, flag);
    sage_mfma_kernel<<<GR, 256, 0, stream>>>(aggb, (const u16*)feat, wt + WT_1L, wt + WT_1R, b1l, hb1, flag);
    aggb_kernel<<<NN / 4, 256, 0, stream>>>(hb1, rowptr, col, aggb, flag);
    sage_mfma_kernel<<<GR, 256, 0, stream>>>(aggb, hb1, wt + WT_2L, wt + WT_2R, b2l, hb2, flag);
    head_mfma_kernel<128, 304><<<GR, 256, 0, stream>>>(hb2, wt + WT_HD, bhd, d_out, o_flab, HD, flag);
    head_mfma_kernel<128, 112><<<GR, 256, 0, stream>>>(hb2, wt + WT_CLS, bclas, d_out, o_log, NCLS, flag);
    headconv_mfma_kernel<<<GR, 256, 0, stream>>>(hb2, wt + WT_CONV, bconv, gamma, beta, rm, rv,
                                                 pre_b, d_out, o_tanh, flag);
    head_mfma_kernel<64, 112><<<GR, 256, 0, stream>>>((const u16*)d_out + o_tanh, wt + WT_CV, bcv,
                                                      d_out, o_fcv, NCLS, flag);
    true_lab_b16_kernel<<<(NN + 255) / 256, 256, 0, stream>>>(pre_b, wtl, btl, d_out, o_tl, flag);

    // ---------------- f32-input path (flag=0) ----------------
    if (mfma_ok) {
        tr_f32_kernel<<<(WT_TOTAL + 255) / 256, 256, 0, stream>>>(
            (const float*)w1l, (const float*)w1r, (const float*)w2l, (const float*)w2r,
            (const float*)whd, (const float*)wclas, (const float*)wconv, (const float*)wcv,
            wtf_hi, wtf_lo, flag);

        agg_f32_kernel<<<NN / 4, 256, 0, stream>>>((const float*)feat, rowptr, col, buf1, flag);
        sage_mfma_f32_kernel<<<RB, 256, 0, stream>>>(
            buf1, (const float*)feat,
            wtf_hi + WT_1L, wtf_lo + WT_1L, wtf_hi + WT_1R, wtf_lo + WT_1R,
            (const float*)b1l, buf1, flag);
        agg_f32_kernel<<<NN / 4, 256, 0, stream>>>(buf1, rowptr, col, buf2, flag);
        sage_mfma_f32_kernel<<<RB, 256, 0, stream>>>(
            buf2, buf1,
            wtf_hi + WT_2L, wtf_lo + WT_2L, wtf_hi + WT_2R, wtf_lo + WT_2R,
            (const float*)b2l, buf2, flag);

        heads3_f32_kernel<<<RB, 256, 0, stream>>>(
            buf2, wtf_hi + WT_HD, wtf_lo + WT_HD,
            (const float*)bhd, (const float*)bclas, (const float*)bconv,
            (const float*)gamma, (const float*)beta, (const float*)rm, (const float*)rv,
            (const float*)wtl, (const float*)btl,
            (float*)d_out, o_flab, o_log, o_tanh, o_tl, flag);
        headcv_f32_kernel<<<GR, 256, 0, stream>>>(
            (const float*)d_out + o_tanh, wtf_hi + WT_CV, wtf_lo + WT_CV,
            (const float*)bcv, (float*)d_out, o_fcv, flag);
    } else {
        // fallback: original vector path (workspace too small for split weights)
        agg_f32_kernel<<<NN / 4, 256, 0, stream>>>((const float*)feat, rowptr, col, buf1, flag);
        sage_f32_kernel<<<NN / 8, 256, 0, stream>>>(buf1, (const float*)feat, w1l, b1l, w1r, buf1, flag);
        agg_f32_kernel<<<NN / 4, 256, 0, stream>>>(buf1, rowptr, col, buf2, flag);
        sage_f32_kernel<<<NN / 8, 256, 0, stream>>>(buf2, buf1, w2l, b2l, w2r, buf2, flag);

        head_f32_kernel<FDIM, false><<<NN / 16, 256, 0, stream>>>(
            buf2, whd, bhd, d_out, o_flab, HD,
            nullptr, nullptr, nullptr, nullptr, nullptr, 0, flag);
        head_f32_kernel<FDIM, false><<<NN / 16, 256, 0, stream>>>(
            buf2, wclas, bclas, d_out, o_log, NCLS,
            nullptr, nullptr, nullptr, nullptr, nullptr, 0, flag);
        head_f32_kernel<FDIM, false><<<NN / 16, 256, 0, stream>>>(
            buf2, wconv, bconv, d_out, o_tanh, NBITS,
            gamma, beta, rm, rv, pre_f, 1, flag);
        head_f32_kernel<NBITS, true><<<NN / 16, 256, 0, stream>>>(
            pre_f, wcv, bcv, d_out, o_fcv, NCLS,
            nullptr, nullptr, nullptr, nullptr, nullptr, 0, flag);
        true_lab_f32_kernel<<<(NN + 255) / 256, 256, 0, stream>>>(pre_f, wtl, btl, d_out, o_tl, flag);
    }
}

// Round 7
// 637.291 us; speedup vs baseline: 1.5749x; 1.0984x over previous
//
#include <hip/hip_runtime.h>
#include <hip/hip_bf16.h>
#include <math.h>

#define NN 50000
#define NE 800000
#define FDIM 128
#define NBITS 64
#define NCLS 100
#define HD 300

typedef unsigned short u16;
typedef __attribute__((ext_vector_type(8))) short bf16x8;
typedef __attribute__((ext_vector_type(4))) float f32x4;

#define MFMA16(a, b, c) __builtin_amdgcn_mfma_f32_16x16x32_bf16((a), (b), (c), 0, 0, 0)

__device__ __forceinline__ float us2f(unsigned short u) {
    union { unsigned int i; float f; } x; x.i = ((unsigned int)u) << 16; return x.f;
}
__device__ __forceinline__ unsigned short f2bf(float f) {
    union { float f; unsigned int i; } x; x.f = f;
    unsigned int i = x.i;
    i += 0x7fffu + ((i >> 16) & 1u);   // round-to-nearest-even
    return (unsigned short)(i >> 16);
}
__device__ __forceinline__ unsigned short f2bf_trunc(float f) {
    union { float f; unsigned int i; } x; x.f = f;
    return (unsigned short)(x.i >> 16);   // round-toward-zero
}

template <bool BF>
__device__ __forceinline__ float ldv(const void* p, size_t i) {
    return BF ? us2f(((const unsigned short*)p)[i]) : ((const float*)p)[i];
}
template <bool BF>
__device__ __forceinline__ void stv(void* p, size_t i, float v) {
    if (BF) ((unsigned short*)p)[i] = f2bf(v);
    else    ((float*)p)[i] = v;
}

// quarter-group reduction: sum across the 4 sixteen-lane groups of a wave
__device__ __forceinline__ float qred(float v) {
    v += __shfl_xor(v, 16);
    v += __shfl_xor(v, 32);
    return v;
}

// ---------------- dtype detection (flag=1 => bf16 buffers) ----------------
__global__ void __launch_bounds__(256) detect_kernel(const unsigned short* __restrict__ f,
                                                     int* __restrict__ flag) {
    __shared__ int bad;
    if (threadIdx.x == 0) bad = 0;
    __syncthreads();
    int b = 0;
    for (int i = threadIdx.x; i < 4096; i += 256) {
        float v = us2f(f[i]);
        if (!(fabsf(v) < 1e4f)) b = 1;   // catches NaN too
    }
    if (b) atomicOr(&bad, 1);
    __syncthreads();
    if (threadIdx.x == 0) flag[0] = bad ? 0 : 1;
}

// ---------------- CSR build ----------------
__global__ void __launch_bounds__(256) deg_kernel(const int* __restrict__ dst,
                                                  int* __restrict__ deg) {
    int e = blockIdx.x * 256 + threadIdx.x;
    if (e < NE) atomicAdd(&deg[dst[e]], 1);
}

__global__ void __launch_bounds__(1024) scan_kernel(const int* __restrict__ deg,
                                                    int* __restrict__ rowptr) {
    __shared__ int wsum[16];
    __shared__ int carry_sh;
    int t = threadIdx.x;
    int lane = t & 63;
    int w = t >> 6;
    if (t == 0) carry_sh = 0;
    __syncthreads();
    for (int base = 0; base < NN; base += 1024) {
        int i = base + t;
        int v = (i < NN) ? deg[i] : 0;
        int x = v;
#pragma unroll
        for (int off = 1; off < 64; off <<= 1) {
            int u = __shfl_up(x, off);
            if (lane >= off) x += u;
        }
        if (lane == 63) wsum[w] = x;
        __syncthreads();
        if (w == 0) {
            int y = (lane < 16) ? wsum[lane] : 0;
#pragma unroll
            for (int off = 1; off < 16; off <<= 1) {
                int u = __shfl_up(y, off);
                if (lane >= off) y += u;
            }
            if (lane < 16) wsum[lane] = y;
        }
        __syncthreads();
        int woff = (w > 0) ? wsum[w - 1] : 0;
        int incl = x + woff;
        int carry = carry_sh;
        if (i < NN) rowptr[i] = carry + incl - v;   // exclusive
        __syncthreads();
        if (t == 1023) carry_sh = carry + incl;
        __syncthreads();
    }
    if (t == 0) rowptr[NN] = carry_sh;
}

__global__ void __launch_bounds__(256) fill_kernel(const int* __restrict__ src,
                                                   const int* __restrict__ dst,
                                                   const int* __restrict__ rowptr,
                                                   int* __restrict__ cursor,
                                                   int* __restrict__ col) {
    int e = blockIdx.x * 256 + threadIdx.x;
    if (e >= NE) return;
    int d = dst[e];
    int p = atomicAdd(&cursor[d], 1);
    col[rowptr[d] + p] = src[e];
}

// ---------------- weight transpose/pack layout ----------------
#define WT_1L   0
#define WT_1R   16384
#define WT_2L   32768
#define WT_2R   49152
#define WT_HD   65536
#define WT_CLS  104448
#define WT_CONV 118784
#define WT_CV   126976
#define WT_TOTAL 134144

// bf16-input mode: single packed WT (overlays deg+cursor)
__global__ void __launch_bounds__(256) tr_all_kernel(
        const void* w1l, const void* w1r, const void* w2l, const void* w2r,
        const void* whd, const void* wclas, const void* wconv, const void* wcv,
        u16* __restrict__ wt, const int* __restrict__ flag) {
    if (!flag[0]) return;
    int idx = blockIdx.x * 256 + threadIdx.x;
    if (idx >= WT_TOTAL) return;
    const u16* src; int K, F, d;
    if      (idx < WT_1R)  { src = (const u16*)w1l;   K = 128; F = 128; d = idx - WT_1L; }
    else if (idx < WT_2L)  { src = (const u16*)w1r;   K = 128; F = 128; d = idx - WT_1R; }
    else if (idx < WT_2R)  { src = (const u16*)w2l;   K = 128; F = 128; d = idx - WT_2L; }
    else if (idx < WT_HD)  { src = (const u16*)w2r;   K = 128; F = 128; d = idx - WT_2R; }
    else if (idx < WT_CLS) { src = (const u16*)whd;   K = 128; F = 300; d = idx - WT_HD; }
    else if (idx < WT_CONV){ src = (const u16*)wclas; K = 128; F = 100; d = idx - WT_CLS; }
    else if (idx < WT_CV)  { src = (const u16*)wconv; K = 128; F = 64;  d = idx - WT_CONV; }
    else                   { src = (const u16*)wcv;   K = 64;  F = 100; d = idx - WT_CV; }
    int lgK = (K == 64) ? 6 : 7;
    int f = d >> lgK;
    int k = d & (K - 1);
    wt[idx] = (f < F) ? src[k * F + f] : (u16)0;
}

// f32-input mode: transposed hi/lo split weights (WT_CONV base fixed in r5)
__global__ void __launch_bounds__(256) tr_f32_kernel(
        const float* w1l, const float* w1r, const float* w2l, const float* w2r,
        const float* whd, const float* wclas, const float* wconv, const float* wcv,
        u16* __restrict__ wth, u16* __restrict__ wtlo, const int* __restrict__ flag) {
    if (flag[0]) return;
    int idx = blockIdx.x * 256 + threadIdx.x;
    if (idx >= WT_TOTAL) return;
    const float* src; int K, F, d;
    if      (idx < WT_1R)  { src = w1l;   K = 128; F = 128; d = idx - WT_1L; }
    else if (idx < WT_2L)  { src = w1r;   K = 128; F = 128; d = idx - WT_1R; }
    else if (idx < WT_2R)  { src = w2l;   K = 128; F = 128; d = idx - WT_2L; }
    else if (idx < WT_HD)  { src = w2r;   K = 128; F = 128; d = idx - WT_2R; }
    else if (idx < WT_CLS) { src = whd;   K = 128; F = 300; d = idx - WT_HD; }
    else if (idx < WT_CONV){ src = wclas; K = 128; F = 100; d = idx - WT_CLS; }
    else if (idx < WT_CV)  { src = wconv; K = 128; F = 64;  d = idx - WT_CONV; }
    else                   { src = wcv;   K = 64;  F = 100; d = idx - WT_CV; }
    int lgK = (K == 64) ? 6 : 7;
    int f = d >> lgK;
    int k = d & (K - 1);
    float v = (f < F) ? src[k * F + f] : 0.f;
    u16 h = f2bf_trunc(v);
    wth[idx]  = h;
    wtlo[idx] = f2bf(v - us2f(h));
}

// ---------------- ROUND-7: f32 -> bf16 activation conversion ----------------
__global__ void __launch_bounds__(256) cvt_bf_kernel(const float* __restrict__ x,
                                                     u16* __restrict__ y,
                                                     const int* __restrict__ flag) {
    if (flag[0]) return;
    size_t i = ((size_t)blockIdx.x * 256 + threadIdx.x) * 8;
    float4 a = *(const float4*)(x + i);
    float4 b = *(const float4*)(x + i + 4);
    union { u16 u[8]; uint4 v; } pk;
    pk.u[0] = f2bf(a.x); pk.u[1] = f2bf(a.y); pk.u[2] = f2bf(a.z); pk.u[3] = f2bf(a.w);
    pk.u[4] = f2bf(b.x); pk.u[5] = f2bf(b.y); pk.u[6] = f2bf(b.z); pk.u[7] = f2bf(b.w);
    *(uint4*)(y + i) = pk.v;
}

// ---------------- gather aggregation ----------------
// ROUND-7 (f32 mode): gather bf16 rows (half the bytes of f32), f32 accum,
// bf16 out. 4 neighbors/iter (16-lane groups, 8 channels/lane). [struct: r6]
__global__ void __launch_bounds__(256) agg_bfA_kernel(const u16* __restrict__ x,
                                                      const int* __restrict__ rowptr,
                                                      const int* __restrict__ col,
                                                      u16* __restrict__ aggm,
                                                      const int* __restrict__ flag) {
    if (flag[0]) return;
    int node = blockIdx.x * 4 + (threadIdx.x >> 6);
    int lane = threadIdx.x & 63;
    int q  = lane >> 4;           // quarter-group 0..3, one neighbor each
    int c0 = (lane & 15) * 8;     // 8 bf16 channels per lane (16 B)
    int beg = rowptr[node], end = rowptr[node + 1];
    float s[8] = {0.f, 0.f, 0.f, 0.f, 0.f, 0.f, 0.f, 0.f};
    int j = beg;
    for (; j + 4 <= end; j += 4) {
        int nbr = col[j + q];
        bf16x8 u = *(const bf16x8*)(x + (size_t)nbr * FDIM + c0);
#pragma unroll
        for (int m = 0; m < 8; ++m) s[m] += us2f((u16)u[m]);
    }
    int rem = end - j;
    if (q < rem) {
        int nbr = col[j + q];
        bf16x8 u = *(const bf16x8*)(x + (size_t)nbr * FDIM + c0);
#pragma unroll
        for (int m = 0; m < 8; ++m) s[m] += us2f((u16)u[m]);
    }
#pragma unroll
    for (int m = 0; m < 8; ++m) s[m] = qred(s[m]);
    if (q == 0) {
        float inv = 1.f / fmaxf((float)(end - beg), 1.f);
        union { u16 u[8]; uint4 v; } pk;
#pragma unroll
        for (int m = 0; m < 8; ++m) pk.u[m] = f2bf(s[m] * inv);
        *(uint4*)(aggm + (size_t)node * FDIM + c0) = pk.v;
    }
}

// bf16-input mode gather (flag=1): unchanged [validated r2]
__global__ void __launch_bounds__(256) aggb_kernel(const u16* __restrict__ xv,
                                                   const int* __restrict__ rowptr,
                                                   const int* __restrict__ col,
                                                   u16* __restrict__ aggm,
                                                   const int* __restrict__ flag) {
    if (!flag[0]) return;
    int node = blockIdx.x * 4 + (threadIdx.x >> 6);
    int lane = threadIdx.x & 63;
    int beg = rowptr[node], end = rowptr[node + 1];
    float a0 = 0.f, a1 = 0.f;
    for (int j = beg; j < end; ++j) {
        int nbr = col[j];
        ushort2 u = *(const ushort2*)(xv + (size_t)nbr * FDIM + lane * 2);
        a0 += us2f(u.x); a1 += us2f(u.y);
    }
    float inv = 1.f / fmaxf((float)(end - beg), 1.f);
    ushort2 o; o.x = f2bf(a0 * inv); o.y = f2bf(a1 * inv);
    *(ushort2*)(aggm + (size_t)node * FDIM + lane * 2) = o;
}

// ================= f32-input mode: bf16-activation MFMA path =================

// ROUND-7: h = relu(agg@Wl + x@Wr + b); A operands bf16 (direct load, no split),
// W hi+lo. 16 rows/block, waves split col-tiles [struct validated r3/r5].
// Out-of-place (featb/h1b -> h1b/h2b): no barrier needed.
__global__ void __launch_bounds__(256) sage_bfA_kernel(
        const u16* __restrict__ agg, const u16* __restrict__ x,
        const u16* __restrict__ wlh, const u16* __restrict__ wll,
        const u16* __restrict__ wrh, const u16* __restrict__ wrl,
        const float* __restrict__ bl, u16* __restrict__ hout,
        const int* __restrict__ flag) {
    if (flag[0]) return;
    int wid = threadIdx.x >> 6, lane = threadIdx.x & 63;
    int r0 = blockIdx.x * 16;
    int l15 = lane & 15;
    int koff = (lane >> 4) * 8;

    bf16x8 af[4], xf[4];
    const u16* ap = agg + (size_t)(r0 + l15) * FDIM + koff;
    const u16* xp = x   + (size_t)(r0 + l15) * FDIM + koff;
#pragma unroll
    for (int kf = 0; kf < 4; ++kf) {
        af[kf] = *(const bf16x8*)(ap + kf * 32);
        xf[kf] = *(const bf16x8*)(xp + kf * 32);
    }
    int orow = r0 + (lane >> 4) * 4;
#pragma unroll
    for (int tt = 0; tt < 2; ++tt) {
        int ct = wid * 2 + tt;
        f32x4 acc = {0.f, 0.f, 0.f, 0.f};
        const u16* pLh = wlh + (size_t)(ct * 16 + l15) * FDIM + koff;
        const u16* pLl = wll + (size_t)(ct * 16 + l15) * FDIM + koff;
        const u16* pRh = wrh + (size_t)(ct * 16 + l15) * FDIM + koff;
        const u16* pRl = wrl + (size_t)(ct * 16 + l15) * FDIM + koff;
#pragma unroll
        for (int kf = 0; kf < 4; ++kf) {
            int o0 = kf * 32;
            bf16x8 bLh = *(const bf16x8*)(pLh + o0);
            bf16x8 bLl = *(const bf16x8*)(pLl + o0);
            bf16x8 bRh = *(const bf16x8*)(pRh + o0);
            bf16x8 bRl = *(const bf16x8*)(pRl + o0);
            acc = MFMA16(af[kf], bLh, acc);
            acc = MFMA16(af[kf], bLl, acc);
            acc = MFMA16(xf[kf], bRh, acc);
            acc = MFMA16(xf[kf], bRl, acc);
        }
        int oc = ct * 16 + l15;
        float bv = bl[oc];
#pragma unroll
        for (int i = 0; i < 4; ++i) {
            float v = acc[i] + bv;
            hout[(size_t)(orow + i) * FDIM + oc] = f2bf(v > 0.f ? v : 0.f);
        }
    }
}

// epilogue for the fused 3-head kernel: global col-tile ct in [0,30)
// cols 0..303 -> fea_lab (HD) | 304..415 -> logists (NCLS) | 416..479 -> conv+BN+tanh
// ROUND-7: conv branch also emits bf16 tanh copy for headcv.
__device__ __forceinline__ void heads3_epi(int ct, int l15, int orow, const f32x4& acc,
        const float* bhd, const float* bclas, const float* bconv,
        const float* gamma, const float* beta, const float* rm, const float* rv,
        const float* wtl, float* out, size_t o_flab, size_t o_log, size_t o_tanh,
        u16* tanhb, float* tl) {
    int gcol = ct * 16 + l15;
    if (gcol < 304) {
        if (gcol < 300) {
            float bv = bhd[gcol];
#pragma unroll
            for (int i = 0; i < 4; ++i)
                out[o_flab + (size_t)(orow + i) * HD + gcol] = acc[i] + bv;
        }
    } else if (gcol < 416) {
        int lc = gcol - 304;
        if (lc < NCLS) {
            float bv = bclas[lc];
#pragma unroll
            for (int i = 0; i < 4; ++i)
                out[o_log + (size_t)(orow + i) * NCLS + lc] = acc[i] + bv;
        }
    } else {
        int lc = gcol - 416;
        float bv = bconv[lc];
        float g  = gamma[lc];
        float be = beta[lc];
        float m  = rm[lc];
        float rs = rsqrtf(rv[lc] + 1e-5f);
        float wv = wtl[lc];
#pragma unroll
        for (int i = 0; i < 4; ++i) {
            float p = g * (acc[i] + bv - m) * rs + be;
            float th = tanhf(p);
            out[o_tanh + (size_t)(orow + i) * NBITS + lc] = th;
            tanhb[(size_t)(orow + i) * NBITS + lc] = f2bf(th);
            tl[i] += p * wv;
        }
    }
}

// ROUND-7: fused heads; X = h2 bf16 (direct A load), W hi+lo (2 MFMA/kf).
// 16 rows/block, waves split tiles {0-7},{8-15},{16-22},{23-29} [struct r6].
__global__ void __launch_bounds__(256) heads3_bfA_kernel(
        const u16* __restrict__ X,
        const u16* __restrict__ wh, const u16* __restrict__ wl,
        const float* __restrict__ bhd, const float* __restrict__ bclas,
        const float* __restrict__ bconv,
        const float* __restrict__ gamma, const float* __restrict__ beta,
        const float* __restrict__ rm, const float* __restrict__ rv,
        const float* __restrict__ wtl, const float* __restrict__ btl,
        float* __restrict__ out, size_t o_flab, size_t o_log, size_t o_tanh, size_t o_tl,
        u16* __restrict__ tanhb, const int* __restrict__ flag) {
    if (flag[0]) return;
    int wid = threadIdx.x >> 6, lane = threadIdx.x & 63;
    int r0 = blockIdx.x * 16;
    int l15 = lane & 15;
    int koff = (lane >> 4) * 8;

    bf16x8 af[4];
    const u16* xp = X + (size_t)(r0 + l15) * FDIM + koff;
#pragma unroll
    for (int kf = 0; kf < 4; ++kf) af[kf] = *(const bf16x8*)(xp + kf * 32);

    int orow = r0 + (lane >> 4) * 4;
    float tl[4] = {0.f, 0.f, 0.f, 0.f};

    int t0 = (wid == 0) ? 0 : (wid == 1) ? 8 : (wid == 2) ? 16 : 23;
    int t1 = (wid == 0) ? 8 : (wid == 1) ? 16 : (wid == 2) ? 23 : 30;
    for (int ct = t0; ct < t1; ++ct) {
        f32x4 acc = {0.f, 0.f, 0.f, 0.f};
        const u16* ph = wh + (size_t)(ct * 16 + l15) * FDIM + koff;
        const u16* pl = wl + (size_t)(ct * 16 + l15) * FDIM + koff;
#pragma unroll
        for (int kf = 0; kf < 4; ++kf) {
            int o0 = kf * 32;
            bf16x8 bh = *(const bf16x8*)(ph + o0);
            bf16x8 bl2 = *(const bf16x8*)(pl + o0);
            acc = MFMA16(af[kf], bh, acc);
            acc = MFMA16(af[kf], bl2, acc);
        }
        heads3_epi(ct, l15, orow, acc, bhd, bclas, bconv, gamma, beta, rm, rv,
                   wtl, out, o_flab, o_log, o_tanh, tanhb, tl);
    }

    if (wid == 3) {   // true_lab: conv tiles (26-29) are wave-3-local
        float bt = btl[0];
#pragma unroll
        for (int i = 0; i < 4; ++i) {
            float t = tl[i];
            t += __shfl_xor(t, 1);
            t += __shfl_xor(t, 2);
            t += __shfl_xor(t, 4);
            t += __shfl_xor(t, 8);
            if (l15 == 0) out[o_tl + orow + i] = t + bt;
        }
    }
}

// ROUND-7: fea_convert = tanh_out @ wcv + bcv; X = tanhb bf16, K=64.
// 64 rows/block, wave owns rows, all 7 tiles [struct validated r2/r5].
__global__ void __launch_bounds__(256) headcv_bfA_kernel(
        const u16* __restrict__ X,
        const u16* __restrict__ wh, const u16* __restrict__ wl,
        const float* __restrict__ bcv, float* __restrict__ out, size_t o_fcv,
        const int* __restrict__ flag) {
    if (flag[0]) return;
    int wid = threadIdx.x >> 6, lane = threadIdx.x & 63;
    int r0 = blockIdx.x * 64 + wid * 16;
    if (r0 >= NN) return;
    int l15 = lane & 15;
    int koff = (lane >> 4) * 8;

    bf16x8 af[2];
    const u16* xp = X + (size_t)(r0 + l15) * NBITS + koff;
#pragma unroll
    for (int kf = 0; kf < 2; ++kf) af[kf] = *(const bf16x8*)(xp + kf * 32);

    int orow = r0 + (lane >> 4) * 4;
#pragma unroll
    for (int ct = 0; ct < 7; ++ct) {
        f32x4 acc = {0.f, 0.f, 0.f, 0.f};
        const u16* ph = wh + (size_t)(ct * 16 + l15) * NBITS + koff;
        const u16* pl = wl + (size_t)(ct * 16 + l15) * NBITS + koff;
#pragma unroll
        for (int kf = 0; kf < 2; ++kf) {
            int o0 = kf * 32;
            bf16x8 bh = *(const bf16x8*)(ph + o0);
            bf16x8 bl2 = *(const bf16x8*)(pl + o0);
            acc = MFMA16(af[kf], bh, acc);
            acc = MFMA16(af[kf], bl2, acc);
        }
        int oc = ct * 16 + l15;
        if (oc < NCLS) {
            float bv = bcv[oc];
#pragma unroll
            for (int i = 0; i < 4; ++i)
                out[o_fcv + (size_t)(orow + i) * NCLS + oc] = acc[i] + bv;
        }
    }
}

// ================= f32 vector fallback (only if workspace too small) ========
// f32 mode gather for fallback (r3-validated structure)
__global__ void __launch_bounds__(256) agg_f32_kernel(const float* __restrict__ x,
                                                      const int* __restrict__ rowptr,
                                                      const int* __restrict__ col,
                                                      float* __restrict__ aggm,
                                                      const int* __restrict__ flag) {
    if (flag[0]) return;
    int node = blockIdx.x * 4 + (threadIdx.x >> 6);
    int lane = threadIdx.x & 63;
    int half = lane >> 5;
    int c0 = (lane & 31) * 4;
    int beg = rowptr[node], end = rowptr[node + 1];
    float a0 = 0.f, a1 = 0.f, a2 = 0.f, a3 = 0.f;
    int j = beg;
    for (; j + 2 <= end; j += 2) {
        int nbr = col[j + half];
        float4 u = *(const float4*)(x + (size_t)nbr * FDIM + c0);
        a0 += u.x; a1 += u.y; a2 += u.z; a3 += u.w;
    }
    if (j < end && half == 0) {
        int nbr = col[j];
        float4 u = *(const float4*)(x + (size_t)nbr * FDIM + c0);
        a0 += u.x; a1 += u.y; a2 += u.z; a3 += u.w;
    }
    a0 += __shfl_xor(a0, 32);
    a1 += __shfl_xor(a1, 32);
    a2 += __shfl_xor(a2, 32);
    a3 += __shfl_xor(a3, 32);
    if (half == 0) {
        float inv = 1.f / fmaxf((float)(end - beg), 1.f);
        float4 o; o.x = a0 * inv; o.y = a1 * inv; o.z = a2 * inv; o.w = a3 * inv;
        *(float4*)(aggm + (size_t)node * FDIM + c0) = o;
    }
}

template <bool XBF, bool WBF>
__device__ __forceinline__ void sage_body(const float* aggm, const void* xv,
                                          const void* wl, const void* bl,
                                          const void* wr, float* hout) {
    __shared__ float ms[8][FDIM];
    __shared__ float xs[8][FDIM];
    int n0 = blockIdx.x * 8;
    int t = threadIdx.x;
    for (int idx = t; idx < 8 * FDIM; idx += 256) {
        int j = idx >> 7, k = idx & 127;
        int n = n0 + j;
        ms[j][k] = aggm[(size_t)n * FDIM + k];
        xs[j][k] = ldv<XBF>(xv, (size_t)n * FDIM + k);
    }
    __syncthreads();
    int f = t & 127;
    int h = t >> 7;
    float acc[4] = {0.f, 0.f, 0.f, 0.f};
    for (int k = 0; k < FDIM; ++k) {
        float wlv = ldv<WBF>(wl, k * FDIM + f);
        float wrv = ldv<WBF>(wr, k * FDIM + f);
#pragma unroll
        for (int j = 0; j < 4; ++j) {
            int nn = h + j * 2;
            acc[j] += ms[nn][k] * wlv + xs[nn][k] * wrv;
        }
    }
    float bv = ldv<WBF>(bl, f);
#pragma unroll
    for (int j = 0; j < 4; ++j) {
        int nn = h + j * 2;
        float v = acc[j] + bv;
        hout[(size_t)(n0 + nn) * FDIM + f] = v > 0.f ? v : 0.f;
    }
}

__global__ void __launch_bounds__(256) sage_f32_kernel(const float* aggm, const float* x,
                                                       const void* wl, const void* bl,
                                                       const void* wr, float* hout,
                                                       const int* flag) {
    if (flag[0]) return;
    sage_body<false, false>(aggm, x, wl, bl, wr, hout);
}

template <int KDIM, bool TANH_IN, bool BF>
__device__ __forceinline__ void head_body(const float* X, const void* W, const void* B,
                                          void* Y, size_t yoff, int fout,
                                          const void* gamma, const void* beta,
                                          const void* rm, const void* rv,
                                          float* pre_ws, int mode) {
    __shared__ float xs[16][KDIM];
    int n0 = blockIdx.x * 16;
    int t = threadIdx.x;
    for (int idx = t; idx < 16 * KDIM; idx += 256) {
        int j = idx / KDIM, k = idx % KDIM;
        float v = X[(size_t)(n0 + j) * KDIM + k];
        xs[j][k] = TANH_IN ? tanhf(v) : v;
    }
    __syncthreads();
    for (int f = t; f < fout; f += 256) {
        float acc[16];
#pragma unroll
        for (int j = 0; j < 16; ++j) acc[j] = 0.f;
        for (int k = 0; k < KDIM; ++k) {
            float wv = ldv<BF>(W, (size_t)k * fout + f);
#pragma unroll
            for (int j = 0; j < 16; ++j) acc[j] += xs[j][k] * wv;
        }
        float bv = ldv<BF>(B, f);
        if (mode == 0) {
#pragma unroll
            for (int j = 0; j < 16; ++j)
                stv<BF>(Y, yoff + (size_t)(n0 + j) * fout + f, acc[j] + bv);
        } else {
            float g  = ldv<BF>(gamma, f);
            float be = ldv<BF>(beta, f);
            float m  = ldv<BF>(rm, f);
            float rs = rsqrtf(ldv<BF>(rv, f) + 1e-5f);
#pragma unroll
            for (int j = 0; j < 16; ++j) {
                float p = g * (acc[j] + bv - m) * rs + be;
                pre_ws[(size_t)(n0 + j) * fout + f] = p;
                stv<BF>(Y, yoff + (size_t)(n0 + j) * fout + f, tanhf(p));
            }
        }
    }
}

template <int KDIM, bool TANH_IN>
__global__ void __launch_bounds__(256) head_f32_kernel(const float* X, const void* W,
                                                       const void* B, void* Y, size_t yoff,
                                                       int fout, const void* gamma,
                                                       const void* beta, const void* rm,
                                                       const void* rv, float* pre_ws,
                                                       int mode, const int* flag) {
    if (flag[0]) return;
    head_body<KDIM, TANH_IN, false>(X, W, B, Y, yoff, fout, gamma, beta, rm, rv, pre_ws, mode);
}

template <bool BF>
__device__ __forceinline__ void tl_body(const float* pre, const void* wtl,
                                        const void* btl, void* y, size_t yoff) {
    int i = blockIdx.x * 256 + threadIdx.x;
    if (i >= NN) return;
    float s = ldv<BF>(btl, 0);
#pragma unroll 8
    for (int k = 0; k < NBITS; ++k) s += pre[(size_t)i * NBITS + k] * ldv<BF>(wtl, k);
    stv<BF>(y, yoff + i, s);
}

__global__ void __launch_bounds__(256) true_lab_f32_kernel(const float* pre, const void* wtl,
                                                           const void* btl, void* y,
                                                           size_t yoff, const int* flag) {
    if (flag[0]) return;
    tl_body<false>(pre, wtl, btl, y, yoff);
}

// ================= bf16-input mode (flag=1) MFMA path =================
__global__ void __launch_bounds__(256) sage_mfma_kernel(
        const u16* __restrict__ agg, const u16* __restrict__ x,
        const u16* __restrict__ wtl, const u16* __restrict__ wtr,
        const void* __restrict__ bl, u16* __restrict__ hout,
        const int* __restrict__ flag) {
    if (!flag[0]) return;
    int wid = threadIdx.x >> 6, lane = threadIdx.x & 63;
    int r0 = blockIdx.x * 64 + wid * 16;
    if (r0 >= NN) return;
    int l15 = lane & 15;
    int koff = (lane >> 4) * 8;

    bf16x8 af[4], xf[4];
    const u16* ap = agg + (size_t)(r0 + l15) * FDIM + koff;
    const u16* xp = x   + (size_t)(r0 + l15) * FDIM + koff;
#pragma unroll
    for (int kf = 0; kf < 4; ++kf) {
        af[kf] = *(const bf16x8*)(ap + kf * 32);
        xf[kf] = *(const bf16x8*)(xp + kf * 32);
    }
    int orow = r0 + (lane >> 4) * 4;
    for (int ct = 0; ct < 8; ++ct) {
        int c0 = ct * 16;
        f32x4 acc = {0.f, 0.f, 0.f, 0.f};
        const u16* blp = wtl + (size_t)(c0 + l15) * FDIM + koff;
        const u16* brp = wtr + (size_t)(c0 + l15) * FDIM + koff;
#pragma unroll
        for (int kf = 0; kf < 4; ++kf) {
            bf16x8 bL = *(const bf16x8*)(blp + kf * 32);
            bf16x8 bR = *(const bf16x8*)(brp + kf * 32);
            acc = MFMA16(af[kf], bL, acc);
            acc = MFMA16(xf[kf], bR, acc);
        }
        int ocol = c0 + l15;
        float bv = us2f(((const u16*)bl)[ocol]);
#pragma unroll
        for (int i = 0; i < 4; ++i) {
            float v = acc[i] + bv;
            hout[(size_t)(orow + i) * FDIM + ocol] = f2bf(v > 0.f ? v : 0.f);
        }
    }
}

template <int K, int FP>
__global__ void __launch_bounds__(256) head_mfma_kernel(
        const u16* __restrict__ X, const u16* __restrict__ WT,
        const void* __restrict__ B, void* __restrict__ Y, size_t yoff,
        int fout, const int* __restrict__ flag) {
    if (!flag[0]) return;
    int wid = threadIdx.x >> 6, lane = threadIdx.x & 63;
    int r0 = blockIdx.x * 64 + wid * 16;
    if (r0 >= NN) return;
    int l15 = lane & 15;
    int koff = (lane >> 4) * 8;

    bf16x8 af[K / 32];
    const u16* xp = X + (size_t)(r0 + l15) * K + koff;
#pragma unroll
    for (int kf = 0; kf < K / 32; ++kf) af[kf] = *(const bf16x8*)(xp + kf * 32);

    u16* y = (u16*)Y + yoff;
    int orow = r0 + (lane >> 4) * 4;
    for (int ct = 0; ct < FP / 16; ++ct) {
        int c0 = ct * 16;
        f32x4 acc = {0.f, 0.f, 0.f, 0.f};
        const u16* bp = WT + (size_t)(c0 + l15) * K + koff;
#pragma unroll
        for (int kf = 0; kf < K / 32; ++kf) {
            bf16x8 bF = *(const bf16x8*)(bp + kf * 32);
            acc = MFMA16(af[kf], bF, acc);
        }
        int ocol = c0 + l15;
        if (ocol < fout) {
            float bv = us2f(((const u16*)B)[ocol]);
#pragma unroll
            for (int i = 0; i < 4; ++i)
                y[(size_t)(orow + i) * fout + ocol] = f2bf(acc[i] + bv);
        }
    }
}

__global__ void __launch_bounds__(256) headconv_mfma_kernel(
        const u16* __restrict__ X, const u16* __restrict__ WT,
        const void* __restrict__ B, const void* __restrict__ gamma,
        const void* __restrict__ beta, const void* __restrict__ rm,
        const void* __restrict__ rv, float* __restrict__ pre,
        void* __restrict__ Y, size_t yoff, const int* __restrict__ flag) {
    if (!flag[0]) return;
    int wid = threadIdx.x >> 6, lane = threadIdx.x & 63;
    int r0 = blockIdx.x * 64 + wid * 16;
    if (r0 >= NN) return;
    int l15 = lane & 15;
    int koff = (lane >> 4) * 8;

    bf16x8 af[4];
    const u16* xp = X + (size_t)(r0 + l15) * FDIM + koff;
#pragma unroll
    for (int kf = 0; kf < 4; ++kf) af[kf] = *(const bf16x8*)(xp + kf * 32);

    u16* y = (u16*)Y + yoff;
    int orow = r0 + (lane >> 4) * 4;
    for (int ct = 0; ct < 4; ++ct) {
        int c0 = ct * 16;
        f32x4 acc = {0.f, 0.f, 0.f, 0.f};
        const u16* bp = WT + (size_t)(c0 + l15) * FDIM + koff;
#pragma unroll
        for (int kf = 0; kf < 4; ++kf) {
            bf16x8 bF = *(const bf16x8*)(bp + kf * 32);
            acc = MFMA16(af[kf], bF, acc);
        }
        int ocol = c0 + l15;
        float bv = us2f(((const u16*)B)[ocol]);
        float g  = us2f(((const u16*)gamma)[ocol]);
        float be = us2f(((const u16*)beta)[ocol]);
        float m  = us2f(((const u16*)rm)[ocol]);
        float rs = rsqrtf(us2f(((const u16*)rv)[ocol]) + 1e-5f);
#pragma unroll
        for (int i = 0; i < 4; ++i) {
            float p = g * (acc[i] + bv - m) * rs + be;
            pre[(size_t)(orow + i) * NBITS + ocol] = p;
            y[(size_t)(orow + i) * NBITS + ocol] = f2bf(tanhf(p));
        }
    }
}

__global__ void __launch_bounds__(256) true_lab_b16_kernel(const float* pre, const void* wtl,
                                                           const void* btl, void* y,
                                                           size_t yoff, const int* flag) {
    if (!flag[0]) return;
    tl_body<true>(pre, wtl, btl, y, yoff);
}

extern "C" void kernel_launch(void* const* d_in, const int* in_sizes, int n_in,
                              void* d_out, int out_size, void* d_ws, size_t ws_size,
                              hipStream_t stream) {
    const void* feat = d_in[0];
    const int* edges = (const int*)d_in[1];
    const void* w1l = d_in[2];
    const void* b1l = d_in[3];
    const void* w1r = d_in[4];
    const void* w2l = d_in[5];
    const void* b2l = d_in[6];
    const void* w2r = d_in[7];
    const void* whd = d_in[8];
    const void* bhd = d_in[9];
    const void* wclas = d_in[10];
    const void* bclas = d_in[11];
    const void* wconv = d_in[12];
    const void* bconv = d_in[13];
    const void* gamma = d_in[14];
    const void* beta  = d_in[15];
    const void* rm  = d_in[16];
    const void* rv  = d_in[17];
    const void* wtl = d_in[18];
    const void* btl = d_in[19];
    const void* wcv = d_in[20];
    const void* bcv = d_in[21];

    int* iw     = (int*)d_ws;
    int* flag   = iw;
    int* deg    = iw + 16;
    int* cursor = deg + NN;
    int* rowptr = cursor + NN;
    int* col    = rowptr + 50016;
    float* buf1 = (float*)(col + NE);
    float* buf2 = buf1 + (size_t)NN * FDIM;
    float* pre_f = buf1;                       // fallback path only

    u16* wtf_hi = (u16*)(buf2 + (size_t)NN * FDIM);
    u16* wtf_lo = wtf_hi + WT_TOTAL;
    size_t need = (size_t)(16 + NN + NN + 50016 + NE) * 4
                + 2 * (size_t)NN * FDIM * 4
                + 2 * (size_t)WT_TOTAL * 2;
    bool mfma_ok = ws_size >= need;

    // ROUND-7 f32-mode bf16 activation overlays (same footprint as buf1+buf2):
    //   region A (buf1 lo): featb bf16 | tanhb overlays A after sage1
    //   region B (buf1 hi): h1b bf16
    //   region C (buf2 lo): aggX bf16 (shared gather output, both layers)
    //   region D (buf2 hi): h2b bf16
    u16* featb = (u16*)buf1;
    u16* h1b   = featb + (size_t)NN * FDIM;
    u16* aggX  = (u16*)buf2;
    u16* h2b   = aggX + (size_t)NN * FDIM;
    u16* tanhb = featb;   // reuse region A (featb dead after sage1)

    // bf16-input mode overlays (unchanged)
    u16* aggb = (u16*)buf1;
    u16* hb1  = aggb + (size_t)NN * FDIM;
    u16* hb2  = (u16*)buf2;
    float* pre_b = buf2 + (size_t)NN * 64;

    u16* wt = (u16*)deg;   // bf16-mode packed WT (268 KB < 400 KB deg+cursor)

    const int* src = edges;
    const int* dst = edges + NE;

    hipMemsetAsync(iw, 0, (size_t)(16 + 2 * NN) * sizeof(int), stream);

    detect_kernel<<<1, 256, 0, stream>>>((const unsigned short*)feat, flag);

    // CSR build
    deg_kernel<<<(NE + 255) / 256, 256, 0, stream>>>(dst, deg);
    scan_kernel<<<1, 1024, 0, stream>>>(deg, rowptr);
    fill_kernel<<<(NE + 255) / 256, 256, 0, stream>>>(src, dst, rowptr, cursor, col);

    // output element offsets: logists | tanh_out | fea_lab | fea_convert | true_lab
    size_t o_log  = 0;
    size_t o_tanh = (size_t)NN * NCLS;
    size_t o_flab = o_tanh + (size_t)NN * NBITS;
    size_t o_fcv  = o_flab + (size_t)NN * HD;
    size_t o_tl   = o_fcv + (size_t)NN * NCLS;

    const int GR = (NN + 63) / 64;    // 64 rows/block kernels
    const int RB = NN / 16;           // 16 rows/block kernels = 3125

    // ---------------- bf16-input MFMA path (flag=1) ----------------
    tr_all_kernel<<<(WT_TOTAL + 255) / 256, 256, 0, stream>>>(
        w1l, w1r, w2l, w2r, whd, wclas, wconv, wcv, wt, flag);
    aggb_kernel<<<NN / 4, 256, 0, stream>>>((const u16*)feat, rowptr, col, aggb, flag);
    sage_mfma_kernel<<<GR, 256, 0, stream>>>(aggb, (const u16*)feat, wt + WT_1L, wt + WT_1R, b1l, hb1, flag);
    aggb_kernel<<<NN / 4, 256, 0, stream>>>(hb1, rowptr, col, aggb, flag);
    sage_mfma_kernel<<<GR, 256, 0, stream>>>(aggb, hb1, wt + WT_2L, wt + WT_2R, b2l, hb2, flag);
    head_mfma_kernel<128, 304><<<GR, 256, 0, stream>>>(hb2, wt + WT_HD, bhd, d_out, o_flab, HD, flag);
    head_mfma_kernel<128, 112><<<GR, 256, 0, stream>>>(hb2, wt + WT_CLS, bclas, d_out, o_log, NCLS, flag);
    headconv_mfma_kernel<<<GR, 256, 0, stream>>>(hb2, wt + WT_CONV, bconv, gamma, beta, rm, rv,
                                                 pre_b, d_out, o_tanh, flag);
    head_mfma_kernel<64, 112><<<GR, 256, 0, stream>>>((const u16*)d_out + o_tanh, wt + WT_CV, bcv,
                                                      d_out, o_fcv, NCLS, flag);
    true_lab_b16_kernel<<<(NN + 255) / 256, 256, 0, stream>>>(pre_b, wtl, btl, d_out, o_tl, flag);

    // ---------------- f32-input path (flag=0): bf16 activations ----------------
    if (mfma_ok) {
        tr_f32_kernel<<<(WT_TOTAL + 255) / 256, 256, 0, stream>>>(
            (const float*)w1l, (const float*)w1r, (const float*)w2l, (const float*)w2r,
            (const float*)whd, (const float*)wclas, (const float*)wconv, (const float*)wcv,
            wtf_hi, wtf_lo, flag);

        cvt_bf_kernel<<<RB, 256, 0, stream>>>((const float*)feat, featb, flag);

        agg_bfA_kernel<<<NN / 4, 256, 0, stream>>>(featb, rowptr, col, aggX, flag);
        sage_bfA_kernel<<<RB, 256, 0, stream>>>(
            aggX, featb,
            wtf_hi + WT_1L, wtf_lo + WT_1L, wtf_hi + WT_1R, wtf_lo + WT_1R,
            (const float*)b1l, h1b, flag);
        agg_bfA_kernel<<<NN / 4, 256, 0, stream>>>(h1b, rowptr, col, aggX, flag);
        sage_bfA_kernel<<<RB, 256, 0, stream>>>(
            aggX, h1b,
            wtf_hi + WT_2L, wtf_lo + WT_2L, wtf_hi + WT_2R, wtf_lo + WT_2R,
            (const float*)b2l, h2b, flag);

        heads3_bfA_kernel<<<RB, 256, 0, stream>>>(
            h2b, wtf_hi + WT_HD, wtf_lo + WT_HD,
            (const float*)bhd, (const float*)bclas, (const float*)bconv,
            (const float*)gamma, (const float*)beta, (const float*)rm, (const float*)rv,
            (const float*)wtl, (const float*)btl,
            (float*)d_out, o_flab, o_log, o_tanh, o_tl, tanhb, flag);
        headcv_bfA_kernel<<<GR, 256, 0, stream>>>(
            tanhb, wtf_hi + WT_CV, wtf_lo + WT_CV,
            (const float*)bcv, (float*)d_out, o_fcv, flag);
    } else {
        // fallback: original vector path (workspace too small for split weights)
        agg_f32_kernel<<<NN / 4, 256, 0, stream>>>((const float*)feat, rowptr, col, buf1, flag);
        sage_f32_kernel<<<NN / 8, 256, 0, stream>>>(buf1, (const float*)feat, w1l, b1l, w1r, buf1, flag);
        agg_f32_kernel<<<NN / 4, 256, 0, stream>>>(buf1, rowptr, col, buf2, flag);
        sage_f32_kernel<<<NN / 8, 256, 0, stream>>>(buf2, buf1, w2l, b2l, w2r, buf2, flag);

        head_f32_kernel<FDIM, false><<<NN / 16, 256, 0, stream>>>(
            buf2, whd, bhd, d_out, o_flab, HD,
            nullptr, nullptr, nullptr, nullptr, nullptr, 0, flag);
        head_f32_kernel<FDIM, false><<<NN / 16, 256, 0, stream>>>(
            buf2, wclas, bclas, d_out, o_log, NCLS,
            nullptr, nullptr, nullptr, nullptr, nullptr, 0, flag);
        head_f32_kernel<FDIM, false><<<NN / 16, 256, 0, stream>>>(
            buf2, wconv, bconv, d_out, o_tanh, NBITS,
            gamma, beta, rm, rv, pre_f, 1, flag);
        head_f32_kernel<NBITS, true><<<NN / 16, 256, 0, stream>>>(
            pre_f, wcv, bcv, d_out, o_fcv, NCLS,
            nullptr, nullptr, nullptr, nullptr, nullptr, 0, flag);
        true_lab_f32_kernel<<<(NN + 255) / 256, 256, 0, stream>>>(pre_f, wtl, btl, d_out, o_tl, flag);
    }
}

// Round 8
// 557.201 us; speedup vs baseline: 1.8012x; 1.1437x over previous
//
#include <hip/hip_runtime.h>
#include <hip/hip_bf16.h>
#include <math.h>

#define NN 50000
#define NE 800000
#define FDIM 128
#define NBITS 64
#define NCLS 100
#define HD 300

typedef unsigned short u16;
typedef __attribute__((ext_vector_type(8))) short bf16x8;
typedef __attribute__((ext_vector_type(4))) float f32x4;

#define MFMA16(a, b, c) __builtin_amdgcn_mfma_f32_16x16x32_bf16((a), (b), (c), 0, 0, 0)

__device__ __forceinline__ float us2f(unsigned short u) {
    union { unsigned int i; float f; } x; x.i = ((unsigned int)u) << 16; return x.f;
}
__device__ __forceinline__ unsigned short f2bf(float f) {
    union { float f; unsigned int i; } x; x.f = f;
    unsigned int i = x.i;
    i += 0x7fffu + ((i >> 16) & 1u);   // round-to-nearest-even
    return (unsigned short)(i >> 16);
}
__device__ __forceinline__ unsigned short f2bf_trunc(float f) {
    union { float f; unsigned int i; } x; x.f = f;
    return (unsigned short)(x.i >> 16);   // round-toward-zero
}

template <bool BF>
__device__ __forceinline__ float ldv(const void* p, size_t i) {
    return BF ? us2f(((const unsigned short*)p)[i]) : ((const float*)p)[i];
}
template <bool BF>
__device__ __forceinline__ void stv(void* p, size_t i, float v) {
    if (BF) ((unsigned short*)p)[i] = f2bf(v);
    else    ((float*)p)[i] = v;
}

// quarter-group reduction: sum across the 4 sixteen-lane groups of a wave
__device__ __forceinline__ float qred(float v) {
    v += __shfl_xor(v, 16);
    v += __shfl_xor(v, 32);
    return v;
}

// ---------------- dtype detection (flag=1 => bf16 buffers) ----------------
__global__ void __launch_bounds__(256) detect_kernel(const unsigned short* __restrict__ f,
                                                     int* __restrict__ flag) {
    __shared__ int bad;
    if (threadIdx.x == 0) bad = 0;
    __syncthreads();
    int b = 0;
    for (int i = threadIdx.x; i < 4096; i += 256) {
        float v = us2f(f[i]);
        if (!(fabsf(v) < 1e4f)) b = 1;   // catches NaN too
    }
    if (b) atomicOr(&bad, 1);
    __syncthreads();
    if (threadIdx.x == 0) flag[0] = bad ? 0 : 1;
}

// ---------------- CSR build ----------------
__global__ void __launch_bounds__(256) deg_kernel(const int* __restrict__ dst,
                                                  int* __restrict__ deg) {
    int e = blockIdx.x * 256 + threadIdx.x;
    if (e < NE) atomicAdd(&deg[dst[e]], 1);
}

__global__ void __launch_bounds__(1024) scan_kernel(const int* __restrict__ deg,
                                                    int* __restrict__ rowptr) {
    __shared__ int wsum[16];
    __shared__ int carry_sh;
    int t = threadIdx.x;
    int lane = t & 63;
    int w = t >> 6;
    if (t == 0) carry_sh = 0;
    __syncthreads();
    for (int base = 0; base < NN; base += 1024) {
        int i = base + t;
        int v = (i < NN) ? deg[i] : 0;
        int x = v;
#pragma unroll
        for (int off = 1; off < 64; off <<= 1) {
            int u = __shfl_up(x, off);
            if (lane >= off) x += u;
        }
        if (lane == 63) wsum[w] = x;
        __syncthreads();
        if (w == 0) {
            int y = (lane < 16) ? wsum[lane] : 0;
#pragma unroll
            for (int off = 1; off < 16; off <<= 1) {
                int u = __shfl_up(y, off);
                if (lane >= off) y += u;
            }
            if (lane < 16) wsum[lane] = y;
        }
        __syncthreads();
        int woff = (w > 0) ? wsum[w - 1] : 0;
        int incl = x + woff;
        int carry = carry_sh;
        if (i < NN) rowptr[i] = carry + incl - v;   // exclusive
        __syncthreads();
        if (t == 1023) carry_sh = carry + incl;
        __syncthreads();
    }
    if (t == 0) rowptr[NN] = carry_sh;
}

__global__ void __launch_bounds__(256) fill_kernel(const int* __restrict__ src,
                                                   const int* __restrict__ dst,
                                                   const int* __restrict__ rowptr,
                                                   int* __restrict__ cursor,
                                                   int* __restrict__ col) {
    int e = blockIdx.x * 256 + threadIdx.x;
    if (e >= NE) return;
    int d = dst[e];
    int p = atomicAdd(&cursor[d], 1);
    col[rowptr[d] + p] = src[e];
}

// ---------------- weight transpose/pack layout ----------------
#define WT_1L   0
#define WT_1R   16384
#define WT_2L   32768
#define WT_2R   49152
#define WT_HD   65536
#define WT_CLS  104448
#define WT_CONV 118784
#define WT_CV   126976
#define WT_TOTAL 134144

// bf16-input mode: single packed WT (overlays deg+cursor)
__global__ void __launch_bounds__(256) tr_all_kernel(
        const void* w1l, const void* w1r, const void* w2l, const void* w2r,
        const void* whd, const void* wclas, const void* wconv, const void* wcv,
        u16* __restrict__ wt, const int* __restrict__ flag) {
    if (!flag[0]) return;
    int idx = blockIdx.x * 256 + threadIdx.x;
    if (idx >= WT_TOTAL) return;
    const u16* src; int K, F, d;
    if      (idx < WT_1R)  { src = (const u16*)w1l;   K = 128; F = 128; d = idx - WT_1L; }
    else if (idx < WT_2L)  { src = (const u16*)w1r;   K = 128; F = 128; d = idx - WT_1R; }
    else if (idx < WT_2R)  { src = (const u16*)w2l;   K = 128; F = 128; d = idx - WT_2L; }
    else if (idx < WT_HD)  { src = (const u16*)w2r;   K = 128; F = 128; d = idx - WT_2R; }
    else if (idx < WT_CLS) { src = (const u16*)whd;   K = 128; F = 300; d = idx - WT_HD; }
    else if (idx < WT_CONV){ src = (const u16*)wclas; K = 128; F = 100; d = idx - WT_CLS; }
    else if (idx < WT_CV)  { src = (const u16*)wconv; K = 128; F = 64;  d = idx - WT_CONV; }
    else                   { src = (const u16*)wcv;   K = 64;  F = 100; d = idx - WT_CV; }
    int lgK = (K == 64) ? 6 : 7;
    int f = d >> lgK;
    int k = d & (K - 1);
    wt[idx] = (f < F) ? src[k * F + f] : (u16)0;
}

// f32-input mode: transposed hi/lo split weights (WT_CONV base fixed in r5)
__global__ void __launch_bounds__(256) tr_f32_kernel(
        const float* w1l, const float* w1r, const float* w2l, const float* w2r,
        const float* whd, const float* wclas, const float* wconv, const float* wcv,
        u16* __restrict__ wth, u16* __restrict__ wtlo, const int* __restrict__ flag) {
    if (flag[0]) return;
    int idx = blockIdx.x * 256 + threadIdx.x;
    if (idx >= WT_TOTAL) return;
    const float* src; int K, F, d;
    if      (idx < WT_1R)  { src = w1l;   K = 128; F = 128; d = idx - WT_1L; }
    else if (idx < WT_2L)  { src = w1r;   K = 128; F = 128; d = idx - WT_1R; }
    else if (idx < WT_2R)  { src = w2l;   K = 128; F = 128; d = idx - WT_2L; }
    else if (idx < WT_HD)  { src = w2r;   K = 128; F = 128; d = idx - WT_2R; }
    else if (idx < WT_CLS) { src = whd;   K = 128; F = 300; d = idx - WT_HD; }
    else if (idx < WT_CONV){ src = wclas; K = 128; F = 100; d = idx - WT_CLS; }
    else if (idx < WT_CV)  { src = wconv; K = 128; F = 64;  d = idx - WT_CONV; }
    else                   { src = wcv;   K = 64;  F = 100; d = idx - WT_CV; }
    int lgK = (K == 64) ? 6 : 7;
    int f = d >> lgK;
    int k = d & (K - 1);
    float v = (f < F) ? src[k * F + f] : 0.f;
    u16 h = f2bf_trunc(v);
    wth[idx]  = h;
    wtlo[idx] = f2bf(v - us2f(h));
}

// ---------------- f32 -> bf16 activation conversion ----------------
__global__ void __launch_bounds__(256) cvt_bf_kernel(const float* __restrict__ x,
                                                     u16* __restrict__ y,
                                                     const int* __restrict__ flag) {
    if (flag[0]) return;
    size_t i = ((size_t)blockIdx.x * 256 + threadIdx.x) * 8;
    float4 a = *(const float4*)(x + i);
    float4 b = *(const float4*)(x + i + 4);
    union { u16 u[8]; uint4 v; } pk;
    pk.u[0] = f2bf(a.x); pk.u[1] = f2bf(a.y); pk.u[2] = f2bf(a.z); pk.u[3] = f2bf(a.w);
    pk.u[4] = f2bf(b.x); pk.u[5] = f2bf(b.y); pk.u[6] = f2bf(b.z); pk.u[7] = f2bf(b.w);
    *(uint4*)(y + i) = pk.v;
}

// ---------------- gather aggregation ----------------
// ROUND-8: 8 neighbors in flight (two batches of 4) for deeper MLP.
__global__ void __launch_bounds__(256) agg_bfA_kernel(const u16* __restrict__ x,
                                                      const int* __restrict__ rowptr,
                                                      const int* __restrict__ col,
                                                      u16* __restrict__ aggm,
                                                      const int* __restrict__ flag) {
    if (flag[0]) return;
    int node = blockIdx.x * 4 + (threadIdx.x >> 6);
    int lane = threadIdx.x & 63;
    int q  = lane >> 4;           // quarter-group 0..3, one neighbor each
    int c0 = (lane & 15) * 8;     // 8 bf16 channels per lane (16 B)
    int beg = rowptr[node], end = rowptr[node + 1];
    float s[8] = {0.f, 0.f, 0.f, 0.f, 0.f, 0.f, 0.f, 0.f};
    int j = beg;
    for (; j + 8 <= end; j += 8) {
        int n0 = col[j + q];
        int n1 = col[j + 4 + q];
        bf16x8 u0 = *(const bf16x8*)(x + (size_t)n0 * FDIM + c0);
        bf16x8 u1 = *(const bf16x8*)(x + (size_t)n1 * FDIM + c0);
#pragma unroll
        for (int m = 0; m < 8; ++m) s[m] += us2f((u16)u0[m]);
#pragma unroll
        for (int m = 0; m < 8; ++m) s[m] += us2f((u16)u1[m]);
    }
    for (; j + 4 <= end; j += 4) {
        int nbr = col[j + q];
        bf16x8 u = *(const bf16x8*)(x + (size_t)nbr * FDIM + c0);
#pragma unroll
        for (int m = 0; m < 8; ++m) s[m] += us2f((u16)u[m]);
    }
    int rem = end - j;
    if (q < rem) {
        int nbr = col[j + q];
        bf16x8 u = *(const bf16x8*)(x + (size_t)nbr * FDIM + c0);
#pragma unroll
        for (int m = 0; m < 8; ++m) s[m] += us2f((u16)u[m]);
    }
#pragma unroll
    for (int m = 0; m < 8; ++m) s[m] = qred(s[m]);
    if (q == 0) {
        float inv = 1.f / fmaxf((float)(end - beg), 1.f);
        union { u16 u[8]; uint4 v; } pk;
#pragma unroll
        for (int m = 0; m < 8; ++m) pk.u[m] = f2bf(s[m] * inv);
        *(uint4*)(aggm + (size_t)node * FDIM + c0) = pk.v;
    }
}

// bf16-input mode gather (flag=1): unchanged [validated r2]
__global__ void __launch_bounds__(256) aggb_kernel(const u16* __restrict__ xv,
                                                   const int* __restrict__ rowptr,
                                                   const int* __restrict__ col,
                                                   u16* __restrict__ aggm,
                                                   const int* __restrict__ flag) {
    if (!flag[0]) return;
    int node = blockIdx.x * 4 + (threadIdx.x >> 6);
    int lane = threadIdx.x & 63;
    int beg = rowptr[node], end = rowptr[node + 1];
    float a0 = 0.f, a1 = 0.f;
    for (int j = beg; j < end; ++j) {
        int nbr = col[j];
        ushort2 u = *(const ushort2*)(xv + (size_t)nbr * FDIM + lane * 2);
        a0 += us2f(u.x); a1 += us2f(u.y);
    }
    float inv = 1.f / fmaxf((float)(end - beg), 1.f);
    ushort2 o; o.x = f2bf(a0 * inv); o.y = f2bf(a1 * inv);
    *(ushort2*)(aggm + (size_t)node * FDIM + lane * 2) = o;
}

// ================= f32-input mode: bf16-activation MFMA path =================

// ROUND-8: h = relu(agg@Wl + x@Wr + b); 32 rows/block (2 row-groups share one
// B-fragment stream -> 2 independent MFMA chains, half the panel re-stream).
// Waves split the 8 col-tiles (2 each) [struct validated r3/r5/r7].
__global__ void __launch_bounds__(256) sage_bfA_kernel(
        const u16* __restrict__ agg, const u16* __restrict__ x,
        const u16* __restrict__ wlh, const u16* __restrict__ wll,
        const u16* __restrict__ wrh, const u16* __restrict__ wrl,
        const float* __restrict__ bl, u16* __restrict__ hout,
        const int* __restrict__ flag) {
    if (flag[0]) return;
    int wid = threadIdx.x >> 6, lane = threadIdx.x & 63;
    int r0 = blockIdx.x * 32;
    bool g2 = (r0 + 16) < NN;
    int r1 = g2 ? (r0 + 16) : r0;   // clamp A-loads when group2 invalid
    int l15 = lane & 15;
    int koff = (lane >> 4) * 8;

    bf16x8 af1[4], xf1[4], af2[4], xf2[4];
    const u16* ap1 = agg + (size_t)(r0 + l15) * FDIM + koff;
    const u16* xp1 = x   + (size_t)(r0 + l15) * FDIM + koff;
    const u16* ap2 = agg + (size_t)(r1 + l15) * FDIM + koff;
    const u16* xp2 = x   + (size_t)(r1 + l15) * FDIM + koff;
#pragma unroll
    for (int kf = 0; kf < 4; ++kf) {
        af1[kf] = *(const bf16x8*)(ap1 + kf * 32);
        xf1[kf] = *(const bf16x8*)(xp1 + kf * 32);
        af2[kf] = *(const bf16x8*)(ap2 + kf * 32);
        xf2[kf] = *(const bf16x8*)(xp2 + kf * 32);
    }
    int orow1 = r0 + (lane >> 4) * 4;
    int orow2 = r1 + (lane >> 4) * 4;
#pragma unroll
    for (int tt = 0; tt < 2; ++tt) {
        int ct = wid * 2 + tt;
        f32x4 acc1 = {0.f, 0.f, 0.f, 0.f};
        f32x4 acc2 = {0.f, 0.f, 0.f, 0.f};
        const u16* pLh = wlh + (size_t)(ct * 16 + l15) * FDIM + koff;
        const u16* pLl = wll + (size_t)(ct * 16 + l15) * FDIM + koff;
        const u16* pRh = wrh + (size_t)(ct * 16 + l15) * FDIM + koff;
        const u16* pRl = wrl + (size_t)(ct * 16 + l15) * FDIM + koff;
#pragma unroll
        for (int kf = 0; kf < 4; ++kf) {
            int o0 = kf * 32;
            bf16x8 bLh = *(const bf16x8*)(pLh + o0);
            bf16x8 bLl = *(const bf16x8*)(pLl + o0);
            bf16x8 bRh = *(const bf16x8*)(pRh + o0);
            bf16x8 bRl = *(const bf16x8*)(pRl + o0);
            acc1 = MFMA16(af1[kf], bLh, acc1);
            acc2 = MFMA16(af2[kf], bLh, acc2);
            acc1 = MFMA16(af1[kf], bLl, acc1);
            acc2 = MFMA16(af2[kf], bLl, acc2);
            acc1 = MFMA16(xf1[kf], bRh, acc1);
            acc2 = MFMA16(xf2[kf], bRh, acc2);
            acc1 = MFMA16(xf1[kf], bRl, acc1);
            acc2 = MFMA16(xf2[kf], bRl, acc2);
        }
        int oc = ct * 16 + l15;
        float bv = bl[oc];
#pragma unroll
        for (int i = 0; i < 4; ++i) {
            float v1 = acc1[i] + bv;
            hout[(size_t)(orow1 + i) * FDIM + oc] = f2bf(v1 > 0.f ? v1 : 0.f);
        }
        if (g2) {
#pragma unroll
            for (int i = 0; i < 4; ++i) {
                float v2 = acc2[i] + bv;
                hout[(size_t)(orow2 + i) * FDIM + oc] = f2bf(v2 > 0.f ? v2 : 0.f);
            }
        }
    }
}

// epilogue for the fused 3-head kernel: global col-tile ct in [0,30)
// cols 0..303 -> fea_lab (HD) | 304..415 -> logists (NCLS) | 416..479 -> conv+BN+tanh
__device__ __forceinline__ void heads3_epi(int ct, int l15, int orow, const f32x4& acc,
        const float* bhd, const float* bclas, const float* bconv,
        const float* gamma, const float* beta, const float* rm, const float* rv,
        const float* wtl, float* out, size_t o_flab, size_t o_log, size_t o_tanh,
        u16* tanhb, float* tl) {
    int gcol = ct * 16 + l15;
    if (gcol < 304) {
        if (gcol < 300) {
            float bv = bhd[gcol];
#pragma unroll
            for (int i = 0; i < 4; ++i)
                out[o_flab + (size_t)(orow + i) * HD + gcol] = acc[i] + bv;
        }
    } else if (gcol < 416) {
        int lc = gcol - 304;
        if (lc < NCLS) {
            float bv = bclas[lc];
#pragma unroll
            for (int i = 0; i < 4; ++i)
                out[o_log + (size_t)(orow + i) * NCLS + lc] = acc[i] + bv;
        }
    } else {
        int lc = gcol - 416;
        float bv = bconv[lc];
        float g  = gamma[lc];
        float be = beta[lc];
        float m  = rm[lc];
        float rs = rsqrtf(rv[lc] + 1e-5f);
        float wv = wtl[lc];
#pragma unroll
        for (int i = 0; i < 4; ++i) {
            float p = g * (acc[i] + bv - m) * rs + be;
            float th = tanhf(p);
            out[o_tanh + (size_t)(orow + i) * NBITS + lc] = th;
            tanhb[(size_t)(orow + i) * NBITS + lc] = f2bf(th);
            tl[i] += p * wv;
        }
    }
}

// ROUND-8: fused heads; 32 rows/block, 2 row-groups share the weight stream.
// Waves split tiles {0-7},{8-15},{16-22},{23-29} [struct r6/r7].
__global__ void __launch_bounds__(256) heads3_bfA_kernel(
        const u16* __restrict__ X,
        const u16* __restrict__ wh, const u16* __restrict__ wl,
        const float* __restrict__ bhd, const float* __restrict__ bclas,
        const float* __restrict__ bconv,
        const float* __restrict__ gamma, const float* __restrict__ beta,
        const float* __restrict__ rm, const float* __restrict__ rv,
        const float* __restrict__ wtl, const float* __restrict__ btl,
        float* __restrict__ out, size_t o_flab, size_t o_log, size_t o_tanh, size_t o_tl,
        u16* __restrict__ tanhb, const int* __restrict__ flag) {
    if (flag[0]) return;
    int wid = threadIdx.x >> 6, lane = threadIdx.x & 63;
    int r0 = blockIdx.x * 32;
    bool g2 = (r0 + 16) < NN;
    int r1 = g2 ? (r0 + 16) : r0;
    int l15 = lane & 15;
    int koff = (lane >> 4) * 8;

    bf16x8 a1[4], a2[4];
    const u16* xp1 = X + (size_t)(r0 + l15) * FDIM + koff;
    const u16* xp2 = X + (size_t)(r1 + l15) * FDIM + koff;
#pragma unroll
    for (int kf = 0; kf < 4; ++kf) {
        a1[kf] = *(const bf16x8*)(xp1 + kf * 32);
        a2[kf] = *(const bf16x8*)(xp2 + kf * 32);
    }

    int orow1 = r0 + (lane >> 4) * 4;
    int orow2 = r1 + (lane >> 4) * 4;
    float tl1[4] = {0.f, 0.f, 0.f, 0.f};
    float tl2[4] = {0.f, 0.f, 0.f, 0.f};

    int t0 = (wid == 0) ? 0 : (wid == 1) ? 8 : (wid == 2) ? 16 : 23;
    int t1 = (wid == 0) ? 8 : (wid == 1) ? 16 : (wid == 2) ? 23 : 30;
    for (int ct = t0; ct < t1; ++ct) {
        f32x4 acc1 = {0.f, 0.f, 0.f, 0.f};
        f32x4 acc2 = {0.f, 0.f, 0.f, 0.f};
        const u16* ph = wh + (size_t)(ct * 16 + l15) * FDIM + koff;
        const u16* pl = wl + (size_t)(ct * 16 + l15) * FDIM + koff;
#pragma unroll
        for (int kf = 0; kf < 4; ++kf) {
            int o0 = kf * 32;
            bf16x8 bh = *(const bf16x8*)(ph + o0);
            bf16x8 bl2 = *(const bf16x8*)(pl + o0);
            acc1 = MFMA16(a1[kf], bh, acc1);
            acc2 = MFMA16(a2[kf], bh, acc2);
            acc1 = MFMA16(a1[kf], bl2, acc1);
            acc2 = MFMA16(a2[kf], bl2, acc2);
        }
        heads3_epi(ct, l15, orow1, acc1, bhd, bclas, bconv, gamma, beta, rm, rv,
                   wtl, out, o_flab, o_log, o_tanh, tanhb, tl1);
        if (g2)
            heads3_epi(ct, l15, orow2, acc2, bhd, bclas, bconv, gamma, beta, rm, rv,
                       wtl, out, o_flab, o_log, o_tanh, tanhb, tl2);
    }

    if (wid == 3) {   // true_lab: conv tiles (26-29) are wave-3-local
        float bt = btl[0];
#pragma unroll
        for (int i = 0; i < 4; ++i) {
            float t = tl1[i];
            t += __shfl_xor(t, 1);
            t += __shfl_xor(t, 2);
            t += __shfl_xor(t, 4);
            t += __shfl_xor(t, 8);
            if (l15 == 0) out[o_tl + orow1 + i] = t + bt;
        }
        if (g2) {
#pragma unroll
            for (int i = 0; i < 4; ++i) {
                float t = tl2[i];
                t += __shfl_xor(t, 1);
                t += __shfl_xor(t, 2);
                t += __shfl_xor(t, 4);
                t += __shfl_xor(t, 8);
                if (l15 == 0) out[o_tl + orow2 + i] = t + bt;
            }
        }
    }
}

// fea_convert = tanh_out @ wcv + bcv; X = tanhb bf16, K=64.
// 64 rows/block, wave owns rows, all 7 tiles [struct validated r2/r5/r7].
__global__ void __launch_bounds__(256) headcv_bfA_kernel(
        const u16* __restrict__ X,
        const u16* __restrict__ wh, const u16* __restrict__ wl,
        const float* __restrict__ bcv, float* __restrict__ out, size_t o_fcv,
        const int* __restrict__ flag) {
    if (flag[0]) return;
    int wid = threadIdx.x >> 6, lane = threadIdx.x & 63;
    int r0 = blockIdx.x * 64 + wid * 16;
    if (r0 >= NN) return;
    int l15 = lane & 15;
    int koff = (lane >> 4) * 8;

    bf16x8 af[2];
    const u16* xp = X + (size_t)(r0 + l15) * NBITS + koff;
#pragma unroll
    for (int kf = 0; kf < 2; ++kf) af[kf] = *(const bf16x8*)(xp + kf * 32);

    int orow = r0 + (lane >> 4) * 4;
#pragma unroll
    for (int ct = 0; ct < 7; ++ct) {
        f32x4 acc = {0.f, 0.f, 0.f, 0.f};
        const u16* ph = wh + (size_t)(ct * 16 + l15) * NBITS + koff;
        const u16* pl = wl + (size_t)(ct * 16 + l15) * NBITS + koff;
#pragma unroll
        for (int kf = 0; kf < 2; ++kf) {
            int o0 = kf * 32;
            bf16x8 bh = *(const bf16x8*)(ph + o0);
            bf16x8 bl2 = *(const bf16x8*)(pl + o0);
            acc = MFMA16(af[kf], bh, acc);
            acc = MFMA16(af[kf], bl2, acc);
        }
        int oc = ct * 16 + l15;
        if (oc < NCLS) {
            float bv = bcv[oc];
#pragma unroll
            for (int i = 0; i < 4; ++i)
                out[o_fcv + (size_t)(orow + i) * NCLS + oc] = acc[i] + bv;
        }
    }
}

// ================= f32 vector fallback (only if workspace too small) ========
__global__ void __launch_bounds__(256) agg_f32_kernel(const float* __restrict__ x,
                                                      const int* __restrict__ rowptr,
                                                      const int* __restrict__ col,
                                                      float* __restrict__ aggm,
                                                      const int* __restrict__ flag) {
    if (flag[0]) return;
    int node = blockIdx.x * 4 + (threadIdx.x >> 6);
    int lane = threadIdx.x & 63;
    int half = lane >> 5;
    int c0 = (lane & 31) * 4;
    int beg = rowptr[node], end = rowptr[node + 1];
    float a0 = 0.f, a1 = 0.f, a2 = 0.f, a3 = 0.f;
    int j = beg;
    for (; j + 2 <= end; j += 2) {
        int nbr = col[j + half];
        float4 u = *(const float4*)(x + (size_t)nbr * FDIM + c0);
        a0 += u.x; a1 += u.y; a2 += u.z; a3 += u.w;
    }
    if (j < end && half == 0) {
        int nbr = col[j];
        float4 u = *(const float4*)(x + (size_t)nbr * FDIM + c0);
        a0 += u.x; a1 += u.y; a2 += u.z; a3 += u.w;
    }
    a0 += __shfl_xor(a0, 32);
    a1 += __shfl_xor(a1, 32);
    a2 += __shfl_xor(a2, 32);
    a3 += __shfl_xor(a3, 32);
    if (half == 0) {
        float inv = 1.f / fmaxf((float)(end - beg), 1.f);
        float4 o; o.x = a0 * inv; o.y = a1 * inv; o.z = a2 * inv; o.w = a3 * inv;
        *(float4*)(aggm + (size_t)node * FDIM + c0) = o;
    }
}

template <bool XBF, bool WBF>
__device__ __forceinline__ void sage_body(const float* aggm, const void* xv,
                                          const void* wl, const void* bl,
                                          const void* wr, float* hout) {
    __shared__ float ms[8][FDIM];
    __shared__ float xs[8][FDIM];
    int n0 = blockIdx.x * 8;
    int t = threadIdx.x;
    for (int idx = t; idx < 8 * FDIM; idx += 256) {
        int j = idx >> 7, k = idx & 127;
        int n = n0 + j;
        ms[j][k] = aggm[(size_t)n * FDIM + k];
        xs[j][k] = ldv<XBF>(xv, (size_t)n * FDIM + k);
    }
    __syncthreads();
    int f = t & 127;
    int h = t >> 7;
    float acc[4] = {0.f, 0.f, 0.f, 0.f};
    for (int k = 0; k < FDIM; ++k) {
        float wlv = ldv<WBF>(wl, k * FDIM + f);
        float wrv = ldv<WBF>(wr, k * FDIM + f);
#pragma unroll
        for (int j = 0; j < 4; ++j) {
            int nn = h + j * 2;
            acc[j] += ms[nn][k] * wlv + xs[nn][k] * wrv;
        }
    }
    float bv = ldv<WBF>(bl, f);
#pragma unroll
    for (int j = 0; j < 4; ++j) {
        int nn = h + j * 2;
        float v = acc[j] + bv;
        hout[(size_t)(n0 + nn) * FDIM + f] = v > 0.f ? v : 0.f;
    }
}

__global__ void __launch_bounds__(256) sage_f32_kernel(const float* aggm, const float* x,
                                                       const void* wl, const void* bl,
                                                       const void* wr, float* hout,
                                                       const int* flag) {
    if (flag[0]) return;
    sage_body<false, false>(aggm, x, wl, bl, wr, hout);
}

template <int KDIM, bool TANH_IN, bool BF>
__device__ __forceinline__ void head_body(const float* X, const void* W, const void* B,
                                          void* Y, size_t yoff, int fout,
                                          const void* gamma, const void* beta,
                                          const void* rm, const void* rv,
                                          float* pre_ws, int mode) {
    __shared__ float xs[16][KDIM];
    int n0 = blockIdx.x * 16;
    int t = threadIdx.x;
    for (int idx = t; idx < 16 * KDIM; idx += 256) {
        int j = idx / KDIM, k = idx % KDIM;
        float v = X[(size_t)(n0 + j) * KDIM + k];
        xs[j][k] = TANH_IN ? tanhf(v) : v;
    }
    __syncthreads();
    for (int f = t; f < fout; f += 256) {
        float acc[16];
#pragma unroll
        for (int j = 0; j < 16; ++j) acc[j] = 0.f;
        for (int k = 0; k < KDIM; ++k) {
            float wv = ldv<BF>(W, (size_t)k * fout + f);
#pragma unroll
            for (int j = 0; j < 16; ++j) acc[j] += xs[j][k] * wv;
        }
        float bv = ldv<BF>(B, f);
        if (mode == 0) {
#pragma unroll
            for (int j = 0; j < 16; ++j)
                stv<BF>(Y, yoff + (size_t)(n0 + j) * fout + f, acc[j] + bv);
        } else {
            float g  = ldv<BF>(gamma, f);
            float be = ldv<BF>(beta, f);
            float m  = ldv<BF>(rm, f);
            float rs = rsqrtf(ldv<BF>(rv, f) + 1e-5f);
#pragma unroll
            for (int j = 0; j < 16; ++j) {
                float p = g * (acc[j] + bv - m) * rs + be;
                pre_ws[(size_t)(n0 + j) * fout + f] = p;
                stv<BF>(Y, yoff + (size_t)(n0 + j) * fout + f, tanhf(p));
            }
        }
    }
}

template <int KDIM, bool TANH_IN>
__global__ void __launch_bounds__(256) head_f32_kernel(const float* X, const void* W,
                                                       const void* B, void* Y, size_t yoff,
                                                       int fout, const void* gamma,
                                                       const void* beta, const void* rm,
                                                       const void* rv, float* pre_ws,
                                                       int mode, const int* flag) {
    if (flag[0]) return;
    head_body<KDIM, TANH_IN, false>(X, W, B, Y, yoff, fout, gamma, beta, rm, rv, pre_ws, mode);
}

template <bool BF>
__device__ __forceinline__ void tl_body(const float* pre, const void* wtl,
                                        const void* btl, void* y, size_t yoff) {
    int i = blockIdx.x * 256 + threadIdx.x;
    if (i >= NN) return;
    float s = ldv<BF>(btl, 0);
#pragma unroll 8
    for (int k = 0; k < NBITS; ++k) s += pre[(size_t)i * NBITS + k] * ldv<BF>(wtl, k);
    stv<BF>(y, yoff + i, s);
}

__global__ void __launch_bounds__(256) true_lab_f32_kernel(const float* pre, const void* wtl,
                                                           const void* btl, void* y,
                                                           size_t yoff, const int* flag) {
    if (flag[0]) return;
    tl_body<false>(pre, wtl, btl, y, yoff);
}

// ================= bf16-input mode (flag=1) MFMA path =================
__global__ void __launch_bounds__(256) sage_mfma_kernel(
        const u16* __restrict__ agg, const u16* __restrict__ x,
        const u16* __restrict__ wtl, const u16* __restrict__ wtr,
        const void* __restrict__ bl, u16* __restrict__ hout,
        const int* __restrict__ flag) {
    if (!flag[0]) return;
    int wid = threadIdx.x >> 6, lane = threadIdx.x & 63;
    int r0 = blockIdx.x * 64 + wid * 16;
    if (r0 >= NN) return;
    int l15 = lane & 15;
    int koff = (lane >> 4) * 8;

    bf16x8 af[4], xf[4];
    const u16* ap = agg + (size_t)(r0 + l15) * FDIM + koff;
    const u16* xp = x   + (size_t)(r0 + l15) * FDIM + koff;
#pragma unroll
    for (int kf = 0; kf < 4; ++kf) {
        af[kf] = *(const bf16x8*)(ap + kf * 32);
        xf[kf] = *(const bf16x8*)(xp + kf * 32);
    }
    int orow = r0 + (lane >> 4) * 4;
    for (int ct = 0; ct < 8; ++ct) {
        int c0 = ct * 16;
        f32x4 acc = {0.f, 0.f, 0.f, 0.f};
        const u16* blp = wtl + (size_t)(c0 + l15) * FDIM + koff;
        const u16* brp = wtr + (size_t)(c0 + l15) * FDIM + koff;
#pragma unroll
        for (int kf = 0; kf < 4; ++kf) {
            bf16x8 bL = *(const bf16x8*)(blp + kf * 32);
            bf16x8 bR = *(const bf16x8*)(brp + kf * 32);
            acc = MFMA16(af[kf], bL, acc);
            acc = MFMA16(xf[kf], bR, acc);
        }
        int ocol = c0 + l15;
        float bv = us2f(((const u16*)bl)[ocol]);
#pragma unroll
        for (int i = 0; i < 4; ++i) {
            float v = acc[i] + bv;
            hout[(size_t)(orow + i) * FDIM + ocol] = f2bf(v > 0.f ? v : 0.f);
        }
    }
}

template <int K, int FP>
__global__ void __launch_bounds__(256) head_mfma_kernel(
        const u16* __restrict__ X, const u16* __restrict__ WT,
        const void* __restrict__ B, void* __restrict__ Y, size_t yoff,
        int fout, const int* __restrict__ flag) {
    if (!flag[0]) return;
    int wid = threadIdx.x >> 6, lane = threadIdx.x & 63;
    int r0 = blockIdx.x * 64 + wid * 16;
    if (r0 >= NN) return;
    int l15 = lane & 15;
    int koff = (lane >> 4) * 8;

    bf16x8 af[K / 32];
    const u16* xp = X + (size_t)(r0 + l15) * K + koff;
#pragma unroll
    for (int kf = 0; kf < K / 32; ++kf) af[kf] = *(const bf16x8*)(xp + kf * 32);

    u16* y = (u16*)Y + yoff;
    int orow = r0 + (lane >> 4) * 4;
    for (int ct = 0; ct < FP / 16; ++ct) {
        int c0 = ct * 16;
        f32x4 acc = {0.f, 0.f, 0.f, 0.f};
        const u16* bp = WT + (size_t)(c0 + l15) * K + koff;
#pragma unroll
        for (int kf = 0; kf < K / 32; ++kf) {
            bf16x8 bF = *(const bf16x8*)(bp + kf * 32);
            acc = MFMA16(af[kf], bF, acc);
        }
        int ocol = c0 + l15;
        if (ocol < fout) {
            float bv = us2f(((const u16*)B)[ocol]);
#pragma unroll
            for (int i = 0; i < 4; ++i)
                y[(size_t)(orow + i) * fout + ocol] = f2bf(acc[i] + bv);
        }
    }
}

__global__ void __launch_bounds__(256) headconv_mfma_kernel(
        const u16* __restrict__ X, const u16* __restrict__ WT,
        const void* __restrict__ B, const void* __restrict__ gamma,
        const void* __restrict__ beta, const void* __restrict__ rm,
        const void* __restrict__ rv, float* __restrict__ pre,
        void* __restrict__ Y, size_t yoff, const int* __restrict__ flag) {
    if (!flag[0]) return;
    int wid = threadIdx.x >> 6, lane = threadIdx.x & 63;
    int r0 = blockIdx.x * 64 + wid * 16;
    if (r0 >= NN) return;
    int l15 = lane & 15;
    int koff = (lane >> 4) * 8;

    bf16x8 af[4];
    const u16* xp = X + (size_t)(r0 + l15) * FDIM + koff;
#pragma unroll
    for (int kf = 0; kf < 4; ++kf) af[kf] = *(const bf16x8*)(xp + kf * 32);

    u16* y = (u16*)Y + yoff;
    int orow = r0 + (lane >> 4) * 4;
    for (int ct = 0; ct < 4; ++ct) {
        int c0 = ct * 16;
        f32x4 acc = {0.f, 0.f, 0.f, 0.f};
        const u16* bp = WT + (size_t)(c0 + l15) * FDIM + koff;
#pragma unroll
        for (int kf = 0; kf < 4; ++kf) {
            bf16x8 bF = *(const bf16x8*)(bp + kf * 32);
            acc = MFMA16(af[kf], bF, acc);
        }
        int ocol = c0 + l15;
        float bv = us2f(((const u16*)B)[ocol]);
        float g  = us2f(((const u16*)gamma)[ocol]);
        float be = us2f(((const u16*)beta)[ocol]);
        float m  = us2f(((const u16*)rm)[ocol]);
        float rs = rsqrtf(us2f(((const u16*)rv)[ocol]) + 1e-5f);
#pragma unroll
        for (int i = 0; i < 4; ++i) {
            float p = g * (acc[i] + bv - m) * rs + be;
            pre[(size_t)(orow + i) * NBITS + ocol] = p;
            y[(size_t)(orow + i) * NBITS + ocol] = f2bf(tanhf(p));
        }
    }
}

__global__ void __launch_bounds__(256) true_lab_b16_kernel(const float* pre, const void* wtl,
                                                           const void* btl, void* y,
                                                           size_t yoff, const int* flag) {
    if (!flag[0]) return;
    tl_body<true>(pre, wtl, btl, y, yoff);
}

extern "C" void kernel_launch(void* const* d_in, const int* in_sizes, int n_in,
                              void* d_out, int out_size, void* d_ws, size_t ws_size,
                              hipStream_t stream) {
    const void* feat = d_in[0];
    const int* edges = (const int*)d_in[1];
    const void* w1l = d_in[2];
    const void* b1l = d_in[3];
    const void* w1r = d_in[4];
    const void* w2l = d_in[5];
    const void* b2l = d_in[6];
    const void* w2r = d_in[7];
    const void* whd = d_in[8];
    const void* bhd = d_in[9];
    const void* wclas = d_in[10];
    const void* bclas = d_in[11];
    const void* wconv = d_in[12];
    const void* bconv = d_in[13];
    const void* gamma = d_in[14];
    const void* beta  = d_in[15];
    const void* rm  = d_in[16];
    const void* rv  = d_in[17];
    const void* wtl = d_in[18];
    const void* btl = d_in[19];
    const void* wcv = d_in[20];
    const void* bcv = d_in[21];

    int* iw     = (int*)d_ws;
    int* flag   = iw;
    int* deg    = iw + 16;
    int* cursor = deg + NN;
    int* rowptr = cursor + NN;
    int* col    = rowptr + 50016;
    float* buf1 = (float*)(col + NE);
    float* buf2 = buf1 + (size_t)NN * FDIM;
    float* pre_f = buf1;                       // fallback path only

    u16* wtf_hi = (u16*)(buf2 + (size_t)NN * FDIM);
    u16* wtf_lo = wtf_hi + WT_TOTAL;
    size_t need = (size_t)(16 + NN + NN + 50016 + NE) * 4
                + 2 * (size_t)NN * FDIM * 4
                + 2 * (size_t)WT_TOTAL * 2;
    bool mfma_ok = ws_size >= need;

    // f32-mode bf16 activation overlays (same footprint as buf1+buf2):
    u16* featb = (u16*)buf1;
    u16* h1b   = featb + (size_t)NN * FDIM;
    u16* aggX  = (u16*)buf2;
    u16* h2b   = aggX + (size_t)NN * FDIM;
    u16* tanhb = featb;   // reuse region A (featb dead after sage1)

    // bf16-input mode overlays (unchanged)
    u16* aggb = (u16*)buf1;
    u16* hb1  = aggb + (size_t)NN * FDIM;
    u16* hb2  = (u16*)buf2;
    float* pre_b = buf2 + (size_t)NN * 64;

    u16* wt = (u16*)deg;   // bf16-mode packed WT (268 KB < 400 KB deg+cursor)

    const int* src = edges;
    const int* dst = edges + NE;

    hipMemsetAsync(iw, 0, (size_t)(16 + 2 * NN) * sizeof(int), stream);

    detect_kernel<<<1, 256, 0, stream>>>((const unsigned short*)feat, flag);

    // CSR build
    deg_kernel<<<(NE + 255) / 256, 256, 0, stream>>>(dst, deg);
    scan_kernel<<<1, 1024, 0, stream>>>(deg, rowptr);
    fill_kernel<<<(NE + 255) / 256, 256, 0, stream>>>(src, dst, rowptr, cursor, col);

    // output element offsets: logists | tanh_out | fea_lab | fea_convert | true_lab
    size_t o_log  = 0;
    size_t o_tanh = (size_t)NN * NCLS;
    size_t o_flab = o_tanh + (size_t)NN * NBITS;
    size_t o_fcv  = o_flab + (size_t)NN * HD;
    size_t o_tl   = o_fcv + (size_t)NN * NCLS;

    const int GR   = (NN + 63) / 64;    // 64 rows/block kernels
    const int RB   = NN / 16;           // 16 rows/block kernels = 3125
    const int RB32 = (NN + 31) / 32;    // 32 rows/block kernels = 1563

    // ---------------- bf16-input MFMA path (flag=1) ----------------
    tr_all_kernel<<<(WT_TOTAL + 255) / 256, 256, 0, stream>>>(
        w1l, w1r, w2l, w2r, whd, wclas, wconv, wcv, wt, flag);
    aggb_kernel<<<NN / 4, 256, 0, stream>>>((const u16*)feat, rowptr, col, aggb, flag);
    sage_mfma_kernel<<<GR, 256, 0, stream>>>(aggb, (const u16*)feat, wt + WT_1L, wt + WT_1R, b1l, hb1, flag);
    aggb_kernel<<<NN / 4, 256, 0, stream>>>(hb1, rowptr, col, aggb, flag);
    sage_mfma_kernel<<<GR, 256, 0, stream>>>(aggb, hb1, wt + WT_2L, wt + WT_2R, b2l, hb2, flag);
    head_mfma_kernel<128, 304><<<GR, 256, 0, stream>>>(hb2, wt + WT_HD, bhd, d_out, o_flab, HD, flag);
    head_mfma_kernel<128, 112><<<GR, 256, 0, stream>>>(hb2, wt + WT_CLS, bclas, d_out, o_log, NCLS, flag);
    headconv_mfma_kernel<<<GR, 256, 0, stream>>>(hb2, wt + WT_CONV, bconv, gamma, beta, rm, rv,
                                                 pre_b, d_out, o_tanh, flag);
    head_mfma_kernel<64, 112><<<GR, 256, 0, stream>>>((const u16*)d_out + o_tanh, wt + WT_CV, bcv,
                                                      d_out, o_fcv, NCLS, flag);
    true_lab_b16_kernel<<<(NN + 255) / 256, 256, 0, stream>>>(pre_b, wtl, btl, d_out, o_tl, flag);

    // ---------------- f32-input path (flag=0): bf16 activations ----------------
    if (mfma_ok) {
        tr_f32_kernel<<<(WT_TOTAL + 255) / 256, 256, 0, stream>>>(
            (const float*)w1l, (const float*)w1r, (const float*)w2l, (const float*)w2r,
            (const float*)whd, (const float*)wclas, (const float*)wconv, (const float*)wcv,
            wtf_hi, wtf_lo, flag);

        cvt_bf_kernel<<<RB, 256, 0, stream>>>((const float*)feat, featb, flag);

        agg_bfA_kernel<<<NN / 4, 256, 0, stream>>>(featb, rowptr, col, aggX, flag);
        sage_bfA_kernel<<<RB32, 256, 0, stream>>>(
            aggX, featb,
            wtf_hi + WT_1L, wtf_lo + WT_1L, wtf_hi + WT_1R, wtf_lo + WT_1R,
            (const float*)b1l, h1b, flag);
        agg_bfA_kernel<<<NN / 4, 256, 0, stream>>>(h1b, rowptr, col, aggX, flag);
        sage_bfA_kernel<<<RB32, 256, 0, stream>>>(
            aggX, h1b,
            wtf_hi + WT_2L, wtf_lo + WT_2L, wtf_hi + WT_2R, wtf_lo + WT_2R,
            (const float*)b2l, h2b, flag);

        heads3_bfA_kernel<<<RB32, 256, 0, stream>>>(
            h2b, wtf_hi + WT_HD, wtf_lo + WT_HD,
            (const float*)bhd, (const float*)bclas, (const float*)bconv,
            (const float*)gamma, (const float*)beta, (const float*)rm, (const float*)rv,
            (const float*)wtl, (const float*)btl,
            (float*)d_out, o_flab, o_log, o_tanh, o_tl, tanhb, flag);
        headcv_bfA_kernel<<<GR, 256, 0, stream>>>(
            tanhb, wtf_hi + WT_CV, wtf_lo + WT_CV,
            (const float*)bcv, (float*)d_out, o_fcv, flag);
    } else {
        // fallback: original vector path (workspace too small for split weights)
        agg_f32_kernel<<<NN / 4, 256, 0, stream>>>((const float*)feat, rowptr, col, buf1, flag);
        sage_f32_kernel<<<NN / 8, 256, 0, stream>>>(buf1, (const float*)feat, w1l, b1l, w1r, buf1, flag);
        agg_f32_kernel<<<NN / 4, 256, 0, stream>>>(buf1, rowptr, col, buf2, flag);
        sage_f32_kernel<<<NN / 8, 256, 0, stream>>>(buf2, buf1, w2l, b2l, w2r, buf2, flag);

        head_f32_kernel<FDIM, false><<<NN / 16, 256, 0, stream>>>(
            buf2, whd, bhd, d_out, o_flab, HD,
            nullptr, nullptr, nullptr, nullptr, nullptr, 0, flag);
        head_f32_kernel<FDIM, false><<<NN / 16, 256, 0, stream>>>(
            buf2, wclas, bclas, d_out, o_log, NCLS,
            nullptr, nullptr, nullptr, nullptr, nullptr, 0, flag);
        head_f32_kernel<FDIM, false><<<NN / 16, 256, 0, stream>>>(
            buf2, wconv, bconv, d_out, o_tanh, NBITS,
            gamma, beta, rm, rv, pre_f, 1, flag);
        head_f32_kernel<NBITS, true><<<NN / 16, 256, 0, stream>>>(
            pre_f, wcv, bcv, d_out, o_fcv, NCLS,
            nullptr, nullptr, nullptr, nullptr, nullptr, 0, flag);
        true_lab_f32_kernel<<<(NN + 255) / 256, 256, 0, stream>>>(pre_f, wtl, btl, d_out, o_tl, flag);
    }
}